// Round 6
// baseline (1922.829 us; speedup 1.0000x reference)
//
#include <hip/hip_runtime.h>
#include <hip/hip_bf16.h>
#include <math.h>

#define HW 65536L

typedef __attribute__((ext_vector_type(8))) short bf16x8;
typedef __attribute__((ext_vector_type(4))) float f32x4;

__device__ __forceinline__ int iabs_(int v) { return v < 0 ? -v : v; }

// ---------------- conv 1x1 (Cin=96), register-resident, no LDS ----------------
// Output-channel groups split across blockIdx.z for occupancy (R5).
__global__ __launch_bounds__(256) void conv1x1(
    const float* __restrict__ in, long in_bstride,
    const float* __restrict__ w,
    float* __restrict__ out, long out_bstride,
    int ng_per, int mode)
{
  const int t = threadIdx.x;
  const int p = blockIdx.x * 256 + t;
  const int b = blockIdx.y;
  float x[96];
  if (mode == 0) {
    const float* src = in + (long)b * in_bstride + p;
    #pragma unroll
    for (int c = 0; c < 96; c++) x[c] = src[(long)c * HW];
  } else {
    // input is attention output (B,4096,1536); spatial pixel p maps to
    // att[n][blk*96+ci], n=(y%64)*64+(x%64), blk=(y/64)*4+(x/64)
    const int py = p >> 8, px = p & 255;
    const float* src = in + (long)b * in_bstride
        + ((long)((py & 63)*64 + (px & 63)) * 16 + ((py >> 6)*4 + (px >> 6))) * 96;
    #pragma unroll
    for (int cb = 0; cb < 24; cb++) {
      float4 v = *(const float4*)&src[cb*4];
      x[cb*4+0] = v.x; x[cb*4+1] = v.y; x[cb*4+2] = v.z; x[cb*4+3] = v.w;
    }
  }
  float* dst = out + (long)b * out_bstride + p;
  const int g0 = blockIdx.z * ng_per;
  for (int gi = 0; gi < ng_per; gi++) {
    const int g = g0 + gi;
    const float* wg = w + g*8*96;
    float acc[8];
    #pragma unroll
    for (int j = 0; j < 8; j++) acc[j] = 0.f;
    #pragma unroll
    for (int k = 0; k < 96; k++) {
      float xv = x[k];
      #pragma unroll
      for (int j = 0; j < 8; j++) acc[j] = fmaf(wg[j*96 + k], xv, acc[j]);
    }
    #pragma unroll
    for (int j = 0; j < 8; j++) dst[(long)(g*8 + j) * HW] = acc[j];
  }
}

// ---------------- depthwise 3x3 pad 1 ----------------
__global__ __launch_bounds__(256) void dw3x3(
    const float* __restrict__ in, const float* __restrict__ w,
    float* __restrict__ out, int CH)
{
  const int t = threadIdx.x;
  const int p = blockIdx.x * 256 + t;
  const int ch = blockIdx.y, b = blockIdx.z;
  const int y = p >> 8, x = p & 255;
  const float* ip = in + (long)(b*CH + ch) * HW;
  const float* wp = w + ch*9;
  float acc = 0.f;
  #pragma unroll
  for (int dy = -1; dy <= 1; dy++) {
    int yy = y + dy;
    if (yy < 0 || yy > 255) continue;
    #pragma unroll
    for (int dx = -1; dx <= 1; dx++) {
      int xx = x + dx;
      if (xx < 0 || xx > 255) continue;
      acc = fmaf(ip[yy*256 + xx], wp[(dy+1)*3 + (dx+1)], acc);
    }
  }
  out[(long)(b*CH + ch) * HW + p] = acc;
}

// ------- depthwise 3x3 fused with v_s permutation (coalesced, LDS reorder) ----
__global__ __launch_bounds__(256) void dw3x3_vs(
    const float* __restrict__ in, const float* __restrict__ w,
    float* __restrict__ vs)
{
  __shared__ float tile[96*65];
  const int t = threadIdx.x;
  const int gb = blockIdx.x;          // 0..1023 = y*4 + xb
  const int b = blockIdx.y;
  const int y = gb >> 2, xb = gb & 3;
  const int x0 = xb * 64;
  #pragma unroll
  for (int i = 0; i < 24; i++) {
    const int idx = i*256 + t;
    const int ci = idx >> 6, xl = idx & 63;
    const float* ip = in + ((long)b*96 + ci) * HW;
    const float* wp = w + ci*9;
    const int x = x0 + xl;
    float acc = 0.f;
    #pragma unroll
    for (int dy = -1; dy <= 1; dy++) {
      const int yy = y + dy;
      if (yy < 0 || yy > 255) continue;
      const float* rp = ip + yy*256;
      #pragma unroll
      for (int dx = -1; dx <= 1; dx++) {
        const int xx = x + dx;
        if (xx < 0 || xx > 255) continue;
        acc = fmaf(rp[xx], wp[(dy+1)*3 + (dx+1)], acc);
      }
    }
    tile[ci*65 + xl] = acc;
  }
  __syncthreads();
  const int blk = (y >> 6)*4 + xb;
  float* obase = vs + ((long)b*4096 + (long)(y & 63)*64) * 1536 + blk*96;
  #pragma unroll
  for (int i = 0; i < 24; i++) {
    const int idx = i*256 + t;
    const int nl = idx / 96, ci = idx % 96;
    obase[(long)nl*1536 + ci] = tile[ci*65 + nl];
  }
}

// ---------------- depthwise 4x4 stride 4 pad 1 (256->64) ----------------
__global__ __launch_bounds__(256) void dw4x4s4(
    const float* __restrict__ in, const float* __restrict__ w,
    float* __restrict__ out)
{
  const int t = threadIdx.x;
  const int op = blockIdx.x * 256 + t;
  const int ch = blockIdx.y, b = blockIdx.z;
  const int oy = op >> 6, ox = op & 63;
  const float* ip = in + (long)(b*192 + ch) * HW;
  const float* wp = w + ch*16;
  float acc = 0.f;
  #pragma unroll
  for (int ty = 0; ty < 4; ty++) {
    int iy = 4*oy + ty - 1;
    if (iy < 0 || iy > 255) continue;
    #pragma unroll
    for (int tx = 0; tx < 4; tx++) {
      int ix = 4*ox + tx - 1;
      if (ix < 0 || ix > 255) continue;
      acc = fmaf(ip[iy*256 + ix], wp[ty*4 + tx], acc);
    }
  }
  out[(long)(b*192 + ch) * 4096 + op] = acc;
}

// ---------------- l2 norm over 192 channels + transpose to (B,4096,192) ----
__global__ __launch_bounds__(256) void l2n192(
    const float* __restrict__ in, float* __restrict__ out)
{
  const int t = threadIdx.x;
  const int wid = t >> 6, lane = t & 63;
  const int gw = blockIdx.x * 4 + wid;      // 0..8191
  const int b = gw >> 12, n = gw & 4095;
  const float* ip = in + (long)b * 786432;  // 192*4096
  float v0 = ip[(long)(lane      ) * 4096 + n];
  float v1 = ip[(long)(lane +  64) * 4096 + n];
  float v2 = ip[(long)(lane + 128) * 4096 + n];
  float ss = v0*v0 + v1*v1 + v2*v2;
  #pragma unroll
  for (int s = 1; s < 64; s <<= 1) ss += __shfl_xor(ss, s, 64);
  float nrm = fmaxf(sqrtf(ss), 1e-12f);
  float* op = out + ((long)b*4096 + n) * 192;
  op[lane      ] = v0 / nrm;
  op[lane +  64] = v1 / nrm;
  op[lane + 128] = v2 / nrm;
}

// ---------------- split fp32 -> (hi,lo) bf16 planes: (4096,192) -> (4096,384) -
__global__ __launch_bounds__(256) void bf16split(
    const float* __restrict__ in, unsigned short* __restrict__ outp)
{
  const int i = blockIdx.x * 256 + threadIdx.x;   // 0..786431
  const int n = i / 192, k = i % 192;
  float f = in[i];
  __hip_bfloat16 h = __float2bfloat16(f);
  float hf = __bfloat162float(h);
  __hip_bfloat16 l = __float2bfloat16(f - hf);
  outp[(long)n*384 + k]       = *(unsigned short*)&h;
  outp[(long)n*384 + 192 + k] = *(unsigned short*)&l;
}

// ---------------- attention QK^T via split-bf16 MFMA (one batch) ------------
#define LDSROW 40   // ushorts per staged row (32 data + 8 pad) = 80 B
__global__ __launch_bounds__(256) void attn_qk_mfma(
    const unsigned short* __restrict__ Qsp, const unsigned short* __restrict__ Ksp,
    float* __restrict__ attn, const float* __restrict__ tp)
{
  __shared__ unsigned short qs[256*LDSROW];   // [hl*128+row][LDSROW]
  __shared__ unsigned short ks[256*LDSROW];
  const int t = threadIdx.x;
  const int lane = t & 63, w = t >> 6;
  const int n0 = blockIdx.x * 128;   // Q rows
  const int m0 = blockIdx.y * 128;   // K rows
  const int wr = (w >> 1) * 64, wc = (w & 1) * 64;
  f32x4 acc[4][4] = {};
  const int srow = t & 127;
  const int shl  = t >> 7;           // 0 = hi plane, 1 = lo plane
  const unsigned short* qsrc = Qsp + (long)(n0 + srow) * 384 + shl * 192;
  const unsigned short* ksrc = Ksp + (long)(m0 + srow) * 384 + shl * 192;
  unsigned short* qdst = qs + (shl*128 + srow) * LDSROW;
  unsigned short* kdst = ks + (shl*128 + srow) * LDSROW;
  const int fr = lane & 15;
  const int fk = lane >> 4;
  for (int s = 0; s < 6; s++) {
    __syncthreads();
    #pragma unroll
    for (int j = 0; j < 4; j++) {
      *(bf16x8*)(qdst + j*8) = *(const bf16x8*)(qsrc + s*32 + j*8);
      *(bf16x8*)(kdst + j*8) = *(const bf16x8*)(ksrc + s*32 + j*8);
    }
    __syncthreads();
    bf16x8 ah[4], al[4], bh[4], bl[4];
    #pragma unroll
    for (int i = 0; i < 4; i++) {
      ah[i] = *(const bf16x8*)(qs + (      wr + i*16 + fr) * LDSROW + fk*8);
      al[i] = *(const bf16x8*)(qs + (128 + wr + i*16 + fr) * LDSROW + fk*8);
      bh[i] = *(const bf16x8*)(ks + (      wc + i*16 + fr) * LDSROW + fk*8);
      bl[i] = *(const bf16x8*)(ks + (128 + wc + i*16 + fr) * LDSROW + fk*8);
    }
    #pragma unroll
    for (int i = 0; i < 4; i++)
      #pragma unroll
      for (int j = 0; j < 4; j++) {
        acc[i][j] = __builtin_amdgcn_mfma_f32_16x16x32_bf16(ah[i], bh[j], acc[i][j], 0, 0, 0);
        acc[i][j] = __builtin_amdgcn_mfma_f32_16x16x32_bf16(ah[i], bl[j], acc[i][j], 0, 0, 0);
        acc[i][j] = __builtin_amdgcn_mfma_f32_16x16x32_bf16(al[i], bh[j], acc[i][j], 0, 0, 0);
      }
  }
  const float temp = tp[0];
  #pragma unroll
  for (int i = 0; i < 4; i++)
    #pragma unroll
    for (int j = 0; j < 4; j++)
      #pragma unroll
      for (int r = 0; r < 4; r++) {
        const int nn = n0 + wr + i*16 + (lane >> 4)*4 + r;  // Q row (M)
        const int mm = m0 + wc + j*16 + (lane & 15);        // K row (N)
        attn[(long)nn*4096 + mm] = acc[i][j][r] * temp;
      }
}

// ------- top-5 + local mask + softmax + sparse out (one batch, one row/blk) -
__global__ __launch_bounds__(256) void attn_out_k(
    const float* __restrict__ attn, const float* __restrict__ vs,
    float* __restrict__ outr)
{
  __shared__ float row[4096];
  __shared__ float top5[256*5];
  __shared__ int   lm[4096];
  __shared__ float lw[4096];
  __shared__ float redf[8];
  __shared__ int   scan[256];
  const int t = threadIdx.x;
  const int n = blockIdx.x;
  const float* ar = attn + (long)n * 4096;
  #pragma unroll
  for (int k = 0; k < 16; k++) row[k*256 + t] = ar[k*256 + t];
  __syncthreads();
  float t0=-INFINITY,t1=-INFINITY,t2=-INFINITY,t3=-INFINITY,t4=-INFINITY;
  #pragma unroll
  for (int k = 0; k < 16; k++) {
    float v = row[k*256 + t];
    if (v > t4) {
      if (v > t0)      { t4=t3; t3=t2; t2=t1; t1=t0; t0=v; }
      else if (v > t1) { t4=t3; t3=t2; t2=t1; t1=v; }
      else if (v > t2) { t4=t3; t3=t2; t2=v; }
      else if (v > t3) { t4=t3; t3=v; }
      else             { t4=v; }
    }
  }
  top5[t*5+0]=t0; top5[t*5+1]=t1; top5[t*5+2]=t2; top5[t*5+3]=t3; top5[t*5+4]=t4;
  __syncthreads();
  for (int s = 128; s >= 1; s >>= 1) {
    if (t < s) {
      float* A = &top5[t*5];
      const float* B = &top5[(t+s)*5];
      float m[5]; int i = 0, j = 0;
      #pragma unroll
      for (int k = 0; k < 5; k++) {
        float av = A[i], bv = B[j];
        if (av >= bv) { m[k] = av; i++; } else { m[k] = bv; j++; }
      }
      #pragma unroll
      for (int k = 0; k < 5; k++) A[k] = m[k];
    }
    __syncthreads();
  }
  const float kth = top5[4];
  const int y = n >> 6, x = n & 63;
  int myc = 0;
  float wmax = -INFINITY;
  #pragma unroll
  for (int k = 0; k < 16; k++) {
    int m = k*256 + t;
    float a = row[m];
    int c = ((a >= kth) ? 1 : 0) +
            (((iabs_(y - (m >> 6)) + iabs_(x - (m & 63))) <= 4) ? 1 : 0);
    float wv = a * (float)c;
    if (wv != 0.0f) { myc++; wmax = fmaxf(wmax, wv); }
  }
  scan[t] = myc;
  __syncthreads();
  for (int s = 1; s < 256; s <<= 1) {
    int v = (t >= s) ? scan[t-s] : 0;
    __syncthreads();
    scan[t] += v;
    __syncthreads();
  }
  const int base = scan[t] - myc;
  const int cnt = scan[255];
  {
    int idx = base;
    #pragma unroll
    for (int k = 0; k < 16; k++) {
      int m = k*256 + t;
      float a = row[m];
      int c = ((a >= kth) ? 1 : 0) +
              (((iabs_(y - (m >> 6)) + iabs_(x - (m & 63))) <= 4) ? 1 : 0);
      float wv = a * (float)c;
      if (wv != 0.0f) { lm[idx] = m; lw[idx] = wv; idx++; }
    }
  }
  #pragma unroll
  for (int s = 1; s < 64; s <<= 1) wmax = fmaxf(wmax, __shfl_xor(wmax, s, 64));
  if ((t & 63) == 0) redf[t >> 6] = wmax;
  __syncthreads();
  const float gmax = fmaxf(fmaxf(redf[0], redf[1]), fmaxf(redf[2], redf[3]));
  __syncthreads();
  float ps = 0.f;
  for (int i = t; i < cnt; i += 256) ps += expf(lw[i] - gmax);
  #pragma unroll
  for (int s = 1; s < 64; s <<= 1) ps += __shfl_xor(ps, s, 64);
  if ((t & 63) == 0) redf[4 + (t >> 6)] = ps;
  __syncthreads();
  const float S = redf[4] + redf[5] + redf[6] + redf[7];
  const float invS = 1.0f / S;
  float a0=0,a1=0,a2=0,a3=0,a4=0,a5=0;
  for (int e = 0; e < cnt; e++) {
    float se = expf(lw[e] - gmax) * invS;
    const float* vr = vs + (long)lm[e] * 1536;
    a0 = fmaf(se, vr[          t], a0);
    a1 = fmaf(se, vr[ 256 + t], a1);
    a2 = fmaf(se, vr[ 512 + t], a2);
    a3 = fmaf(se, vr[ 768 + t], a3);
    a4 = fmaf(se, vr[1024 + t], a4);
    a5 = fmaf(se, vr[1280 + t], a5);
  }
  float* orow = outr + (long)n * 1536;
  orow[          t] = a0;
  orow[ 256 + t] = a1;
  orow[ 512 + t] = a2;
  orow[ 768 + t] = a3;
  orow[1024 + t] = a4;
  orow[1280 + t] = a5;
}

// ---------------- per-channel l2 norm over 65536 (fhr q2/k2) ----------------
__global__ __launch_bounds__(1024) void l2n_sp(
    const float* __restrict__ in, float* __restrict__ out)
{
  const int ch = blockIdx.x, b = blockIdx.y, t = threadIdx.x;
  const float* ip = in + ((long)b*96 + ch) * HW;
  float ss = 0.f;
  for (int i = t; i < 65536; i += 1024) { float v = ip[i]; ss = fmaf(v, v, ss); }
  __shared__ float red[16];
  #pragma unroll
  for (int s = 1; s < 64; s <<= 1) ss += __shfl_xor(ss, s, 64);
  if ((t & 63) == 0) red[t >> 6] = ss;
  __syncthreads();
  if (t == 0) {
    float s2 = 0.f;
    for (int i = 0; i < 16; i++) s2 += red[i];
    red[0] = fmaxf(sqrtf(s2), 1e-12f);
  }
  __syncthreads();
  const float nrm = red[0];
  float* op = out + ((long)b*96 + ch) * HW;
  for (int i = t; i < 65536; i += 1024) op[i] = ip[i] / nrm;
}

// -------- a2 stage 1: partial Gram (12x12) over 4096-elem chunks ------------
#define A2_NCH 16
__global__ __launch_bounds__(256) void a2_part(
    const float* __restrict__ q2n, const float* __restrict__ k2n,
    float* __restrict__ part)
{
  __shared__ float sh[24*260];
  const int t = threadIdx.x;
  const int ch = blockIdx.x, h = blockIdx.y, b = blockIdx.z;
  const long base = ((long)b*96 + h*12) * HW + ch*4096;
  const int c = t / 12, d = t - (t/12)*12;   // valid for t<144
  float acc = 0.f;
  for (int sub = 0; sub < 16; sub++) {
    __syncthreads();
    #pragma unroll
    for (int j = 0; j < 6; j++) {
      const int v = j*256 + t;          // 0..1535
      const int row = v >> 6;           // 0..23
      const int col4 = v & 63;
      const float* src = (row < 12)
        ? q2n + base + (long)row*HW + sub*256 + col4*4
        : k2n + base + (long)(row-12)*HW + sub*256 + col4*4;
      *(float4*)&sh[row*260 + col4*4] = *(const float4*)src;
    }
    __syncthreads();
    if (t < 144) {
      const float* qr = &sh[c*260];
      const float* kr = &sh[(12+d)*260];
      #pragma unroll
      for (int i4 = 0; i4 < 64; i4++) {
        float4 qv = *(const float4*)&qr[i4*4];
        float4 kv = *(const float4*)&kr[i4*4];
        acc = fmaf(qv.x, kv.x, acc);
        acc = fmaf(qv.y, kv.y, acc);
        acc = fmaf(qv.z, kv.z, acc);
        acc = fmaf(qv.w, kv.w, acc);
      }
    }
  }
  if (t < 144)
    part[(((long)b*8 + h)*A2_NCH + ch)*144 + t] = acc;
}

// -------- a2 stage 2: deterministic reduce + temp scale + softmax(12) -------
__global__ __launch_bounds__(256) void a2_fin(
    const float* __restrict__ part, const float* __restrict__ temp,
    float* __restrict__ a2s)
{
  __shared__ float m[144];
  const int t = threadIdx.x;
  const int h = blockIdx.x, b = blockIdx.y;
  if (t < 144) {
    float s = 0.f;
    const float* pp = part + (((long)b*8 + h)*A2_NCH)*144 + t;
    #pragma unroll
    for (int ch = 0; ch < A2_NCH; ch++) s += pp[ch*144];
    m[t] = s * temp[h];
  }
  __syncthreads();
  if (t < 12) {
    float mx = -INFINITY;
    #pragma unroll
    for (int d = 0; d < 12; d++) mx = fmaxf(mx, m[t*12+d]);
    float e[12], sum = 0.f;
    #pragma unroll
    for (int d = 0; d < 12; d++) { e[d] = expf(m[t*12+d]-mx); sum += e[d]; }
    float inv = 1.0f/sum;
    float* op = a2s + (((long)b*8 + h)*12 + t)*12;
    #pragma unroll
    for (int d = 0; d < 12; d++) op[d] = e[d]*inv;
  }
}

// ---------------- o2pre = a2 @ v2 ----------------
__global__ __launch_bounds__(256) void o2pre_kern(
    const float* __restrict__ a2s, const float* __restrict__ v2,
    float* __restrict__ o2p)
{
  const int t = threadIdx.x;
  const int n = blockIdx.x * 256 + t;
  const int bh = blockIdx.y, b = bh >> 3, h = bh & 7;
  const float* a = a2s + (long)bh * 144;
  const float* vb = v2 + ((long)b*96 + h*12) * HW;
  float vv[12];
  #pragma unroll
  for (int d = 0; d < 12; d++) vv[d] = vb[(long)d*HW + n];
  float* ob = o2p + ((long)b*96 + h*12) * HW;
  #pragma unroll
  for (int c = 0; c < 12; c++) {
    float s = 0.f;
    #pragma unroll
    for (int d = 0; d < 12; d++) s = fmaf(a[c*12 + d], vv[d], s);
    ob[(long)c*HW + n] = s;
  }
}

extern "C" void kernel_launch(void* const* d_in, const int* in_sizes, int n_in,
                              void* d_out, int out_size, void* d_ws, size_t ws_size,
                              hipStream_t stream) {
  const float* x        = (const float*)d_in[0];
  const float* qk_w     = (const float*)d_in[1];
  const float* qk_dw    = (const float*)d_in[2];
  const float* v_w      = (const float*)d_in[3];
  const float* v_dw     = (const float*)d_in[4];
  const float* k2_w     = (const float*)d_in[5];
  const float* k2_dw    = (const float*)d_in[6];
  const float* q2_w     = (const float*)d_in[7];
  const float* q2_dw    = (const float*)d_in[8];
  const float* proj_w   = (const float*)d_in[9];
  const float* sab_temp = (const float*)d_in[10];
  const float* fqkv_w   = (const float*)d_in[11];
  const float* fqkv_dw  = (const float*)d_in[12];
  const float* fproj_w  = (const float*)d_in[13];
  const float* fhr_temp = (const float*)d_in[14];
  float* out = (float*)d_out;
  float* ws  = (float*)d_ws;

  // d_out regions (floats)
  float* O2  = out;               // (2,96,256,256)
  float* KS  = out + 12582912;    // (2,1,1,4096,192)  = normalized k
  float* VS  = out + 14155776;    // (2,1,1,4096,1536) = permuted v
  float* K2N = out + 26738688;    // (2,8,12,65536)    = normalized k2
  float* V2  = out + 39321600;    // (2,8,12,65536)    = raw v2

  // ws arena (floats)
  float* A0   = ws;                // 25165824 (attn uses first 16777216)
  float* A1   = ws + 25165824;     // 25165824
  float* QD   = ws + 50331648;     // 1572864
  float* KD   = ws + 51904512;     // 1572864
  float* QN   = ws + 53477376;     // 1572864
  float* A2S  = ws + 55050240;     // 2304
  float* PART = ws + 55052544;     // 36864
  unsigned short* QSP = (unsigned short*)(A0 + 16777216);  // 4096*384 ushort
  unsigned short* KSP = (unsigned short*)(A0 + 16777216 + 786432);

  dim3 b256(256), b1024(1024);

  // 1) y1_qk = 1x1(x, qk_w) -> A0 (2,192,HW); 24 groups / 3 blocks
  conv1x1<<<dim3(256,2,3), b256, 0, stream>>>(x, 96L*HW, qk_w, A0, 192L*HW, 8, 0);
  // 2) qk = dw3x3(y1_qk) -> A1 (2,192,HW); q=ch[0:96), k=ch[96:192)
  dw3x3<<<dim3(256,192,2), b256, 0, stream>>>(A0, qk_dw, A1, 192);
  // 3) y1_v = 1x1(x, v_w) -> A0 (2,96,HW); 12 groups / 2 blocks
  conv1x1<<<dim3(256,2,2), b256, 0, stream>>>(x, 96L*HW, v_w, A0, 96L*HW, 6, 0);
  // 4) v_s = permute(dw3x3(y1_v)) -> d_out
  dw3x3_vs<<<dim3(1024,2), b256, 0, stream>>>(A0, v_dw, VS);
  // 5) q2pre = 1x1(q, q2_w) -> A0 (2,192,HW)
  conv1x1<<<dim3(256,2,3), b256, 0, stream>>>(A1, 192L*HW, q2_w, A0, 192L*HW, 8, 0);
  // 6) qd = dw4x4s4(q2pre)
  dw4x4s4<<<dim3(16,192,2), b256, 0, stream>>>(A0, q2_dw, QD);
  // 7) k2pre = 1x1(k, k2_w) -> A0
  conv1x1<<<dim3(256,2,3), b256, 0, stream>>>(A1 + 96L*HW, 192L*HW, k2_w, A0, 192L*HW, 8, 0);
  // 8) kd = dw4x4s4(k2pre)
  dw4x4s4<<<dim3(16,192,2), b256, 0, stream>>>(A0, k2_dw, KD);
  // 9/10) l2norm + transpose -> qn (ws), kn (d_out k_s)
  l2n192<<<dim3(2048), b256, 0, stream>>>(QD, QN);
  l2n192<<<dim3(2048), b256, 0, stream>>>(KD, KS);
  // 11) attention, per batch (attn materialized in A0[0:16.7M])
  for (int b = 0; b < 2; b++) {
    bf16split<<<dim3(3072), b256, 0, stream>>>(QN + (long)b*786432, QSP);
    bf16split<<<dim3(3072), b256, 0, stream>>>(KS + (long)b*786432, KSP);
    attn_qk_mfma<<<dim3(32,32), b256, 0, stream>>>(QSP, KSP, A0, sab_temp);
    attn_out_k<<<dim3(4096), b256, 0, stream>>>(
        A0, VS + (long)b*6291456, A1 + (long)b*6291456);
  }
  // 12) aligned = 1x1(permuted attn-out, proj_w) -> A0[0:12.58M]
  conv1x1<<<dim3(256,2,2), b256, 0, stream>>>(A1, 6291456L, proj_w, A0, 96L*HW, 6, 1);
  // 13-15) fhr qkv: three sequential 96-ch paths
  float* PRE  = A0 + 12582912;
  float* DW1  = A1 + 12582912;
  float* Q2NB = A1;
  // q2
  conv1x1<<<dim3(256,2,2), b256, 0, stream>>>(A0, 96L*HW, fqkv_w,        PRE, 96L*HW, 6, 0);
  dw3x3<<<dim3(256,96,2), b256, 0, stream>>>(PRE, fqkv_dw,        DW1, 96);
  l2n_sp<<<dim3(96,2), b1024, 0, stream>>>(DW1, Q2NB);
  // k2
  conv1x1<<<dim3(256,2,2), b256, 0, stream>>>(A0, 96L*HW, fqkv_w +  9216, PRE, 96L*HW, 6, 0);
  dw3x3<<<dim3(256,96,2), b256, 0, stream>>>(PRE, fqkv_dw +  864, DW1, 96);
  l2n_sp<<<dim3(96,2), b1024, 0, stream>>>(DW1, K2N);
  // v2 (raw dw output is the v2 output layout directly)
  conv1x1<<<dim3(256,2,2), b256, 0, stream>>>(A0, 96L*HW, fqkv_w + 18432, PRE, 96L*HW, 6, 0);
  dw3x3<<<dim3(256,96,2), b256, 0, stream>>>(PRE, fqkv_dw + 1728, V2, 96);
  // 16) a2 = softmax(q2n.k2n^T * fhr_temp), two-stage deterministic
  a2_part<<<dim3(A2_NCH,8,2), b256, 0, stream>>>(Q2NB, K2N, PART);
  a2_fin<<<dim3(8,2), b256, 0, stream>>>(PART, fhr_temp, A2S);
  // 17) o2pre = a2 @ v2 -> A0
  o2pre_kern<<<dim3(256,16), b256, 0, stream>>>(A2S, V2, A0);
  // 18) o2 = 1x1(o2pre, fproj_w) -> d_out
  conv1x1<<<dim3(256,2,2), b256, 0, stream>>>(A0, 96L*HW, fproj_w, O2, 96L*HW, 6, 0);
}

// Round 7
// 1286.393 us; speedup vs baseline: 1.4947x; 1.4947x over previous
//
#include <hip/hip_runtime.h>
#include <hip/hip_bf16.h>
#include <math.h>

#define HW 65536L

typedef __attribute__((ext_vector_type(8))) short bf16x8;
typedef __attribute__((ext_vector_type(4))) float f32x4;

__device__ __forceinline__ int iabs_(int v) { return v < 0 ? -v : v; }

// ---- split all 1x1 weights into (hi,lo) bf16 planes: whl[2][1152][96] ----
// row map: qk 0..191 | v 192..287 | q2 288..479 | k2 480..671 | proj 672..767
//          fqkv 768..1055 | fproj 1056..1151
__global__ __launch_bounds__(256) void wsplit(
    const float* __restrict__ qk, const float* __restrict__ v,
    const float* __restrict__ q2, const float* __restrict__ k2,
    const float* __restrict__ pj, const float* __restrict__ fq,
    const float* __restrict__ fp, unsigned short* __restrict__ whl)
{
  const int e = blockIdx.x*256 + threadIdx.x;
  if (e >= 110592) return;
  const int row = e / 96, col = e - row*96;
  float f;
  if      (row <  192) f = qk[e];
  else if (row <  288) f = v [(row-192)*96+col];
  else if (row <  480) f = q2[(row-288)*96+col];
  else if (row <  672) f = k2[(row-480)*96+col];
  else if (row <  768) f = pj[(row-672)*96+col];
  else if (row < 1056) f = fq[(row-768)*96+col];
  else                 f = fp[(row-1056)*96+col];
  __hip_bfloat16 h = __float2bfloat16(f);
  float hf = __bfloat162float(h);
  __hip_bfloat16 l = __float2bfloat16(f - hf);
  whl[e]          = *(unsigned short*)&h;
  whl[110592 + e] = *(unsigned short*)&l;
}

// ---------------- conv 1x1 via split-bf16 MFMA ----------------
// out[b][m0*16+..][p] = sum_c W[cout][c] * X[b][c][p], K=96, 128-pixel tiles.
// mode 0: X is (B,96/192...,HW) channel-planar (channel stride HW).
// mode 1: X is attention-out (B,4096,1536) permuted layout.
#define BLDS 104   // ushorts per pixel row (96 data + 8 pad) -> 2-way banks (free)
__global__ __launch_bounds__(256) void conv1x1_mfma(
    const float* __restrict__ in, long in_bstride,
    const unsigned short* __restrict__ whl, int wrow0,
    float* __restrict__ out, long out_bstride,
    int mtiles, int mode)
{
  __shared__ unsigned short bhs[128*BLDS];
  __shared__ unsigned short bls[128*BLDS];
  const int t = threadIdx.x;
  const int p0 = blockIdx.x * 128;
  const int b = blockIdx.y;
  if (mode == 0) {
    #pragma unroll
    for (int it = 0; it < 48; it++) {
      const int idx = it*256 + t;
      const int c = idx >> 7, pix = idx & 127;
      float f = in[(long)b*in_bstride + (long)c*HW + p0 + pix];
      __hip_bfloat16 h = __float2bfloat16(f);
      float hf = __bfloat162float(h);
      __hip_bfloat16 l = __float2bfloat16(f - hf);
      bhs[pix*BLDS + c] = *(unsigned short*)&h;
      bls[pix*BLDS + c] = *(unsigned short*)&l;
    }
  } else {
    // att[n][blk*96+ci]: pixel p -> n=(y%64)*64+(x%64), blk=(y/64)*4+(x/64);
    // channels contiguous per pixel.
    const int pp = t >> 1, half = (t & 1)*48;
    const int p = p0 + pp;
    const int py = p >> 8, px = p & 255;
    const float* src = in + (long)b*in_bstride
        + ((long)((py & 63)*64 + (px & 63))*16 + ((py >> 6)*4 + (px >> 6)))*96 + half;
    #pragma unroll
    for (int j4 = 0; j4 < 12; j4++) {
      float4 v4 = *(const float4*)&src[j4*4];
      float fv[4] = {v4.x, v4.y, v4.z, v4.w};
      #pragma unroll
      for (int u = 0; u < 4; u++) {
        __hip_bfloat16 h = __float2bfloat16(fv[u]);
        float hf = __bfloat162float(h);
        __hip_bfloat16 l = __float2bfloat16(fv[u] - hf);
        bhs[pp*BLDS + half + j4*4 + u] = *(unsigned short*)&h;
        bls[pp*BLDS + half + j4*4 + u] = *(unsigned short*)&l;
      }
    }
  }
  __syncthreads();
  const int lane = t & 63, w = t >> 6;
  const int fr = lane & 15, fk = lane >> 4;
  // B fragments: wave owns 32 pixels (2 N-tiles), register-resident for all M.
  bf16x8 Bh[2][3], Bl[2][3];
  #pragma unroll
  for (int nt = 0; nt < 2; nt++)
    #pragma unroll
    for (int kt = 0; kt < 3; kt++) {
      const int pix = w*32 + nt*16 + fr;
      Bh[nt][kt] = *(const bf16x8*)(bhs + pix*BLDS + kt*32 + fk*8);
      Bl[nt][kt] = *(const bf16x8*)(bls + pix*BLDS + kt*32 + fk*8);
    }
  float* dst = out + (long)b*out_bstride + p0 + w*32;
  for (int m = 0; m < mtiles; m++) {
    const long wbase = (long)(wrow0 + m*16 + fr)*96 + fk*8;
    bf16x8 Ah[3], Al[3];
    #pragma unroll
    for (int kt = 0; kt < 3; kt++) {
      Ah[kt] = *(const bf16x8*)(whl + wbase + kt*32);
      Al[kt] = *(const bf16x8*)(whl + 110592 + wbase + kt*32);
    }
    f32x4 acc[2] = {};
    #pragma unroll
    for (int nt = 0; nt < 2; nt++)
      #pragma unroll
      for (int kt = 0; kt < 3; kt++) {
        acc[nt] = __builtin_amdgcn_mfma_f32_16x16x32_bf16(Ah[kt], Bh[nt][kt], acc[nt], 0, 0, 0);
        acc[nt] = __builtin_amdgcn_mfma_f32_16x16x32_bf16(Ah[kt], Bl[nt][kt], acc[nt], 0, 0, 0);
        acc[nt] = __builtin_amdgcn_mfma_f32_16x16x32_bf16(Al[kt], Bh[nt][kt], acc[nt], 0, 0, 0);
      }
    #pragma unroll
    for (int nt = 0; nt < 2; nt++)
      #pragma unroll
      for (int r = 0; r < 4; r++)
        dst[(long)(m*16 + fk*4 + r)*HW + nt*16 + fr] = acc[nt][r];
  }
}

// ---------------- depthwise 3x3 pad 1 ----------------
__global__ __launch_bounds__(256) void dw3x3(
    const float* __restrict__ in, const float* __restrict__ w,
    float* __restrict__ out, int CH)
{
  const int t = threadIdx.x;
  const int p = blockIdx.x * 256 + t;
  const int ch = blockIdx.y, b = blockIdx.z;
  const int y = p >> 8, x = p & 255;
  const float* ip = in + (long)(b*CH + ch) * HW;
  const float* wp = w + ch*9;
  float acc = 0.f;
  #pragma unroll
  for (int dy = -1; dy <= 1; dy++) {
    int yy = y + dy;
    if (yy < 0 || yy > 255) continue;
    #pragma unroll
    for (int dx = -1; dx <= 1; dx++) {
      int xx = x + dx;
      if (xx < 0 || xx > 255) continue;
      acc = fmaf(ip[yy*256 + xx], wp[(dy+1)*3 + (dx+1)], acc);
    }
  }
  out[(long)(b*CH + ch) * HW + p] = acc;
}

// ------- depthwise 3x3 fused with v_s permutation (coalesced, LDS reorder) ----
__global__ __launch_bounds__(256) void dw3x3_vs(
    const float* __restrict__ in, const float* __restrict__ w,
    float* __restrict__ vs)
{
  __shared__ float tile[96*65];
  const int t = threadIdx.x;
  const int gb = blockIdx.x;          // 0..1023 = y*4 + xb
  const int b = blockIdx.y;
  const int y = gb >> 2, xb = gb & 3;
  const int x0 = xb * 64;
  #pragma unroll
  for (int i = 0; i < 24; i++) {
    const int idx = i*256 + t;
    const int ci = idx >> 6, xl = idx & 63;
    const float* ip = in + ((long)b*96 + ci) * HW;
    const float* wp = w + ci*9;
    const int x = x0 + xl;
    float acc = 0.f;
    #pragma unroll
    for (int dy = -1; dy <= 1; dy++) {
      const int yy = y + dy;
      if (yy < 0 || yy > 255) continue;
      const float* rp = ip + yy*256;
      #pragma unroll
      for (int dx = -1; dx <= 1; dx++) {
        const int xx = x + dx;
        if (xx < 0 || xx > 255) continue;
        acc = fmaf(rp[xx], wp[(dy+1)*3 + (dx+1)], acc);
      }
    }
    tile[ci*65 + xl] = acc;
  }
  __syncthreads();
  const int blk = (y >> 6)*4 + xb;
  float* obase = vs + ((long)b*4096 + (long)(y & 63)*64) * 1536 + blk*96;
  #pragma unroll
  for (int i = 0; i < 24; i++) {
    const int idx = i*256 + t;
    const int nl = idx / 96, ci = idx % 96;
    obase[(long)nl*1536 + ci] = tile[ci*65 + nl];
  }
}

// ---------------- depthwise 4x4 stride 4 pad 1 (256->64) ----------------
__global__ __launch_bounds__(256) void dw4x4s4(
    const float* __restrict__ in, const float* __restrict__ w,
    float* __restrict__ out)
{
  const int t = threadIdx.x;
  const int op = blockIdx.x * 256 + t;
  const int ch = blockIdx.y, b = blockIdx.z;
  const int oy = op >> 6, ox = op & 63;
  const float* ip = in + (long)(b*192 + ch) * HW;
  const float* wp = w + ch*16;
  float acc = 0.f;
  #pragma unroll
  for (int ty = 0; ty < 4; ty++) {
    int iy = 4*oy + ty - 1;
    if (iy < 0 || iy > 255) continue;
    #pragma unroll
    for (int tx = 0; tx < 4; tx++) {
      int ix = 4*ox + tx - 1;
      if (ix < 0 || ix > 255) continue;
      acc = fmaf(ip[iy*256 + ix], wp[ty*4 + tx], acc);
    }
  }
  out[(long)(b*192 + ch) * 4096 + op] = acc;
}

// ---------------- l2 norm over 192 channels + transpose to (B,4096,192) ----
__global__ __launch_bounds__(256) void l2n192(
    const float* __restrict__ in, float* __restrict__ out)
{
  const int t = threadIdx.x;
  const int wid = t >> 6, lane = t & 63;
  const int gw = blockIdx.x * 4 + wid;      // 0..8191
  const int b = gw >> 12, n = gw & 4095;
  const float* ip = in + (long)b * 786432;  // 192*4096
  float v0 = ip[(long)(lane      ) * 4096 + n];
  float v1 = ip[(long)(lane +  64) * 4096 + n];
  float v2 = ip[(long)(lane + 128) * 4096 + n];
  float ss = v0*v0 + v1*v1 + v2*v2;
  #pragma unroll
  for (int s = 1; s < 64; s <<= 1) ss += __shfl_xor(ss, s, 64);
  float nrm = fmaxf(sqrtf(ss), 1e-12f);
  float* op = out + ((long)b*4096 + n) * 192;
  op[lane      ] = v0 / nrm;
  op[lane +  64] = v1 / nrm;
  op[lane + 128] = v2 / nrm;
}

// ---------------- split fp32 -> (hi,lo) bf16 planes: (4096,192) -> (4096,384) -
__global__ __launch_bounds__(256) void bf16split(
    const float* __restrict__ in, unsigned short* __restrict__ outp)
{
  const int i = blockIdx.x * 256 + threadIdx.x;   // 0..786431
  const int n = i / 192, k = i % 192;
  float f = in[i];
  __hip_bfloat16 h = __float2bfloat16(f);
  float hf = __bfloat162float(h);
  __hip_bfloat16 l = __float2bfloat16(f - hf);
  outp[(long)n*384 + k]       = *(unsigned short*)&h;
  outp[(long)n*384 + 192 + k] = *(unsigned short*)&l;
}

// ---------------- attention QK^T via split-bf16 MFMA (one batch) ------------
#define LDSROW 40   // ushorts per staged row (32 data + 8 pad) = 80 B
__global__ __launch_bounds__(256) void attn_qk_mfma(
    const unsigned short* __restrict__ Qsp, const unsigned short* __restrict__ Ksp,
    float* __restrict__ attn, const float* __restrict__ tp)
{
  __shared__ unsigned short qs[256*LDSROW];   // [hl*128+row][LDSROW]
  __shared__ unsigned short ks[256*LDSROW];
  const int t = threadIdx.x;
  const int lane = t & 63, w = t >> 6;
  const int n0 = blockIdx.x * 128;   // Q rows
  const int m0 = blockIdx.y * 128;   // K rows
  const int wr = (w >> 1) * 64, wc = (w & 1) * 64;
  f32x4 acc[4][4] = {};
  const int srow = t & 127;
  const int shl  = t >> 7;           // 0 = hi plane, 1 = lo plane
  const unsigned short* qsrc = Qsp + (long)(n0 + srow) * 384 + shl * 192;
  const unsigned short* ksrc = Ksp + (long)(m0 + srow) * 384 + shl * 192;
  unsigned short* qdst = qs + (shl*128 + srow) * LDSROW;
  unsigned short* kdst = ks + (shl*128 + srow) * LDSROW;
  const int fr = lane & 15;
  const int fk = lane >> 4;
  for (int s = 0; s < 6; s++) {
    __syncthreads();
    #pragma unroll
    for (int j = 0; j < 4; j++) {
      *(bf16x8*)(qdst + j*8) = *(const bf16x8*)(qsrc + s*32 + j*8);
      *(bf16x8*)(kdst + j*8) = *(const bf16x8*)(ksrc + s*32 + j*8);
    }
    __syncthreads();
    bf16x8 ah[4], al[4], bh[4], bl[4];
    #pragma unroll
    for (int i = 0; i < 4; i++) {
      ah[i] = *(const bf16x8*)(qs + (      wr + i*16 + fr) * LDSROW + fk*8);
      al[i] = *(const bf16x8*)(qs + (128 + wr + i*16 + fr) * LDSROW + fk*8);
      bh[i] = *(const bf16x8*)(ks + (      wc + i*16 + fr) * LDSROW + fk*8);
      bl[i] = *(const bf16x8*)(ks + (128 + wc + i*16 + fr) * LDSROW + fk*8);
    }
    #pragma unroll
    for (int i = 0; i < 4; i++)
      #pragma unroll
      for (int j = 0; j < 4; j++) {
        acc[i][j] = __builtin_amdgcn_mfma_f32_16x16x32_bf16(ah[i], bh[j], acc[i][j], 0, 0, 0);
        acc[i][j] = __builtin_amdgcn_mfma_f32_16x16x32_bf16(ah[i], bl[j], acc[i][j], 0, 0, 0);
        acc[i][j] = __builtin_amdgcn_mfma_f32_16x16x32_bf16(al[i], bh[j], acc[i][j], 0, 0, 0);
      }
  }
  const float temp = tp[0];
  #pragma unroll
  for (int i = 0; i < 4; i++)
    #pragma unroll
    for (int j = 0; j < 4; j++)
      #pragma unroll
      for (int r = 0; r < 4; r++) {
        const int nn = n0 + wr + i*16 + (lane >> 4)*4 + r;  // Q row (M)
        const int mm = m0 + wc + j*16 + (lane & 15);        // K row (N)
        attn[(long)nn*4096 + mm] = acc[i][j][r] * temp;
      }
}

// ------- top-5 + local mask + softmax + sparse out (one batch, one row/blk) -
__global__ __launch_bounds__(256) void attn_out_k(
    const float* __restrict__ attn, const float* __restrict__ vs,
    float* __restrict__ outr)
{
  __shared__ float row[4096];
  __shared__ float top5[256*5];
  __shared__ int   lm[4096];
  __shared__ float lw[4096];
  __shared__ float redf[8];
  __shared__ int   scan[256];
  const int t = threadIdx.x;
  const int n = blockIdx.x;
  const float* ar = attn + (long)n * 4096;
  #pragma unroll
  for (int k = 0; k < 16; k++) row[k*256 + t] = ar[k*256 + t];
  __syncthreads();
  float t0=-INFINITY,t1=-INFINITY,t2=-INFINITY,t3=-INFINITY,t4=-INFINITY;
  #pragma unroll
  for (int k = 0; k < 16; k++) {
    float v = row[k*256 + t];
    if (v > t4) {
      if (v > t0)      { t4=t3; t3=t2; t2=t1; t1=t0; t0=v; }
      else if (v > t1) { t4=t3; t3=t2; t2=t1; t1=v; }
      else if (v > t2) { t4=t3; t3=t2; t2=v; }
      else if (v > t3) { t4=t3; t3=v; }
      else             { t4=v; }
    }
  }
  top5[t*5+0]=t0; top5[t*5+1]=t1; top5[t*5+2]=t2; top5[t*5+3]=t3; top5[t*5+4]=t4;
  __syncthreads();
  for (int s = 128; s >= 1; s >>= 1) {
    if (t < s) {
      float* A = &top5[t*5];
      const float* B = &top5[(t+s)*5];
      float m[5]; int i = 0, j = 0;
      #pragma unroll
      for (int k = 0; k < 5; k++) {
        float av = A[i], bv = B[j];
        if (av >= bv) { m[k] = av; i++; } else { m[k] = bv; j++; }
      }
      #pragma unroll
      for (int k = 0; k < 5; k++) A[k] = m[k];
    }
    __syncthreads();
  }
  const float kth = top5[4];
  const int y = n >> 6, x = n & 63;
  int myc = 0;
  float wmax = -INFINITY;
  #pragma unroll
  for (int k = 0; k < 16; k++) {
    int m = k*256 + t;
    float a = row[m];
    int c = ((a >= kth) ? 1 : 0) +
            (((iabs_(y - (m >> 6)) + iabs_(x - (m & 63))) <= 4) ? 1 : 0);
    float wv = a * (float)c;
    if (wv != 0.0f) { myc++; wmax = fmaxf(wmax, wv); }
  }
  scan[t] = myc;
  __syncthreads();
  for (int s = 1; s < 256; s <<= 1) {
    int v = (t >= s) ? scan[t-s] : 0;
    __syncthreads();
    scan[t] += v;
    __syncthreads();
  }
  const int base = scan[t] - myc;
  const int cnt = scan[255];
  {
    int idx = base;
    #pragma unroll
    for (int k = 0; k < 16; k++) {
      int m = k*256 + t;
      float a = row[m];
      int c = ((a >= kth) ? 1 : 0) +
              (((iabs_(y - (m >> 6)) + iabs_(x - (m & 63))) <= 4) ? 1 : 0);
      float wv = a * (float)c;
      if (wv != 0.0f) { lm[idx] = m; lw[idx] = wv; idx++; }
    }
  }
  #pragma unroll
  for (int s = 1; s < 64; s <<= 1) wmax = fmaxf(wmax, __shfl_xor(wmax, s, 64));
  if ((t & 63) == 0) redf[t >> 6] = wmax;
  __syncthreads();
  const float gmax = fmaxf(fmaxf(redf[0], redf[1]), fmaxf(redf[2], redf[3]));
  __syncthreads();
  float ps = 0.f;
  for (int i = t; i < cnt; i += 256) ps += expf(lw[i] - gmax);
  #pragma unroll
  for (int s = 1; s < 64; s <<= 1) ps += __shfl_xor(ps, s, 64);
  if ((t & 63) == 0) redf[4 + (t >> 6)] = ps;
  __syncthreads();
  const float S = redf[4] + redf[5] + redf[6] + redf[7];
  const float invS = 1.0f / S;
  float a0=0,a1=0,a2=0,a3=0,a4=0,a5=0;
  for (int e = 0; e < cnt; e++) {
    float se = expf(lw[e] - gmax) * invS;
    const float* vr = vs + (long)lm[e] * 1536;
    a0 = fmaf(se, vr[          t], a0);
    a1 = fmaf(se, vr[ 256 + t], a1);
    a2 = fmaf(se, vr[ 512 + t], a2);
    a3 = fmaf(se, vr[ 768 + t], a3);
    a4 = fmaf(se, vr[1024 + t], a4);
    a5 = fmaf(se, vr[1280 + t], a5);
  }
  float* orow = outr + (long)n * 1536;
  orow[          t] = a0;
  orow[ 256 + t] = a1;
  orow[ 512 + t] = a2;
  orow[ 768 + t] = a3;
  orow[1024 + t] = a4;
  orow[1280 + t] = a5;
}

// ---------------- per-channel l2 norm over 65536 (fhr q2/k2) ----------------
__global__ __launch_bounds__(1024) void l2n_sp(
    const float* __restrict__ in, float* __restrict__ out)
{
  const int ch = blockIdx.x, b = blockIdx.y, t = threadIdx.x;
  const float* ip = in + ((long)b*96 + ch) * HW;
  float ss = 0.f;
  for (int i = t; i < 65536; i += 1024) { float v = ip[i]; ss = fmaf(v, v, ss); }
  __shared__ float red[16];
  #pragma unroll
  for (int s = 1; s < 64; s <<= 1) ss += __shfl_xor(ss, s, 64);
  if ((t & 63) == 0) red[t >> 6] = ss;
  __syncthreads();
  if (t == 0) {
    float s2 = 0.f;
    for (int i = 0; i < 16; i++) s2 += red[i];
    red[0] = fmaxf(sqrtf(s2), 1e-12f);
  }
  __syncthreads();
  const float nrm = red[0];
  float* op = out + ((long)b*96 + ch) * HW;
  for (int i = t; i < 65536; i += 1024) op[i] = ip[i] / nrm;
}

// -------- a2 stage 1: partial Gram (12x12) over 4096-elem chunks ------------
#define A2_NCH 16
__global__ __launch_bounds__(256) void a2_part(
    const float* __restrict__ q2n, const float* __restrict__ k2n,
    float* __restrict__ part)
{
  __shared__ float sh[24*260];
  const int t = threadIdx.x;
  const int ch = blockIdx.x, h = blockIdx.y, b = blockIdx.z;
  const long base = ((long)b*96 + h*12) * HW + ch*4096;
  const int c = t / 12, d = t - (t/12)*12;   // valid for t<144
  float acc = 0.f;
  for (int sub = 0; sub < 16; sub++) {
    __syncthreads();
    #pragma unroll
    for (int j = 0; j < 6; j++) {
      const int v = j*256 + t;          // 0..1535
      const int row = v >> 6;           // 0..23
      const int col4 = v & 63;
      const float* src = (row < 12)
        ? q2n + base + (long)row*HW + sub*256 + col4*4
        : k2n + base + (long)(row-12)*HW + sub*256 + col4*4;
      *(float4*)&sh[row*260 + col4*4] = *(const float4*)src;
    }
    __syncthreads();
    if (t < 144) {
      const float* qr = &sh[c*260];
      const float* kr = &sh[(12+d)*260];
      #pragma unroll
      for (int i4 = 0; i4 < 64; i4++) {
        float4 qv = *(const float4*)&qr[i4*4];
        float4 kv = *(const float4*)&kr[i4*4];
        acc = fmaf(qv.x, kv.x, acc);
        acc = fmaf(qv.y, kv.y, acc);
        acc = fmaf(qv.z, kv.z, acc);
        acc = fmaf(qv.w, kv.w, acc);
      }
    }
  }
  if (t < 144)
    part[(((long)b*8 + h)*A2_NCH + ch)*144 + t] = acc;
}

// -------- a2 stage 2: deterministic reduce + temp scale + softmax(12) -------
__global__ __launch_bounds__(256) void a2_fin(
    const float* __restrict__ part, const float* __restrict__ temp,
    float* __restrict__ a2s)
{
  __shared__ float m[144];
  const int t = threadIdx.x;
  const int h = blockIdx.x, b = blockIdx.y;
  if (t < 144) {
    float s = 0.f;
    const float* pp = part + (((long)b*8 + h)*A2_NCH)*144 + t;
    #pragma unroll
    for (int ch = 0; ch < A2_NCH; ch++) s += pp[ch*144];
    m[t] = s * temp[h];
  }
  __syncthreads();
  if (t < 12) {
    float mx = -INFINITY;
    #pragma unroll
    for (int d = 0; d < 12; d++) mx = fmaxf(mx, m[t*12+d]);
    float e[12], sum = 0.f;
    #pragma unroll
    for (int d = 0; d < 12; d++) { e[d] = expf(m[t*12+d]-mx); sum += e[d]; }
    float inv = 1.0f/sum;
    float* op = a2s + (((long)b*8 + h)*12 + t)*12;
    #pragma unroll
    for (int d = 0; d < 12; d++) op[d] = e[d]*inv;
  }
}

// ---------------- o2pre = a2 @ v2 ----------------
__global__ __launch_bounds__(256) void o2pre_kern(
    const float* __restrict__ a2s, const float* __restrict__ v2,
    float* __restrict__ o2p)
{
  const int t = threadIdx.x;
  const int n = blockIdx.x * 256 + t;
  const int bh = blockIdx.y, b = bh >> 3, h = bh & 7;
  const float* a = a2s + (long)bh * 144;
  const float* vb = v2 + ((long)b*96 + h*12) * HW;
  float vv[12];
  #pragma unroll
  for (int d = 0; d < 12; d++) vv[d] = vb[(long)d*HW + n];
  float* ob = o2p + ((long)b*96 + h*12) * HW;
  #pragma unroll
  for (int c = 0; c < 12; c++) {
    float s = 0.f;
    #pragma unroll
    for (int d = 0; d < 12; d++) s = fmaf(a[c*12 + d], vv[d], s);
    ob[(long)c*HW + n] = s;
  }
}

extern "C" void kernel_launch(void* const* d_in, const int* in_sizes, int n_in,
                              void* d_out, int out_size, void* d_ws, size_t ws_size,
                              hipStream_t stream) {
  const float* x        = (const float*)d_in[0];
  const float* qk_w     = (const float*)d_in[1];
  const float* qk_dw    = (const float*)d_in[2];
  const float* v_w      = (const float*)d_in[3];
  const float* v_dw     = (const float*)d_in[4];
  const float* k2_w     = (const float*)d_in[5];
  const float* k2_dw    = (const float*)d_in[6];
  const float* q2_w     = (const float*)d_in[7];
  const float* q2_dw    = (const float*)d_in[8];
  const float* proj_w   = (const float*)d_in[9];
  const float* sab_temp = (const float*)d_in[10];
  const float* fqkv_w   = (const float*)d_in[11];
  const float* fqkv_dw  = (const float*)d_in[12];
  const float* fproj_w  = (const float*)d_in[13];
  const float* fhr_temp = (const float*)d_in[14];
  float* out = (float*)d_out;
  float* ws  = (float*)d_ws;

  // d_out regions (floats)
  float* O2  = out;               // (2,96,256,256)
  float* KS  = out + 12582912;    // (2,1,1,4096,192)  = normalized k
  float* VS  = out + 14155776;    // (2,1,1,4096,1536) = permuted v
  float* K2N = out + 26738688;    // (2,8,12,65536)    = normalized k2
  float* V2  = out + 39321600;    // (2,8,12,65536)    = raw v2

  // ws arena (floats)
  float* A0   = ws;                // 25165824 (attn uses first 16777216)
  float* A1   = ws + 25165824;     // 25165824
  float* QD   = ws + 50331648;     // 1572864
  float* KD   = ws + 51904512;     // 1572864
  float* QN   = ws + 53477376;     // 1572864  (also hosts WHL outside steps 9-11)
  float* A2S  = ws + 55050240;     // 2304
  float* PART = ws + 55052544;     // 36864
  unsigned short* QSP = (unsigned short*)(A0 + 16777216);  // 4096*384 ushort
  unsigned short* KSP = (unsigned short*)(A0 + 16777216 + 786432);
  // WHL (split 1x1 weights) lives in QN's slot: 221184 ushorts = 110592 floats.
  // QN is only live steps 9-11; wsplit is re-run after the attention loop.
  unsigned short* WHL = (unsigned short*)QN;

  dim3 b256(256), b1024(1024);

  // 0) split all 1x1 conv weights to bf16 hi/lo
  wsplit<<<dim3(432), b256, 0, stream>>>(qk_w, v_w, q2_w, k2_w, proj_w, fqkv_w, fproj_w, WHL);
  // 1) y1_qk = 1x1(x, qk_w) -> A0 (2,192,HW)
  conv1x1_mfma<<<dim3(512,2), b256, 0, stream>>>(x, 96L*HW, WHL, 0, A0, 192L*HW, 12, 0);
  // 2) qk = dw3x3(y1_qk) -> A1 (2,192,HW); q=ch[0:96), k=ch[96:192)
  dw3x3<<<dim3(256,192,2), b256, 0, stream>>>(A0, qk_dw, A1, 192);
  // 3) y1_v = 1x1(x, v_w) -> A0 (2,96,HW)
  conv1x1_mfma<<<dim3(512,2), b256, 0, stream>>>(x, 96L*HW, WHL, 192, A0, 96L*HW, 6, 0);
  // 4) v_s = permute(dw3x3(y1_v)) -> d_out
  dw3x3_vs<<<dim3(1024,2), b256, 0, stream>>>(A0, v_dw, VS);
  // 5) q2pre = 1x1(q, q2_w) -> A0 (2,192,HW)
  conv1x1_mfma<<<dim3(512,2), b256, 0, stream>>>(A1, 192L*HW, WHL, 288, A0, 192L*HW, 12, 0);
  // 6) qd = dw4x4s4(q2pre)
  dw4x4s4<<<dim3(16,192,2), b256, 0, stream>>>(A0, q2_dw, QD);
  // 7) k2pre = 1x1(k, k2_w) -> A0
  conv1x1_mfma<<<dim3(512,2), b256, 0, stream>>>(A1 + 96L*HW, 192L*HW, WHL, 480, A0, 192L*HW, 12, 0);
  // 8) kd = dw4x4s4(k2pre)
  dw4x4s4<<<dim3(16,192,2), b256, 0, stream>>>(A0, k2_dw, KD);
  // 9/10) l2norm + transpose -> qn (ws, clobbers WHL), kn (d_out k_s)
  l2n192<<<dim3(2048), b256, 0, stream>>>(QD, QN);
  l2n192<<<dim3(2048), b256, 0, stream>>>(KD, KS);
  // 11) attention, per batch (attn materialized in A0[0:16.7M])
  for (int b = 0; b < 2; b++) {
    bf16split<<<dim3(3072), b256, 0, stream>>>(QN + (long)b*786432, QSP);
    bf16split<<<dim3(3072), b256, 0, stream>>>(KS + (long)b*786432, KSP);
    attn_qk_mfma<<<dim3(32,32), b256, 0, stream>>>(QSP, KSP, A0, sab_temp);
    attn_out_k<<<dim3(4096), b256, 0, stream>>>(
        A0, VS + (long)b*6291456, A1 + (long)b*6291456);
  }
  // re-split weights (QN slot was clobbered by step 9)
  wsplit<<<dim3(432), b256, 0, stream>>>(qk_w, v_w, q2_w, k2_w, proj_w, fqkv_w, fproj_w, WHL);
  // 12) aligned = 1x1(permuted attn-out, proj_w) -> A0[0:12.58M]
  conv1x1_mfma<<<dim3(512,2), b256, 0, stream>>>(A1, 6291456L, WHL, 672, A0, 96L*HW, 6, 1);
  // 13-15) fhr qkv: three sequential 96-ch paths
  float* PRE  = A0 + 12582912;
  float* DW1  = A1 + 12582912;
  float* Q2NB = A1;
  // q2
  conv1x1_mfma<<<dim3(512,2), b256, 0, stream>>>(A0, 96L*HW, WHL, 768, PRE, 96L*HW, 6, 0);
  dw3x3<<<dim3(256,96,2), b256, 0, stream>>>(PRE, fqkv_dw,        DW1, 96);
  l2n_sp<<<dim3(96,2), b1024, 0, stream>>>(DW1, Q2NB);
  // k2
  conv1x1_mfma<<<dim3(512,2), b256, 0, stream>>>(A0, 96L*HW, WHL, 864, PRE, 96L*HW, 6, 0);
  dw3x3<<<dim3(256,96,2), b256, 0, stream>>>(PRE, fqkv_dw +  864, DW1, 96);
  l2n_sp<<<dim3(96,2), b1024, 0, stream>>>(DW1, K2N);
  // v2 (raw dw output is the v2 output layout directly)
  conv1x1_mfma<<<dim3(512,2), b256, 0, stream>>>(A0, 96L*HW, WHL, 960, PRE, 96L*HW, 6, 0);
  dw3x3<<<dim3(256,96,2), b256, 0, stream>>>(PRE, fqkv_dw + 1728, V2, 96);
  // 16) a2 = softmax(q2n.k2n^T * fhr_temp), two-stage deterministic
  a2_part<<<dim3(A2_NCH,8,2), b256, 0, stream>>>(Q2NB, K2N, PART);
  a2_fin<<<dim3(8,2), b256, 0, stream>>>(PART, fhr_temp, A2S);
  // 17) o2pre = a2 @ v2 -> A0
  o2pre_kern<<<dim3(256,16), b256, 0, stream>>>(A2S, V2, A0);
  // 18) o2 = 1x1(o2pre, fproj_w) -> d_out
  conv1x1_mfma<<<dim3(512,2), b256, 0, stream>>>(A0, 96L*HW, WHL, 1056, O2, 96L*HW, 6, 0);
}

// Round 8
// 1106.499 us; speedup vs baseline: 1.7378x; 1.1626x over previous
//
#include <hip/hip_runtime.h>
#include <hip/hip_bf16.h>
#include <math.h>

#define HW 65536L

typedef __attribute__((ext_vector_type(8))) short bf16x8;
typedef __attribute__((ext_vector_type(4))) float f32x4;

__device__ __forceinline__ int iabs_(int v) { return v < 0 ? -v : v; }

// ---- split all 1x1 weights into (hi,lo) bf16 planes: whl[2][1152][96] ----
// row map: qk 0..191 | v 192..287 | q2 288..479 | k2 480..671 | proj 672..767
//          fqkv 768..1055 | fproj 1056..1151
__global__ __launch_bounds__(256) void wsplit(
    const float* __restrict__ qk, const float* __restrict__ v,
    const float* __restrict__ q2, const float* __restrict__ k2,
    const float* __restrict__ pj, const float* __restrict__ fq,
    const float* __restrict__ fp, unsigned short* __restrict__ whl)
{
  const int e = blockIdx.x*256 + threadIdx.x;
  if (e >= 110592) return;
  const int row = e / 96, col = e - row*96;
  float f;
  if      (row <  192) f = qk[e];
  else if (row <  288) f = v [(row-192)*96+col];
  else if (row <  480) f = q2[(row-288)*96+col];
  else if (row <  672) f = k2[(row-480)*96+col];
  else if (row <  768) f = pj[(row-672)*96+col];
  else if (row < 1056) f = fq[(row-768)*96+col];
  else                 f = fp[(row-1056)*96+col];
  __hip_bfloat16 h = __float2bfloat16(f);
  float hf = __bfloat162float(h);
  __hip_bfloat16 l = __float2bfloat16(f - hf);
  whl[e]          = *(unsigned short*)&h;
  whl[110592 + e] = *(unsigned short*)&l;
}

// ---------------- conv 1x1 via split-bf16 MFMA ----------------
#define BLDS 104   // ushorts per pixel row (96 data + 8 pad) -> 2-way banks (free)
__global__ __launch_bounds__(256) void conv1x1_mfma(
    const float* __restrict__ in, long in_bstride,
    const unsigned short* __restrict__ whl, int wrow0,
    float* __restrict__ out, long out_bstride,
    int mtiles, int mode)
{
  __shared__ unsigned short bhs[128*BLDS];
  __shared__ unsigned short bls[128*BLDS];
  const int t = threadIdx.x;
  const int p0 = blockIdx.x * 128;
  const int b = blockIdx.y;
  if (mode == 0) {
    #pragma unroll
    for (int it = 0; it < 48; it++) {
      const int idx = it*256 + t;
      const int c = idx >> 7, pix = idx & 127;
      float f = in[(long)b*in_bstride + (long)c*HW + p0 + pix];
      __hip_bfloat16 h = __float2bfloat16(f);
      float hf = __bfloat162float(h);
      __hip_bfloat16 l = __float2bfloat16(f - hf);
      bhs[pix*BLDS + c] = *(unsigned short*)&h;
      bls[pix*BLDS + c] = *(unsigned short*)&l;
    }
  } else {
    const int pp = t >> 1, half = (t & 1)*48;
    const int p = p0 + pp;
    const int py = p >> 8, px = p & 255;
    const float* src = in + (long)b*in_bstride
        + ((long)((py & 63)*64 + (px & 63))*16 + ((py >> 6)*4 + (px >> 6)))*96 + half;
    #pragma unroll
    for (int j4 = 0; j4 < 12; j4++) {
      float4 v4 = *(const float4*)&src[j4*4];
      float fv[4] = {v4.x, v4.y, v4.z, v4.w};
      #pragma unroll
      for (int u = 0; u < 4; u++) {
        __hip_bfloat16 h = __float2bfloat16(fv[u]);
        float hf = __bfloat162float(h);
        __hip_bfloat16 l = __float2bfloat16(fv[u] - hf);
        bhs[pp*BLDS + half + j4*4 + u] = *(unsigned short*)&h;
        bls[pp*BLDS + half + j4*4 + u] = *(unsigned short*)&l;
      }
    }
  }
  __syncthreads();
  const int lane = t & 63, w = t >> 6;
  const int fr = lane & 15, fk = lane >> 4;
  bf16x8 Bh[2][3], Bl[2][3];
  #pragma unroll
  for (int nt = 0; nt < 2; nt++)
    #pragma unroll
    for (int kt = 0; kt < 3; kt++) {
      const int pix = w*32 + nt*16 + fr;
      Bh[nt][kt] = *(const bf16x8*)(bhs + pix*BLDS + kt*32 + fk*8);
      Bl[nt][kt] = *(const bf16x8*)(bls + pix*BLDS + kt*32 + fk*8);
    }
  float* dst = out + (long)b*out_bstride + p0 + w*32;
  for (int m = 0; m < mtiles; m++) {
    const long wbase = (long)(wrow0 + m*16 + fr)*96 + fk*8;
    bf16x8 Ah[3], Al[3];
    #pragma unroll
    for (int kt = 0; kt < 3; kt++) {
      Ah[kt] = *(const bf16x8*)(whl + wbase + kt*32);
      Al[kt] = *(const bf16x8*)(whl + 110592 + wbase + kt*32);
    }
    f32x4 acc[2] = {};
    #pragma unroll
    for (int nt = 0; nt < 2; nt++)
      #pragma unroll
      for (int kt = 0; kt < 3; kt++) {
        acc[nt] = __builtin_amdgcn_mfma_f32_16x16x32_bf16(Ah[kt], Bh[nt][kt], acc[nt], 0, 0, 0);
        acc[nt] = __builtin_amdgcn_mfma_f32_16x16x32_bf16(Ah[kt], Bl[nt][kt], acc[nt], 0, 0, 0);
        acc[nt] = __builtin_amdgcn_mfma_f32_16x16x32_bf16(Al[kt], Bh[nt][kt], acc[nt], 0, 0, 0);
      }
    #pragma unroll
    for (int nt = 0; nt < 2; nt++)
      #pragma unroll
      for (int r = 0; r < 4; r++)
        dst[(long)(m*16 + fk*4 + r)*HW + nt*16 + fr] = acc[nt][r];
  }
}

// -------- depthwise 3x3 pad 1, 4-wide vectorized (R7: issue-rate fix) --------
__global__ __launch_bounds__(256) void dw3x3v(
    const float* __restrict__ in, const float* __restrict__ w,
    float* __restrict__ out, int CH)
{
  const int t = threadIdx.x;
  const int p4 = blockIdx.x * 256 + t;        // 0..16383 quad index
  const int ch = blockIdx.y, b = blockIdx.z;
  const int y = p4 >> 6, x0 = (p4 & 63) << 2;
  const float* ip = in + (long)(b*CH + ch) * HW;
  const float* wp = w + ch*9;
  float a0 = 0.f, a1 = 0.f, a2 = 0.f, a3 = 0.f;
  #pragma unroll
  for (int dy = -1; dy <= 1; dy++) {
    const int yy = y + dy;
    if (yy < 0 || yy > 255) continue;
    const float* rp = ip + yy*256;
    const float4 c = *(const float4*)&rp[x0];
    const float left  = (x0 > 0)   ? rp[x0-1] : 0.f;
    const float right = (x0 < 252) ? rp[x0+4] : 0.f;
    const float w0 = wp[(dy+1)*3+0], w1 = wp[(dy+1)*3+1], w2 = wp[(dy+1)*3+2];
    // keep reference accumulation order: w0, then w1, then w2 per row
    a0 = fmaf(left, w0, a0); a0 = fmaf(c.x, w1, a0); a0 = fmaf(c.y, w2, a0);
    a1 = fmaf(c.x,  w0, a1); a1 = fmaf(c.y, w1, a1); a1 = fmaf(c.z, w2, a1);
    a2 = fmaf(c.y,  w0, a2); a2 = fmaf(c.z, w1, a2); a2 = fmaf(c.w, w2, a2);
    a3 = fmaf(c.z,  w0, a3); a3 = fmaf(c.w, w1, a3); a3 = fmaf(right, w2, a3);
  }
  float4 o; o.x = a0; o.y = a1; o.z = a2; o.w = a3;
  *(float4*)&out[(long)(b*CH + ch)*HW + y*256 + x0] = o;
}

// ------- depthwise 3x3 fused with v_s permutation (coalesced, LDS reorder) ----
__global__ __launch_bounds__(256) void dw3x3_vs(
    const float* __restrict__ in, const float* __restrict__ w,
    float* __restrict__ vs)
{
  __shared__ float tile[96*65];
  const int t = threadIdx.x;
  const int gb = blockIdx.x;          // 0..1023 = y*4 + xb
  const int b = blockIdx.y;
  const int y = gb >> 2, xb = gb & 3;
  const int x0 = xb * 64;
  #pragma unroll
  for (int i = 0; i < 24; i++) {
    const int idx = i*256 + t;
    const int ci = idx >> 6, xl = idx & 63;
    const float* ip = in + ((long)b*96 + ci) * HW;
    const float* wp = w + ci*9;
    const int x = x0 + xl;
    float acc = 0.f;
    #pragma unroll
    for (int dy = -1; dy <= 1; dy++) {
      const int yy = y + dy;
      if (yy < 0 || yy > 255) continue;
      const float* rp = ip + yy*256;
      #pragma unroll
      for (int dx = -1; dx <= 1; dx++) {
        const int xx = x + dx;
        if (xx < 0 || xx > 255) continue;
        acc = fmaf(rp[xx], wp[(dy+1)*3 + (dx+1)], acc);
      }
    }
    tile[ci*65 + xl] = acc;
  }
  __syncthreads();
  const int blk = (y >> 6)*4 + xb;
  float* obase = vs + ((long)b*4096 + (long)(y & 63)*64) * 1536 + blk*96;
  #pragma unroll
  for (int i = 0; i < 24; i++) {
    const int idx = i*256 + t;
    const int nl = idx / 96, ci = idx % 96;
    obase[(long)nl*1536 + ci] = tile[ci*65 + nl];
  }
}

// ---------------- depthwise 4x4 stride 4 pad 1 (256->64) ----------------
__global__ __launch_bounds__(256) void dw4x4s4(
    const float* __restrict__ in, const float* __restrict__ w,
    float* __restrict__ out)
{
  const int t = threadIdx.x;
  const int op = blockIdx.x * 256 + t;
  const int ch = blockIdx.y, b = blockIdx.z;
  const int oy = op >> 6, ox = op & 63;
  const float* ip = in + (long)(b*192 + ch) * HW;
  const float* wp = w + ch*16;
  float acc = 0.f;
  #pragma unroll
  for (int ty = 0; ty < 4; ty++) {
    int iy = 4*oy + ty - 1;
    if (iy < 0 || iy > 255) continue;
    #pragma unroll
    for (int tx = 0; tx < 4; tx++) {
      int ix = 4*ox + tx - 1;
      if (ix < 0 || ix > 255) continue;
      acc = fmaf(ip[iy*256 + ix], wp[ty*4 + tx], acc);
    }
  }
  out[(long)(b*192 + ch) * 4096 + op] = acc;
}

// ---------------- l2 norm over 192 channels + transpose to (B,4096,192) ----
__global__ __launch_bounds__(256) void l2n192(
    const float* __restrict__ in, float* __restrict__ out)
{
  const int t = threadIdx.x;
  const int wid = t >> 6, lane = t & 63;
  const int gw = blockIdx.x * 4 + wid;      // 0..8191
  const int b = gw >> 12, n = gw & 4095;
  const float* ip = in + (long)b * 786432;  // 192*4096
  float v0 = ip[(long)(lane      ) * 4096 + n];
  float v1 = ip[(long)(lane +  64) * 4096 + n];
  float v2 = ip[(long)(lane + 128) * 4096 + n];
  float ss = v0*v0 + v1*v1 + v2*v2;
  #pragma unroll
  for (int s = 1; s < 64; s <<= 1) ss += __shfl_xor(ss, s, 64);
  float nrm = fmaxf(sqrtf(ss), 1e-12f);
  float* op = out + ((long)b*4096 + n) * 192;
  op[lane      ] = v0 / nrm;
  op[lane +  64] = v1 / nrm;
  op[lane + 128] = v2 / nrm;
}

// ---------------- split fp32 -> (hi,lo) bf16 planes: (4096,192) -> (4096,384) -
__global__ __launch_bounds__(256) void bf16split(
    const float* __restrict__ in, unsigned short* __restrict__ outp)
{
  const int i = blockIdx.x * 256 + threadIdx.x;   // 0..786431
  const int n = i / 192, k = i % 192;
  float f = in[i];
  __hip_bfloat16 h = __float2bfloat16(f);
  float hf = __bfloat162float(h);
  __hip_bfloat16 l = __float2bfloat16(f - hf);
  outp[(long)n*384 + k]       = *(unsigned short*)&h;
  outp[(long)n*384 + 192 + k] = *(unsigned short*)&l;
}

// ---------------- attention QK^T via split-bf16 MFMA (one batch) ------------
#define LDSROW 40   // ushorts per staged row (32 data + 8 pad) = 80 B
__global__ __launch_bounds__(256) void attn_qk_mfma(
    const unsigned short* __restrict__ Qsp, const unsigned short* __restrict__ Ksp,
    float* __restrict__ attn, const float* __restrict__ tp)
{
  __shared__ unsigned short qs[256*LDSROW];   // [hl*128+row][LDSROW]
  __shared__ unsigned short ks[256*LDSROW];
  const int t = threadIdx.x;
  const int lane = t & 63, w = t >> 6;
  const int n0 = blockIdx.x * 128;   // Q rows
  const int m0 = blockIdx.y * 128;   // K rows
  const int wr = (w >> 1) * 64, wc = (w & 1) * 64;
  f32x4 acc[4][4] = {};
  const int srow = t & 127;
  const int shl  = t >> 7;           // 0 = hi plane, 1 = lo plane
  const unsigned short* qsrc = Qsp + (long)(n0 + srow) * 384 + shl * 192;
  const unsigned short* ksrc = Ksp + (long)(m0 + srow) * 384 + shl * 192;
  unsigned short* qdst = qs + (shl*128 + srow) * LDSROW;
  unsigned short* kdst = ks + (shl*128 + srow) * LDSROW;
  const int fr = lane & 15;
  const int fk = lane >> 4;
  for (int s = 0; s < 6; s++) {
    __syncthreads();
    #pragma unroll
    for (int j = 0; j < 4; j++) {
      *(bf16x8*)(qdst + j*8) = *(const bf16x8*)(qsrc + s*32 + j*8);
      *(bf16x8*)(kdst + j*8) = *(const bf16x8*)(ksrc + s*32 + j*8);
    }
    __syncthreads();
    bf16x8 ah[4], al[4], bh[4], bl[4];
    #pragma unroll
    for (int i = 0; i < 4; i++) {
      ah[i] = *(const bf16x8*)(qs + (      wr + i*16 + fr) * LDSROW + fk*8);
      al[i] = *(const bf16x8*)(qs + (128 + wr + i*16 + fr) * LDSROW + fk*8);
      bh[i] = *(const bf16x8*)(ks + (      wc + i*16 + fr) * LDSROW + fk*8);
      bl[i] = *(const bf16x8*)(ks + (128 + wc + i*16 + fr) * LDSROW + fk*8);
    }
    #pragma unroll
    for (int i = 0; i < 4; i++)
      #pragma unroll
      for (int j = 0; j < 4; j++) {
        acc[i][j] = __builtin_amdgcn_mfma_f32_16x16x32_bf16(ah[i], bh[j], acc[i][j], 0, 0, 0);
        acc[i][j] = __builtin_amdgcn_mfma_f32_16x16x32_bf16(ah[i], bl[j], acc[i][j], 0, 0, 0);
        acc[i][j] = __builtin_amdgcn_mfma_f32_16x16x32_bf16(al[i], bh[j], acc[i][j], 0, 0, 0);
      }
  }
  const float temp = tp[0];
  #pragma unroll
  for (int i = 0; i < 4; i++)
    #pragma unroll
    for (int j = 0; j < 4; j++)
      #pragma unroll
      for (int r = 0; r < 4; r++) {
        const int nn = n0 + wr + i*16 + (lane >> 4)*4 + r;  // Q row (M)
        const int mm = m0 + wc + j*16 + (lane & 15);        // K row (N)
        attn[(long)nn*4096 + mm] = acc[i][j][r] * temp;
      }
}

// ------- top-5 + local mask + softmax + sparse out (one batch, one row/blk) -
__global__ __launch_bounds__(256) void attn_out_k(
    const float* __restrict__ attn, const float* __restrict__ vs,
    float* __restrict__ outr)
{
  __shared__ float row[4096];
  __shared__ float top5[256*5];
  __shared__ int   lm[4096];
  __shared__ float lw[4096];
  __shared__ float redf[8];
  __shared__ int   scan[256];
  const int t = threadIdx.x;
  const int n = blockIdx.x;
  const float* ar = attn + (long)n * 4096;
  #pragma unroll
  for (int k = 0; k < 16; k++) row[k*256 + t] = ar[k*256 + t];
  __syncthreads();
  float t0=-INFINITY,t1=-INFINITY,t2=-INFINITY,t3=-INFINITY,t4=-INFINITY;
  #pragma unroll
  for (int k = 0; k < 16; k++) {
    float v = row[k*256 + t];
    if (v > t4) {
      if (v > t0)      { t4=t3; t3=t2; t2=t1; t1=t0; t0=v; }
      else if (v > t1) { t4=t3; t3=t2; t2=t1; t1=v; }
      else if (v > t2) { t4=t3; t3=t2; t2=v; }
      else if (v > t3) { t4=t3; t3=v; }
      else             { t4=v; }
    }
  }
  top5[t*5+0]=t0; top5[t*5+1]=t1; top5[t*5+2]=t2; top5[t*5+3]=t3; top5[t*5+4]=t4;
  __syncthreads();
  for (int s = 128; s >= 1; s >>= 1) {
    if (t < s) {
      float* A = &top5[t*5];
      const float* B = &top5[(t+s)*5];
      float m[5]; int i = 0, j = 0;
      #pragma unroll
      for (int k = 0; k < 5; k++) {
        float av = A[i], bv = B[j];
        if (av >= bv) { m[k] = av; i++; } else { m[k] = bv; j++; }
      }
      #pragma unroll
      for (int k = 0; k < 5; k++) A[k] = m[k];
    }
    __syncthreads();
  }
  const float kth = top5[4];
  const int y = n >> 6, x = n & 63;
  int myc = 0;
  float wmax = -INFINITY;
  #pragma unroll
  for (int k = 0; k < 16; k++) {
    int m = k*256 + t;
    float a = row[m];
    int c = ((a >= kth) ? 1 : 0) +
            (((iabs_(y - (m >> 6)) + iabs_(x - (m & 63))) <= 4) ? 1 : 0);
    float wv = a * (float)c;
    if (wv != 0.0f) { myc++; wmax = fmaxf(wmax, wv); }
  }
  scan[t] = myc;
  __syncthreads();
  for (int s = 1; s < 256; s <<= 1) {
    int v = (t >= s) ? scan[t-s] : 0;
    __syncthreads();
    scan[t] += v;
    __syncthreads();
  }
  const int base = scan[t] - myc;
  const int cnt = scan[255];
  {
    int idx = base;
    #pragma unroll
    for (int k = 0; k < 16; k++) {
      int m = k*256 + t;
      float a = row[m];
      int c = ((a >= kth) ? 1 : 0) +
              (((iabs_(y - (m >> 6)) + iabs_(x - (m & 63))) <= 4) ? 1 : 0);
      float wv = a * (float)c;
      if (wv != 0.0f) { lm[idx] = m; lw[idx] = wv; idx++; }
    }
  }
  #pragma unroll
  for (int s = 1; s < 64; s <<= 1) wmax = fmaxf(wmax, __shfl_xor(wmax, s, 64));
  if ((t & 63) == 0) redf[t >> 6] = wmax;
  __syncthreads();
  const float gmax = fmaxf(fmaxf(redf[0], redf[1]), fmaxf(redf[2], redf[3]));
  __syncthreads();
  float ps = 0.f;
  for (int i = t; i < cnt; i += 256) ps += expf(lw[i] - gmax);
  #pragma unroll
  for (int s = 1; s < 64; s <<= 1) ps += __shfl_xor(ps, s, 64);
  if ((t & 63) == 0) redf[4 + (t >> 6)] = ps;
  __syncthreads();
  const float S = redf[4] + redf[5] + redf[6] + redf[7];
  const float invS = 1.0f / S;
  float a0=0,a1=0,a2=0,a3=0,a4=0,a5=0;
  for (int e = 0; e < cnt; e++) {
    float se = expf(lw[e] - gmax) * invS;
    const float* vr = vs + (long)lm[e] * 1536;
    a0 = fmaf(se, vr[          t], a0);
    a1 = fmaf(se, vr[ 256 + t], a1);
    a2 = fmaf(se, vr[ 512 + t], a2);
    a3 = fmaf(se, vr[ 768 + t], a3);
    a4 = fmaf(se, vr[1024 + t], a4);
    a5 = fmaf(se, vr[1280 + t], a5);
  }
  float* orow = outr + (long)n * 1536;
  orow[          t] = a0;
  orow[ 256 + t] = a1;
  orow[ 512 + t] = a2;
  orow[ 768 + t] = a3;
  orow[1024 + t] = a4;
  orow[1280 + t] = a5;
}

// ---------------- per-channel l2 norm over 65536 (fhr q2/k2) ----------------
__global__ __launch_bounds__(1024) void l2n_sp(
    const float* __restrict__ in, float* __restrict__ out)
{
  const int ch = blockIdx.x, b = blockIdx.y, t = threadIdx.x;
  const float* ip = in + ((long)b*96 + ch) * HW;
  float ss = 0.f;
  for (int i = t; i < 65536; i += 1024) { float v = ip[i]; ss = fmaf(v, v, ss); }
  __shared__ float red[16];
  #pragma unroll
  for (int s = 1; s < 64; s <<= 1) ss += __shfl_xor(ss, s, 64);
  if ((t & 63) == 0) red[t >> 6] = ss;
  __syncthreads();
  if (t == 0) {
    float s2 = 0.f;
    for (int i = 0; i < 16; i++) s2 += red[i];
    red[0] = fmaxf(sqrtf(s2), 1e-12f);
  }
  __syncthreads();
  const float nrm = red[0];
  float* op = out + ((long)b*96 + ch) * HW;
  for (int i = t; i < 65536; i += 1024) op[i] = ip[i] / nrm;
}

// -------- a2 stage 1: partial Gram (12x12) over 4096-elem chunks ------------
#define A2_NCH 16
__global__ __launch_bounds__(256) void a2_part(
    const float* __restrict__ q2n, const float* __restrict__ k2n,
    float* __restrict__ part)
{
  __shared__ float sh[24*260];
  const int t = threadIdx.x;
  const int ch = blockIdx.x, h = blockIdx.y, b = blockIdx.z;
  const long base = ((long)b*96 + h*12) * HW + ch*4096;
  const int c = t / 12, d = t - (t/12)*12;   // valid for t<144
  float acc = 0.f;
  for (int sub = 0; sub < 16; sub++) {
    __syncthreads();
    #pragma unroll
    for (int j = 0; j < 6; j++) {
      const int v = j*256 + t;          // 0..1535
      const int row = v >> 6;           // 0..23
      const int col4 = v & 63;
      const float* src = (row < 12)
        ? q2n + base + (long)row*HW + sub*256 + col4*4
        : k2n + base + (long)(row-12)*HW + sub*256 + col4*4;
      *(float4*)&sh[row*260 + col4*4] = *(const float4*)src;
    }
    __syncthreads();
    if (t < 144) {
      const float* qr = &sh[c*260];
      const float* kr = &sh[(12+d)*260];
      #pragma unroll
      for (int i4 = 0; i4 < 64; i4++) {
        float4 qv = *(const float4*)&qr[i4*4];
        float4 kv = *(const float4*)&kr[i4*4];
        acc = fmaf(qv.x, kv.x, acc);
        acc = fmaf(qv.y, kv.y, acc);
        acc = fmaf(qv.z, kv.z, acc);
        acc = fmaf(qv.w, kv.w, acc);
      }
    }
  }
  if (t < 144)
    part[(((long)b*8 + h)*A2_NCH + ch)*144 + t] = acc;
}

// -------- a2 stage 2: deterministic reduce + temp scale + softmax(12) -------
__global__ __launch_bounds__(256) void a2_fin(
    const float* __restrict__ part, const float* __restrict__ temp,
    float* __restrict__ a2s)
{
  __shared__ float m[144];
  const int t = threadIdx.x;
  const int h = blockIdx.x, b = blockIdx.y;
  if (t < 144) {
    float s = 0.f;
    const float* pp = part + (((long)b*8 + h)*A2_NCH)*144 + t;
    #pragma unroll
    for (int ch = 0; ch < A2_NCH; ch++) s += pp[ch*144];
    m[t] = s * temp[h];
  }
  __syncthreads();
  if (t < 12) {
    float mx = -INFINITY;
    #pragma unroll
    for (int d = 0; d < 12; d++) mx = fmaxf(mx, m[t*12+d]);
    float e[12], sum = 0.f;
    #pragma unroll
    for (int d = 0; d < 12; d++) { e[d] = expf(m[t*12+d]-mx); sum += e[d]; }
    float inv = 1.0f/sum;
    float* op = a2s + (((long)b*8 + h)*12 + t)*12;
    #pragma unroll
    for (int d = 0; d < 12; d++) op[d] = e[d]*inv;
  }
}

// ---------------- o2pre = a2 @ v2 ----------------
__global__ __launch_bounds__(256) void o2pre_kern(
    const float* __restrict__ a2s, const float* __restrict__ v2,
    float* __restrict__ o2p)
{
  const int t = threadIdx.x;
  const int n = blockIdx.x * 256 + t;
  const int bh = blockIdx.y, b = bh >> 3, h = bh & 7;
  const float* a = a2s + (long)bh * 144;
  const float* vb = v2 + ((long)b*96 + h*12) * HW;
  float vv[12];
  #pragma unroll
  for (int d = 0; d < 12; d++) vv[d] = vb[(long)d*HW + n];
  float* ob = o2p + ((long)b*96 + h*12) * HW;
  #pragma unroll
  for (int c = 0; c < 12; c++) {
    float s = 0.f;
    #pragma unroll
    for (int d = 0; d < 12; d++) s = fmaf(a[c*12 + d], vv[d], s);
    ob[(long)c*HW + n] = s;
  }
}

extern "C" void kernel_launch(void* const* d_in, const int* in_sizes, int n_in,
                              void* d_out, int out_size, void* d_ws, size_t ws_size,
                              hipStream_t stream) {
  const float* x        = (const float*)d_in[0];
  const float* qk_w     = (const float*)d_in[1];
  const float* qk_dw    = (const float*)d_in[2];
  const float* v_w      = (const float*)d_in[3];
  const float* v_dw     = (const float*)d_in[4];
  const float* k2_w     = (const float*)d_in[5];
  const float* k2_dw    = (const float*)d_in[6];
  const float* q2_w     = (const float*)d_in[7];
  const float* q2_dw    = (const float*)d_in[8];
  const float* proj_w   = (const float*)d_in[9];
  const float* sab_temp = (const float*)d_in[10];
  const float* fqkv_w   = (const float*)d_in[11];
  const float* fqkv_dw  = (const float*)d_in[12];
  const float* fproj_w  = (const float*)d_in[13];
  const float* fhr_temp = (const float*)d_in[14];
  float* out = (float*)d_out;
  float* ws  = (float*)d_ws;

  // d_out regions (floats)
  float* O2  = out;               // (2,96,256,256)
  float* KS  = out + 12582912;    // (2,1,1,4096,192)  = normalized k
  float* VS  = out + 14155776;    // (2,1,1,4096,1536) = permuted v
  float* K2N = out + 26738688;    // (2,8,12,65536)    = normalized k2
  float* V2  = out + 39321600;    // (2,8,12,65536)    = raw v2

  // ws arena (floats)
  float* A0   = ws;                // 25165824 (attn uses first 16777216)
  float* A1   = ws + 25165824;     // 25165824
  float* QD   = ws + 50331648;     // 1572864
  float* KD   = ws + 51904512;     // 1572864
  float* QN   = ws + 53477376;     // 1572864  (also hosts WHL outside steps 9-11)
  float* A2S  = ws + 55050240;     // 2304
  float* PART = ws + 55052544;     // 36864
  unsigned short* QSP = (unsigned short*)(A0 + 16777216);  // 4096*384 ushort
  unsigned short* KSP = (unsigned short*)(A0 + 16777216 + 786432);
  unsigned short* WHL = (unsigned short*)QN;

  dim3 b256(256), b1024(1024);

  // 0) split all 1x1 conv weights to bf16 hi/lo
  wsplit<<<dim3(432), b256, 0, stream>>>(qk_w, v_w, q2_w, k2_w, proj_w, fqkv_w, fproj_w, WHL);
  // 1) y1_qk = 1x1(x, qk_w) -> A0 (2,192,HW)
  conv1x1_mfma<<<dim3(512,2), b256, 0, stream>>>(x, 96L*HW, WHL, 0, A0, 192L*HW, 12, 0);
  // 2) qk = dw3x3(y1_qk) -> A1 (2,192,HW); q=ch[0:96), k=ch[96:192)
  dw3x3v<<<dim3(64,192,2), b256, 0, stream>>>(A0, qk_dw, A1, 192);
  // 3) y1_v = 1x1(x, v_w) -> A0 (2,96,HW)
  conv1x1_mfma<<<dim3(512,2), b256, 0, stream>>>(x, 96L*HW, WHL, 192, A0, 96L*HW, 6, 0);
  // 4) v_s = permute(dw3x3(y1_v)) -> d_out
  dw3x3_vs<<<dim3(1024,2), b256, 0, stream>>>(A0, v_dw, VS);
  // 5) q2pre = 1x1(q, q2_w) -> A0 (2,192,HW)
  conv1x1_mfma<<<dim3(512,2), b256, 0, stream>>>(A1, 192L*HW, WHL, 288, A0, 192L*HW, 12, 0);
  // 6) qd = dw4x4s4(q2pre)
  dw4x4s4<<<dim3(16,192,2), b256, 0, stream>>>(A0, q2_dw, QD);
  // 7) k2pre = 1x1(k, k2_w) -> A0
  conv1x1_mfma<<<dim3(512,2), b256, 0, stream>>>(A1 + 96L*HW, 192L*HW, WHL, 480, A0, 192L*HW, 12, 0);
  // 8) kd = dw4x4s4(k2pre)
  dw4x4s4<<<dim3(16,192,2), b256, 0, stream>>>(A0, k2_dw, KD);
  // 9/10) l2norm + transpose -> qn (ws, clobbers WHL), kn (d_out k_s)
  l2n192<<<dim3(2048), b256, 0, stream>>>(QD, QN);
  l2n192<<<dim3(2048), b256, 0, stream>>>(KD, KS);
  // 11) attention, per batch (attn materialized in A0[0:16.7M])
  for (int b = 0; b < 2; b++) {
    bf16split<<<dim3(3072), b256, 0, stream>>>(QN + (long)b*786432, QSP);
    bf16split<<<dim3(3072), b256, 0, stream>>>(KS + (long)b*786432, KSP);
    attn_qk_mfma<<<dim3(32,32), b256, 0, stream>>>(QSP, KSP, A0, sab_temp);
    attn_out_k<<<dim3(4096), b256, 0, stream>>>(
        A0, VS + (long)b*6291456, A1 + (long)b*6291456);
  }
  // re-split weights (QN slot was clobbered by step 9)
  wsplit<<<dim3(432), b256, 0, stream>>>(qk_w, v_w, q2_w, k2_w, proj_w, fqkv_w, fproj_w, WHL);
  // 12) aligned = 1x1(permuted attn-out, proj_w) -> A0[0:12.58M]
  conv1x1_mfma<<<dim3(512,2), b256, 0, stream>>>(A1, 6291456L, WHL, 672, A0, 96L*HW, 6, 1);
  // 13-15) fhr qkv: three sequential 96-ch paths
  float* PRE  = A0 + 12582912;
  float* DW1  = A1 + 12582912;
  float* Q2NB = A1;
  // q2
  conv1x1_mfma<<<dim3(512,2), b256, 0, stream>>>(A0, 96L*HW, WHL, 768, PRE, 96L*HW, 6, 0);
  dw3x3v<<<dim3(64,96,2), b256, 0, stream>>>(PRE, fqkv_dw,        DW1, 96);
  l2n_sp<<<dim3(96,2), b1024, 0, stream>>>(DW1, Q2NB);
  // k2
  conv1x1_mfma<<<dim3(512,2), b256, 0, stream>>>(A0, 96L*HW, WHL, 864, PRE, 96L*HW, 6, 0);
  dw3x3v<<<dim3(64,96,2), b256, 0, stream>>>(PRE, fqkv_dw +  864, DW1, 96);
  l2n_sp<<<dim3(96,2), b1024, 0, stream>>>(DW1, K2N);
  // v2 (raw dw output is the v2 output layout directly)
  conv1x1_mfma<<<dim3(512,2), b256, 0, stream>>>(A0, 96L*HW, WHL, 960, PRE, 96L*HW, 6, 0);
  dw3x3v<<<dim3(64,96,2), b256, 0, stream>>>(PRE, fqkv_dw + 1728, V2, 96);
  // 16) a2 = softmax(q2n.k2n^T * fhr_temp), two-stage deterministic
  a2_part<<<dim3(A2_NCH,8,2), b256, 0, stream>>>(Q2NB, K2N, PART);
  a2_fin<<<dim3(8,2), b256, 0, stream>>>(PART, fhr_temp, A2S);
  // 17) o2pre = a2 @ v2 -> A0
  o2pre_kern<<<dim3(256,16), b256, 0, stream>>>(A2S, V2, A0);
  // 18) o2 = 1x1(o2pre, fproj_w) -> d_out
  conv1x1_mfma<<<dim3(512,2), b256, 0, stream>>>(A0, 96L*HW, WHL, 1056, O2, 96L*HW, 6, 0);
}

// Round 9
// 1007.668 us; speedup vs baseline: 1.9082x; 1.0981x over previous
//
#include <hip/hip_runtime.h>
#include <hip/hip_bf16.h>
#include <math.h>

#define HW 65536L

typedef __attribute__((ext_vector_type(8))) short bf16x8;
typedef __attribute__((ext_vector_type(4))) float f32x4;

__device__ __forceinline__ int iabs_(int v) { return v < 0 ? -v : v; }

// ---- split all 1x1 weights into (hi,lo) bf16 planes: whl[2][1152][96] ----
__global__ __launch_bounds__(256) void wsplit(
    const float* __restrict__ qk, const float* __restrict__ v,
    const float* __restrict__ q2, const float* __restrict__ k2,
    const float* __restrict__ pj, const float* __restrict__ fq,
    const float* __restrict__ fp, unsigned short* __restrict__ whl)
{
  const int e = blockIdx.x*256 + threadIdx.x;
  if (e >= 110592) return;
  const int row = e / 96, col = e - row*96;
  float f;
  if      (row <  192) f = qk[e];
  else if (row <  288) f = v [(row-192)*96+col];
  else if (row <  480) f = q2[(row-288)*96+col];
  else if (row <  672) f = k2[(row-480)*96+col];
  else if (row <  768) f = pj[(row-672)*96+col];
  else if (row < 1056) f = fq[(row-768)*96+col];
  else                 f = fp[(row-1056)*96+col];
  __hip_bfloat16 h = __float2bfloat16(f);
  float hf = __bfloat162float(h);
  __hip_bfloat16 l = __float2bfloat16(f - hf);
  whl[e]          = *(unsigned short*)&h;
  whl[110592 + e] = *(unsigned short*)&l;
}

// ---------------- conv 1x1 via split-bf16 MFMA ----------------
#define BLDS 104
__global__ __launch_bounds__(256) void conv1x1_mfma(
    const float* __restrict__ in, long in_bstride,
    const unsigned short* __restrict__ whl, int wrow0,
    float* __restrict__ out, long out_bstride,
    int mtiles, int mode)
{
  __shared__ unsigned short bhs[128*BLDS];
  __shared__ unsigned short bls[128*BLDS];
  const int t = threadIdx.x;
  const int p0 = blockIdx.x * 128;
  const int b = blockIdx.y;
  if (mode == 0) {
    #pragma unroll
    for (int it = 0; it < 48; it++) {
      const int idx = it*256 + t;
      const int c = idx >> 7, pix = idx & 127;
      float f = in[(long)b*in_bstride + (long)c*HW + p0 + pix];
      __hip_bfloat16 h = __float2bfloat16(f);
      float hf = __bfloat162float(h);
      __hip_bfloat16 l = __float2bfloat16(f - hf);
      bhs[pix*BLDS + c] = *(unsigned short*)&h;
      bls[pix*BLDS + c] = *(unsigned short*)&l;
    }
  } else {
    const int pp = t >> 1, half = (t & 1)*48;
    const int p = p0 + pp;
    const int py = p >> 8, px = p & 255;
    const float* src = in + (long)b*in_bstride
        + ((long)((py & 63)*64 + (px & 63))*16 + ((py >> 6)*4 + (px >> 6)))*96 + half;
    #pragma unroll
    for (int j4 = 0; j4 < 12; j4++) {
      float4 v4 = *(const float4*)&src[j4*4];
      float fv[4] = {v4.x, v4.y, v4.z, v4.w};
      #pragma unroll
      for (int u = 0; u < 4; u++) {
        __hip_bfloat16 h = __float2bfloat16(fv[u]);
        float hf = __bfloat162float(h);
        __hip_bfloat16 l = __float2bfloat16(fv[u] - hf);
        bhs[pp*BLDS + half + j4*4 + u] = *(unsigned short*)&h;
        bls[pp*BLDS + half + j4*4 + u] = *(unsigned short*)&l;
      }
    }
  }
  __syncthreads();
  const int lane = t & 63, w = t >> 6;
  const int fr = lane & 15, fk = lane >> 4;
  bf16x8 Bh[2][3], Bl[2][3];
  #pragma unroll
  for (int nt = 0; nt < 2; nt++)
    #pragma unroll
    for (int kt = 0; kt < 3; kt++) {
      const int pix = w*32 + nt*16 + fr;
      Bh[nt][kt] = *(const bf16x8*)(bhs + pix*BLDS + kt*32 + fk*8);
      Bl[nt][kt] = *(const bf16x8*)(bls + pix*BLDS + kt*32 + fk*8);
    }
  float* dst = out + (long)b*out_bstride + p0 + w*32;
  for (int m = 0; m < mtiles; m++) {
    const long wbase = (long)(wrow0 + m*16 + fr)*96 + fk*8;
    bf16x8 Ah[3], Al[3];
    #pragma unroll
    for (int kt = 0; kt < 3; kt++) {
      Ah[kt] = *(const bf16x8*)(whl + wbase + kt*32);
      Al[kt] = *(const bf16x8*)(whl + 110592 + wbase + kt*32);
    }
    f32x4 acc[2] = {};
    #pragma unroll
    for (int nt = 0; nt < 2; nt++)
      #pragma unroll
      for (int kt = 0; kt < 3; kt++) {
        acc[nt] = __builtin_amdgcn_mfma_f32_16x16x32_bf16(Ah[kt], Bh[nt][kt], acc[nt], 0, 0, 0);
        acc[nt] = __builtin_amdgcn_mfma_f32_16x16x32_bf16(Ah[kt], Bl[nt][kt], acc[nt], 0, 0, 0);
        acc[nt] = __builtin_amdgcn_mfma_f32_16x16x32_bf16(Al[kt], Bh[nt][kt], acc[nt], 0, 0, 0);
      }
    #pragma unroll
    for (int nt = 0; nt < 2; nt++)
      #pragma unroll
      for (int r = 0; r < 4; r++)
        dst[(long)(m*16 + fk*4 + r)*HW + nt*16 + fr] = acc[nt][r];
  }
}

// -------- depthwise 3x3 pad 1, 4-wide vectorized --------
__global__ __launch_bounds__(256) void dw3x3v(
    const float* __restrict__ in, const float* __restrict__ w,
    float* __restrict__ out, int CH)
{
  const int t = threadIdx.x;
  const int p4 = blockIdx.x * 256 + t;
  const int ch = blockIdx.y, b = blockIdx.z;
  const int y = p4 >> 6, x0 = (p4 & 63) << 2;
  const float* ip = in + (long)(b*CH + ch) * HW;
  const float* wp = w + ch*9;
  float a0 = 0.f, a1 = 0.f, a2 = 0.f, a3 = 0.f;
  #pragma unroll
  for (int dy = -1; dy <= 1; dy++) {
    const int yy = y + dy;
    if (yy < 0 || yy > 255) continue;
    const float* rp = ip + yy*256;
    const float4 c = *(const float4*)&rp[x0];
    const float left  = (x0 > 0)   ? rp[x0-1] : 0.f;
    const float right = (x0 < 252) ? rp[x0+4] : 0.f;
    const float w0 = wp[(dy+1)*3+0], w1 = wp[(dy+1)*3+1], w2 = wp[(dy+1)*3+2];
    a0 = fmaf(left, w0, a0); a0 = fmaf(c.x, w1, a0); a0 = fmaf(c.y, w2, a0);
    a1 = fmaf(c.x,  w0, a1); a1 = fmaf(c.y, w1, a1); a1 = fmaf(c.z, w2, a1);
    a2 = fmaf(c.y,  w0, a2); a2 = fmaf(c.z, w1, a2); a2 = fmaf(c.w, w2, a2);
    a3 = fmaf(c.z,  w0, a3); a3 = fmaf(c.w, w1, a3); a3 = fmaf(right, w2, a3);
  }
  float4 o; o.x = a0; o.y = a1; o.z = a2; o.w = a3;
  *(float4*)&out[(long)(b*CH + ch)*HW + y*256 + x0] = o;
}

// ------- depthwise 3x3 fused with v_s permutation (coalesced, LDS reorder) ----
__global__ __launch_bounds__(256) void dw3x3_vs(
    const float* __restrict__ in, const float* __restrict__ w,
    float* __restrict__ vs)
{
  __shared__ float tile[96*65];
  const int t = threadIdx.x;
  const int gb = blockIdx.x;
  const int b = blockIdx.y;
  const int y = gb >> 2, xb = gb & 3;
  const int x0 = xb * 64;
  #pragma unroll
  for (int i = 0; i < 24; i++) {
    const int idx = i*256 + t;
    const int ci = idx >> 6, xl = idx & 63;
    const float* ip = in + ((long)b*96 + ci) * HW;
    const float* wp = w + ci*9;
    const int x = x0 + xl;
    float acc = 0.f;
    #pragma unroll
    for (int dy = -1; dy <= 1; dy++) {
      const int yy = y + dy;
      if (yy < 0 || yy > 255) continue;
      const float* rp = ip + yy*256;
      #pragma unroll
      for (int dx = -1; dx <= 1; dx++) {
        const int xx = x + dx;
        if (xx < 0 || xx > 255) continue;
        acc = fmaf(rp[xx], wp[(dy+1)*3 + (dx+1)], acc);
      }
    }
    tile[ci*65 + xl] = acc;
  }
  __syncthreads();
  const int blk = (y >> 6)*4 + xb;
  float* obase = vs + ((long)b*4096 + (long)(y & 63)*64) * 1536 + blk*96;
  #pragma unroll
  for (int i = 0; i < 24; i++) {
    const int idx = i*256 + t;
    const int nl = idx / 96, ci = idx % 96;
    obase[(long)nl*1536 + ci] = tile[ci*65 + nl];
  }
}

// ---------------- depthwise 4x4 stride 4 pad 1 (256->64) ----------------
__global__ __launch_bounds__(256) void dw4x4s4(
    const float* __restrict__ in, const float* __restrict__ w,
    float* __restrict__ out)
{
  const int t = threadIdx.x;
  const int op = blockIdx.x * 256 + t;
  const int ch = blockIdx.y, b = blockIdx.z;
  const int oy = op >> 6, ox = op & 63;
  const float* ip = in + (long)(b*192 + ch) * HW;
  const float* wp = w + ch*16;
  float acc = 0.f;
  #pragma unroll
  for (int ty = 0; ty < 4; ty++) {
    int iy = 4*oy + ty - 1;
    if (iy < 0 || iy > 255) continue;
    #pragma unroll
    for (int tx = 0; tx < 4; tx++) {
      int ix = 4*ox + tx - 1;
      if (ix < 0 || ix > 255) continue;
      acc = fmaf(ip[iy*256 + ix], wp[ty*4 + tx], acc);
    }
  }
  out[(long)(b*192 + ch) * 4096 + op] = acc;
}

// ---------------- l2 norm over 192 channels + transpose to (B,4096,192) ----
__global__ __launch_bounds__(256) void l2n192(
    const float* __restrict__ in, float* __restrict__ out)
{
  const int t = threadIdx.x;
  const int wid = t >> 6, lane = t & 63;
  const int gw = blockIdx.x * 4 + wid;
  const int b = gw >> 12, n = gw & 4095;
  const float* ip = in + (long)b * 786432;
  float v0 = ip[(long)(lane      ) * 4096 + n];
  float v1 = ip[(long)(lane +  64) * 4096 + n];
  float v2 = ip[(long)(lane + 128) * 4096 + n];
  float ss = v0*v0 + v1*v1 + v2*v2;
  #pragma unroll
  for (int s = 1; s < 64; s <<= 1) ss += __shfl_xor(ss, s, 64);
  float nrm = fmaxf(sqrtf(ss), 1e-12f);
  float* op = out + ((long)b*4096 + n) * 192;
  op[lane      ] = v0 / nrm;
  op[lane +  64] = v1 / nrm;
  op[lane + 128] = v2 / nrm;
}

// ---------------- split fp32 -> (hi,lo) bf16 planes ----------------
__global__ __launch_bounds__(256) void bf16split(
    const float* __restrict__ in, unsigned short* __restrict__ outp)
{
  const int i = blockIdx.x * 256 + threadIdx.x;
  const int n = i / 192, k = i % 192;
  float f = in[i];
  __hip_bfloat16 h = __float2bfloat16(f);
  float hf = __bfloat162float(h);
  __hip_bfloat16 l = __float2bfloat16(f - hf);
  outp[(long)n*384 + k]       = *(unsigned short*)&h;
  outp[(long)n*384 + 192 + k] = *(unsigned short*)&l;
}

// ---------------- attention QK^T via split-bf16 MFMA (one batch) ------------
#define LDSROW 40
__global__ __launch_bounds__(256) void attn_qk_mfma(
    const unsigned short* __restrict__ Qsp, const unsigned short* __restrict__ Ksp,
    float* __restrict__ attn, const float* __restrict__ tp)
{
  __shared__ unsigned short qs[256*LDSROW];
  __shared__ unsigned short ks[256*LDSROW];
  const int t = threadIdx.x;
  const int lane = t & 63, w = t >> 6;
  const int n0 = blockIdx.x * 128;
  const int m0 = blockIdx.y * 128;
  const int wr = (w >> 1) * 64, wc = (w & 1) * 64;
  f32x4 acc[4][4] = {};
  const int srow = t & 127;
  const int shl  = t >> 7;
  const unsigned short* qsrc = Qsp + (long)(n0 + srow) * 384 + shl * 192;
  const unsigned short* ksrc = Ksp + (long)(m0 + srow) * 384 + shl * 192;
  unsigned short* qdst = qs + (shl*128 + srow) * LDSROW;
  unsigned short* kdst = ks + (shl*128 + srow) * LDSROW;
  const int fr = lane & 15;
  const int fk = lane >> 4;
  for (int s = 0; s < 6; s++) {
    __syncthreads();
    #pragma unroll
    for (int j = 0; j < 4; j++) {
      *(bf16x8*)(qdst + j*8) = *(const bf16x8*)(qsrc + s*32 + j*8);
      *(bf16x8*)(kdst + j*8) = *(const bf16x8*)(ksrc + s*32 + j*8);
    }
    __syncthreads();
    bf16x8 ah[4], al[4], bh[4], bl[4];
    #pragma unroll
    for (int i = 0; i < 4; i++) {
      ah[i] = *(const bf16x8*)(qs + (      wr + i*16 + fr) * LDSROW + fk*8);
      al[i] = *(const bf16x8*)(qs + (128 + wr + i*16 + fr) * LDSROW + fk*8);
      bh[i] = *(const bf16x8*)(ks + (      wc + i*16 + fr) * LDSROW + fk*8);
      bl[i] = *(const bf16x8*)(ks + (128 + wc + i*16 + fr) * LDSROW + fk*8);
    }
    #pragma unroll
    for (int i = 0; i < 4; i++)
      #pragma unroll
      for (int j = 0; j < 4; j++) {
        acc[i][j] = __builtin_amdgcn_mfma_f32_16x16x32_bf16(ah[i], bh[j], acc[i][j], 0, 0, 0);
        acc[i][j] = __builtin_amdgcn_mfma_f32_16x16x32_bf16(ah[i], bl[j], acc[i][j], 0, 0, 0);
        acc[i][j] = __builtin_amdgcn_mfma_f32_16x16x32_bf16(al[i], bh[j], acc[i][j], 0, 0, 0);
      }
  }
  const float temp = tp[0];
  #pragma unroll
  for (int i = 0; i < 4; i++)
    #pragma unroll
    for (int j = 0; j < 4; j++)
      #pragma unroll
      for (int r = 0; r < 4; r++) {
        const int nn = n0 + wr + i*16 + (lane >> 4)*4 + r;
        const int mm = m0 + wc + j*16 + (lane & 15);
        attn[(long)nn*4096 + mm] = acc[i][j][r] * temp;
      }
}

// ------- top-5 + local mask + softmax + sparse out (R8: small LDS, shared se) -
#define CAP 128
__global__ __launch_bounds__(256) void attn_out_k(
    const float* __restrict__ attn, const float* __restrict__ vs,
    float* __restrict__ outr)
{
  __shared__ float row[4096];
  __shared__ float top5[256*5];
  __shared__ int   lm[CAP];
  __shared__ float lw[CAP];
  __shared__ float ses[CAP];
  __shared__ float redf[8];
  __shared__ int   scan[256];
  const int t = threadIdx.x;
  const int n = blockIdx.x;
  const float* ar = attn + (long)n * 4096;
  #pragma unroll
  for (int k = 0; k < 16; k++) row[k*256 + t] = ar[k*256 + t];
  __syncthreads();
  float t0=-INFINITY,t1=-INFINITY,t2=-INFINITY,t3=-INFINITY,t4=-INFINITY;
  #pragma unroll
  for (int k = 0; k < 16; k++) {
    float v = row[k*256 + t];
    if (v > t4) {
      if (v > t0)      { t4=t3; t3=t2; t2=t1; t1=t0; t0=v; }
      else if (v > t1) { t4=t3; t3=t2; t2=t1; t1=v; }
      else if (v > t2) { t4=t3; t3=t2; t2=v; }
      else if (v > t3) { t4=t3; t3=v; }
      else             { t4=v; }
    }
  }
  top5[t*5+0]=t0; top5[t*5+1]=t1; top5[t*5+2]=t2; top5[t*5+3]=t3; top5[t*5+4]=t4;
  __syncthreads();
  for (int s = 128; s >= 1; s >>= 1) {
    if (t < s) {
      float* A = &top5[t*5];
      const float* B = &top5[(t+s)*5];
      float m[5]; int i = 0, j = 0;
      #pragma unroll
      for (int k = 0; k < 5; k++) {
        float av = A[i], bv = B[j];
        if (av >= bv) { m[k] = av; i++; } else { m[k] = bv; j++; }
      }
      #pragma unroll
      for (int k = 0; k < 5; k++) A[k] = m[k];
    }
    __syncthreads();
  }
  const float kth = top5[4];
  const int y = n >> 6, x = n & 63;
  int myc = 0;
  float wmax = -INFINITY;
  #pragma unroll
  for (int k = 0; k < 16; k++) {
    int m = k*256 + t;
    float a = row[m];
    int c = ((a >= kth) ? 1 : 0) +
            (((iabs_(y - (m >> 6)) + iabs_(x - (m & 63))) <= 4) ? 1 : 0);
    float wv = a * (float)c;
    if (wv != 0.0f) { myc++; wmax = fmaxf(wmax, wv); }
  }
  scan[t] = myc;
  __syncthreads();
  for (int s = 1; s < 256; s <<= 1) {
    int v = (t >= s) ? scan[t-s] : 0;
    __syncthreads();
    scan[t] += v;
    __syncthreads();
  }
  const int base = scan[t] - myc;
  const int cnt = scan[255];
  {
    int idx = base;
    #pragma unroll
    for (int k = 0; k < 16; k++) {
      int m = k*256 + t;
      float a = row[m];
      int c = ((a >= kth) ? 1 : 0) +
              (((iabs_(y - (m >> 6)) + iabs_(x - (m & 63))) <= 4) ? 1 : 0);
      float wv = a * (float)c;
      if (wv != 0.0f && idx < CAP) { lm[idx] = m; lw[idx] = wv; idx++; }
    }
  }
  // block max of wv
  #pragma unroll
  for (int s = 1; s < 64; s <<= 1) wmax = fmaxf(wmax, __shfl_xor(wmax, s, 64));
  if ((t & 63) == 0) redf[t >> 6] = wmax;
  __syncthreads();
  const float gmax = fmaxf(fmaxf(redf[0], redf[1]), fmaxf(redf[2], redf[3]));
  __syncthreads();
  // exp once, cooperatively
  if (t < cnt && t < CAP) ses[t] = expf(lw[t] - gmax);
  __syncthreads();
  float ps = (t < cnt && t < CAP) ? ses[t] : 0.f;
  #pragma unroll
  for (int s = 1; s < 64; s <<= 1) ps += __shfl_xor(ps, s, 64);
  if ((t & 63) == 0) redf[4 + (t >> 6)] = ps;
  __syncthreads();
  const float S = redf[4] + redf[5] + redf[6] + redf[7];
  const float invS = 1.0f / S;
  float a0=0,a1=0,a2=0,a3=0,a4=0,a5=0;
  const int ecnt = (cnt < CAP) ? cnt : CAP;
  for (int e = 0; e < ecnt; e++) {
    float se = ses[e] * invS;
    const float* vr = vs + (long)lm[e] * 1536;
    a0 = fmaf(se, vr[        t], a0);
    a1 = fmaf(se, vr[ 256 + t], a1);
    a2 = fmaf(se, vr[ 512 + t], a2);
    a3 = fmaf(se, vr[ 768 + t], a3);
    a4 = fmaf(se, vr[1024 + t], a4);
    a5 = fmaf(se, vr[1280 + t], a5);
  }
  float* orow = outr + (long)n * 1536;
  orow[        t] = a0;
  orow[ 256 + t] = a1;
  orow[ 512 + t] = a2;
  orow[ 768 + t] = a3;
  orow[1024 + t] = a4;
  orow[1280 + t] = a5;
}

// ---------------- per-channel l2 norm over 65536 (fhr q2/k2) ----------------
__global__ __launch_bounds__(1024) void l2n_sp(
    const float* __restrict__ in, float* __restrict__ out)
{
  const int ch = blockIdx.x, b = blockIdx.y, t = threadIdx.x;
  const float* ip = in + ((long)b*96 + ch) * HW;
  float ss = 0.f;
  for (int i = t; i < 65536; i += 1024) { float v = ip[i]; ss = fmaf(v, v, ss); }
  __shared__ float red[16];
  #pragma unroll
  for (int s = 1; s < 64; s <<= 1) ss += __shfl_xor(ss, s, 64);
  if ((t & 63) == 0) red[t >> 6] = ss;
  __syncthreads();
  if (t == 0) {
    float s2 = 0.f;
    for (int i = 0; i < 16; i++) s2 += red[i];
    red[0] = fmaxf(sqrtf(s2), 1e-12f);
  }
  __syncthreads();
  const float nrm = red[0];
  float* op = out + ((long)b*96 + ch) * HW;
  for (int i = t; i < 65536; i += 1024) op[i] = ip[i] / nrm;
}

// -------- a2 stage 1: partial Gram (12x12) over 4096-elem chunks ------------
#define A2_NCH 16
__global__ __launch_bounds__(256) void a2_part(
    const float* __restrict__ q2n, const float* __restrict__ k2n,
    float* __restrict__ part)
{
  __shared__ float sh[24*260];
  const int t = threadIdx.x;
  const int ch = blockIdx.x, h = blockIdx.y, b = blockIdx.z;
  const long base = ((long)b*96 + h*12) * HW + ch*4096;
  const int c = t / 12, d = t - (t/12)*12;
  float acc = 0.f;
  for (int sub = 0; sub < 16; sub++) {
    __syncthreads();
    #pragma unroll
    for (int j = 0; j < 6; j++) {
      const int v = j*256 + t;
      const int row = v >> 6;
      const int col4 = v & 63;
      const float* src = (row < 12)
        ? q2n + base + (long)row*HW + sub*256 + col4*4
        : k2n + base + (long)(row-12)*HW + sub*256 + col4*4;
      *(float4*)&sh[row*260 + col4*4] = *(const float4*)src;
    }
    __syncthreads();
    if (t < 144) {
      const float* qr = &sh[c*260];
      const float* kr = &sh[(12+d)*260];
      #pragma unroll
      for (int i4 = 0; i4 < 64; i4++) {
        float4 qv = *(const float4*)&qr[i4*4];
        float4 kv = *(const float4*)&kr[i4*4];
        acc = fmaf(qv.x, kv.x, acc);
        acc = fmaf(qv.y, kv.y, acc);
        acc = fmaf(qv.z, kv.z, acc);
        acc = fmaf(qv.w, kv.w, acc);
      }
    }
  }
  if (t < 144)
    part[(((long)b*8 + h)*A2_NCH + ch)*144 + t] = acc;
}

// -------- a2 stage 2 --------
__global__ __launch_bounds__(256) void a2_fin(
    const float* __restrict__ part, const float* __restrict__ temp,
    float* __restrict__ a2s)
{
  __shared__ float m[144];
  const int t = threadIdx.x;
  const int h = blockIdx.x, b = blockIdx.y;
  if (t < 144) {
    float s = 0.f;
    const float* pp = part + (((long)b*8 + h)*A2_NCH)*144 + t;
    #pragma unroll
    for (int ch = 0; ch < A2_NCH; ch++) s += pp[ch*144];
    m[t] = s * temp[h];
  }
  __syncthreads();
  if (t < 12) {
    float mx = -INFINITY;
    #pragma unroll
    for (int d = 0; d < 12; d++) mx = fmaxf(mx, m[t*12+d]);
    float e[12], sum = 0.f;
    #pragma unroll
    for (int d = 0; d < 12; d++) { e[d] = expf(m[t*12+d]-mx); sum += e[d]; }
    float inv = 1.0f/sum;
    float* op = a2s + (((long)b*8 + h)*12 + t)*12;
    #pragma unroll
    for (int d = 0; d < 12; d++) op[d] = e[d]*inv;
  }
}

// ---------------- o2pre = a2 @ v2 ----------------
__global__ __launch_bounds__(256) void o2pre_kern(
    const float* __restrict__ a2s, const float* __restrict__ v2,
    float* __restrict__ o2p)
{
  const int t = threadIdx.x;
  const int n = blockIdx.x * 256 + t;
  const int bh = blockIdx.y, b = bh >> 3, h = bh & 7;
  const float* a = a2s + (long)bh * 144;
  const float* vb = v2 + ((long)b*96 + h*12) * HW;
  float vv[12];
  #pragma unroll
  for (int d = 0; d < 12; d++) vv[d] = vb[(long)d*HW + n];
  float* ob = o2p + ((long)b*96 + h*12) * HW;
  #pragma unroll
  for (int c = 0; c < 12; c++) {
    float s = 0.f;
    #pragma unroll
    for (int d = 0; d < 12; d++) s = fmaf(a[c*12 + d], vv[d], s);
    ob[(long)c*HW + n] = s;
  }
}

extern "C" void kernel_launch(void* const* d_in, const int* in_sizes, int n_in,
                              void* d_out, int out_size, void* d_ws, size_t ws_size,
                              hipStream_t stream) {
  const float* x        = (const float*)d_in[0];
  const float* qk_w     = (const float*)d_in[1];
  const float* qk_dw    = (const float*)d_in[2];
  const float* v_w      = (const float*)d_in[3];
  const float* v_dw     = (const float*)d_in[4];
  const float* k2_w     = (const float*)d_in[5];
  const float* k2_dw    = (const float*)d_in[6];
  const float* q2_w     = (const float*)d_in[7];
  const float* q2_dw    = (const float*)d_in[8];
  const float* proj_w   = (const float*)d_in[9];
  const float* sab_temp = (const float*)d_in[10];
  const float* fqkv_w   = (const float*)d_in[11];
  const float* fqkv_dw  = (const float*)d_in[12];
  const float* fproj_w  = (const float*)d_in[13];
  const float* fhr_temp = (const float*)d_in[14];
  float* out = (float*)d_out;
  float* ws  = (float*)d_ws;

  float* O2  = out;
  float* KS  = out + 12582912;
  float* VS  = out + 14155776;
  float* K2N = out + 26738688;
  float* V2  = out + 39321600;

  float* A0   = ws;
  float* A1   = ws + 25165824;
  float* QD   = ws + 50331648;
  float* KD   = ws + 51904512;
  float* QN   = ws + 53477376;
  float* A2S  = ws + 55050240;
  float* PART = ws + 55052544;
  unsigned short* QSP = (unsigned short*)(A0 + 16777216);
  unsigned short* KSP = (unsigned short*)(A0 + 16777216 + 786432);
  unsigned short* WHL = (unsigned short*)QN;

  dim3 b256(256), b1024(1024);

  wsplit<<<dim3(432), b256, 0, stream>>>(qk_w, v_w, q2_w, k2_w, proj_w, fqkv_w, fproj_w, WHL);
  conv1x1_mfma<<<dim3(512,2), b256, 0, stream>>>(x, 96L*HW, WHL, 0, A0, 192L*HW, 12, 0);
  dw3x3v<<<dim3(64,192,2), b256, 0, stream>>>(A0, qk_dw, A1, 192);
  conv1x1_mfma<<<dim3(512,2), b256, 0, stream>>>(x, 96L*HW, WHL, 192, A0, 96L*HW, 6, 0);
  dw3x3_vs<<<dim3(1024,2), b256, 0, stream>>>(A0, v_dw, VS);
  conv1x1_mfma<<<dim3(512,2), b256, 0, stream>>>(A1, 192L*HW, WHL, 288, A0, 192L*HW, 12, 0);
  dw4x4s4<<<dim3(16,192,2), b256, 0, stream>>>(A0, q2_dw, QD);
  conv1x1_mfma<<<dim3(512,2), b256, 0, stream>>>(A1 + 96L*HW, 192L*HW, WHL, 480, A0, 192L*HW, 12, 0);
  dw4x4s4<<<dim3(16,192,2), b256, 0, stream>>>(A0, k2_dw, KD);
  l2n192<<<dim3(2048), b256, 0, stream>>>(QD, QN);
  l2n192<<<dim3(2048), b256, 0, stream>>>(KD, KS);
  for (int b = 0; b < 2; b++) {
    bf16split<<<dim3(3072), b256, 0, stream>>>(QN + (long)b*786432, QSP);
    bf16split<<<dim3(3072), b256, 0, stream>>>(KS + (long)b*786432, KSP);
    attn_qk_mfma<<<dim3(32,32), b256, 0, stream>>>(QSP, KSP, A0, sab_temp);
    attn_out_k<<<dim3(4096), b256, 0, stream>>>(
        A0, VS + (long)b*6291456, A1 + (long)b*6291456);
  }
  wsplit<<<dim3(432), b256, 0, stream>>>(qk_w, v_w, q2_w, k2_w, proj_w, fqkv_w, fproj_w, WHL);
  conv1x1_mfma<<<dim3(512,2), b256, 0, stream>>>(A1, 6291456L, WHL, 672, A0, 96L*HW, 6, 1);
  float* PRE  = A0 + 12582912;
  float* DW1  = A1 + 12582912;
  float* Q2NB = A1;
  conv1x1_mfma<<<dim3(512,2), b256, 0, stream>>>(A0, 96L*HW, WHL, 768, PRE, 96L*HW, 6, 0);
  dw3x3v<<<dim3(64,96,2), b256, 0, stream>>>(PRE, fqkv_dw,        DW1, 96);
  l2n_sp<<<dim3(96,2), b1024, 0, stream>>>(DW1, Q2NB);
  conv1x1_mfma<<<dim3(512,2), b256, 0, stream>>>(A0, 96L*HW, WHL, 864, PRE, 96L*HW, 6, 0);
  dw3x3v<<<dim3(64,96,2), b256, 0, stream>>>(PRE, fqkv_dw +  864, DW1, 96);
  l2n_sp<<<dim3(96,2), b1024, 0, stream>>>(DW1, K2N);
  conv1x1_mfma<<<dim3(512,2), b256, 0, stream>>>(A0, 96L*HW, WHL, 960, PRE, 96L*HW, 6, 0);
  dw3x3v<<<dim3(64,96,2), b256, 0, stream>>>(PRE, fqkv_dw + 1728, V2, 96);
  a2_part<<<dim3(A2_NCH,8,2), b256, 0, stream>>>(Q2NB, K2N, PART);
  a2_fin<<<dim3(8,2), b256, 0, stream>>>(PART, fhr_temp, A2S);
  o2pre_kern<<<dim3(256,16), b256, 0, stream>>>(A2S, V2, A0);
  conv1x1_mfma<<<dim3(512,2), b256, 0, stream>>>(A0, 96L*HW, WHL, 1056, O2, 96L*HW, 6, 0);
}

// Round 10
// 918.179 us; speedup vs baseline: 2.0942x; 1.0975x over previous
//
#include <hip/hip_runtime.h>
#include <hip/hip_bf16.h>
#include <math.h>

#define HW 65536L

typedef __attribute__((ext_vector_type(8))) short bf16x8;
typedef __attribute__((ext_vector_type(4))) float f32x4;

__device__ __forceinline__ int iabs_(int v) { return v < 0 ? -v : v; }

// ---- split all 1x1 weights into (hi,lo) bf16 planes: whl[2][1152][96] ----
__global__ __launch_bounds__(256) void wsplit(
    const float* __restrict__ qk, const float* __restrict__ v,
    const float* __restrict__ q2, const float* __restrict__ k2,
    const float* __restrict__ pj, const float* __restrict__ fq,
    const float* __restrict__ fp, unsigned short* __restrict__ whl)
{
  const int e = blockIdx.x*256 + threadIdx.x;
  if (e >= 110592) return;
  const int row = e / 96, col = e - row*96;
  float f;
  if      (row <  192) f = qk[e];
  else if (row <  288) f = v [(row-192)*96+col];
  else if (row <  480) f = q2[(row-288)*96+col];
  else if (row <  672) f = k2[(row-480)*96+col];
  else if (row <  768) f = pj[(row-672)*96+col];
  else if (row < 1056) f = fq[(row-768)*96+col];
  else                 f = fp[(row-1056)*96+col];
  __hip_bfloat16 h = __float2bfloat16(f);
  float hf = __bfloat162float(h);
  __hip_bfloat16 l = __float2bfloat16(f - hf);
  whl[e]          = *(unsigned short*)&h;
  whl[110592 + e] = *(unsigned short*)&l;
}

// ---------------- conv 1x1 via split-bf16 MFMA ----------------
#define BLDS 104
__global__ __launch_bounds__(256) void conv1x1_mfma(
    const float* __restrict__ in, long in_bstride,
    const unsigned short* __restrict__ whl, int wrow0,
    float* __restrict__ out, long out_bstride,
    int mtiles, int mode)
{
  __shared__ unsigned short bhs[128*BLDS];
  __shared__ unsigned short bls[128*BLDS];
  const int t = threadIdx.x;
  const int p0 = blockIdx.x * 128;
  const int b = blockIdx.y;
  if (mode == 0) {
    #pragma unroll
    for (int it = 0; it < 48; it++) {
      const int idx = it*256 + t;
      const int c = idx >> 7, pix = idx & 127;
      float f = in[(long)b*in_bstride + (long)c*HW + p0 + pix];
      __hip_bfloat16 h = __float2bfloat16(f);
      float hf = __bfloat162float(h);
      __hip_bfloat16 l = __float2bfloat16(f - hf);
      bhs[pix*BLDS + c] = *(unsigned short*)&h;
      bls[pix*BLDS + c] = *(unsigned short*)&l;
    }
  } else {
    const int pp = t >> 1, half = (t & 1)*48;
    const int p = p0 + pp;
    const int py = p >> 8, px = p & 255;
    const float* src = in + (long)b*in_bstride
        + ((long)((py & 63)*64 + (px & 63))*16 + ((py >> 6)*4 + (px >> 6)))*96 + half;
    #pragma unroll
    for (int j4 = 0; j4 < 12; j4++) {
      float4 v4 = *(const float4*)&src[j4*4];
      float fv[4] = {v4.x, v4.y, v4.z, v4.w};
      #pragma unroll
      for (int u = 0; u < 4; u++) {
        __hip_bfloat16 h = __float2bfloat16(fv[u]);
        float hf = __bfloat162float(h);
        __hip_bfloat16 l = __float2bfloat16(fv[u] - hf);
        bhs[pp*BLDS + half + j4*4 + u] = *(unsigned short*)&h;
        bls[pp*BLDS + half + j4*4 + u] = *(unsigned short*)&l;
      }
    }
  }
  __syncthreads();
  const int lane = t & 63, w = t >> 6;
  const int fr = lane & 15, fk = lane >> 4;
  bf16x8 Bh[2][3], Bl[2][3];
  #pragma unroll
  for (int nt = 0; nt < 2; nt++)
    #pragma unroll
    for (int kt = 0; kt < 3; kt++) {
      const int pix = w*32 + nt*16 + fr;
      Bh[nt][kt] = *(const bf16x8*)(bhs + pix*BLDS + kt*32 + fk*8);
      Bl[nt][kt] = *(const bf16x8*)(bls + pix*BLDS + kt*32 + fk*8);
    }
  float* dst = out + (long)b*out_bstride + p0 + w*32;
  for (int m = 0; m < mtiles; m++) {
    const long wbase = (long)(wrow0 + m*16 + fr)*96 + fk*8;
    bf16x8 Ah[3], Al[3];
    #pragma unroll
    for (int kt = 0; kt < 3; kt++) {
      Ah[kt] = *(const bf16x8*)(whl + wbase + kt*32);
      Al[kt] = *(const bf16x8*)(whl + 110592 + wbase + kt*32);
    }
    f32x4 acc[2] = {};
    #pragma unroll
    for (int nt = 0; nt < 2; nt++)
      #pragma unroll
      for (int kt = 0; kt < 3; kt++) {
        acc[nt] = __builtin_amdgcn_mfma_f32_16x16x32_bf16(Ah[kt], Bh[nt][kt], acc[nt], 0, 0, 0);
        acc[nt] = __builtin_amdgcn_mfma_f32_16x16x32_bf16(Ah[kt], Bl[nt][kt], acc[nt], 0, 0, 0);
        acc[nt] = __builtin_amdgcn_mfma_f32_16x16x32_bf16(Al[kt], Bh[nt][kt], acc[nt], 0, 0, 0);
      }
    #pragma unroll
    for (int nt = 0; nt < 2; nt++)
      #pragma unroll
      for (int r = 0; r < 4; r++)
        dst[(long)(m*16 + fk*4 + r)*HW + nt*16 + fr] = acc[nt][r];
  }
}

// -------- depthwise 3x3 pad 1, 4-wide vectorized --------
__global__ __launch_bounds__(256) void dw3x3v(
    const float* __restrict__ in, const float* __restrict__ w,
    float* __restrict__ out, int CH)
{
  const int t = threadIdx.x;
  const int p4 = blockIdx.x * 256 + t;
  const int ch = blockIdx.y, b = blockIdx.z;
  const int y = p4 >> 6, x0 = (p4 & 63) << 2;
  const float* ip = in + (long)(b*CH + ch) * HW;
  const float* wp = w + ch*9;
  float a0 = 0.f, a1 = 0.f, a2 = 0.f, a3 = 0.f;
  #pragma unroll
  for (int dy = -1; dy <= 1; dy++) {
    const int yy = y + dy;
    if (yy < 0 || yy > 255) continue;
    const float* rp = ip + yy*256;
    const float4 c = *(const float4*)&rp[x0];
    const float left  = (x0 > 0)   ? rp[x0-1] : 0.f;
    const float right = (x0 < 252) ? rp[x0+4] : 0.f;
    const float w0 = wp[(dy+1)*3+0], w1 = wp[(dy+1)*3+1], w2 = wp[(dy+1)*3+2];
    a0 = fmaf(left, w0, a0); a0 = fmaf(c.x, w1, a0); a0 = fmaf(c.y, w2, a0);
    a1 = fmaf(c.x,  w0, a1); a1 = fmaf(c.y, w1, a1); a1 = fmaf(c.z, w2, a1);
    a2 = fmaf(c.y,  w0, a2); a2 = fmaf(c.z, w1, a2); a2 = fmaf(c.w, w2, a2);
    a3 = fmaf(c.z,  w0, a3); a3 = fmaf(c.w, w1, a3); a3 = fmaf(right, w2, a3);
  }
  float4 o; o.x = a0; o.y = a1; o.z = a2; o.w = a3;
  *(float4*)&out[(long)(b*CH + ch)*HW + y*256 + x0] = o;
}

// ------- depthwise 3x3 fused with v_s permutation (R9: 4-wide compute) ----
// Block = (b, y, xb): 96 ch x 64 px at row y, cols xb*64..+63.
__global__ __launch_bounds__(256) void dw3x3_vs(
    const float* __restrict__ in, const float* __restrict__ w,
    float* __restrict__ vs)
{
  __shared__ float tile[96*65];
  const int t = threadIdx.x;
  const int gb = blockIdx.x;          // 0..1023 = y*4 + xb
  const int b = blockIdx.y;
  const int y = gb >> 2, xb = gb & 3;
  // compute phase: 96 ch x 16 quads = 1536 items, 6 iters, float4 taps
  #pragma unroll
  for (int i = 0; i < 6; i++) {
    const int idx = i*256 + t;
    const int ci = idx >> 4, q = idx & 15;
    const int x0 = xb*64 + q*4;
    const float* ip = in + ((long)b*96 + ci) * HW;
    const float* wp = w + ci*9;
    float a0 = 0.f, a1 = 0.f, a2 = 0.f, a3 = 0.f;
    #pragma unroll
    for (int dy = -1; dy <= 1; dy++) {
      const int yy = y + dy;
      if (yy < 0 || yy > 255) continue;
      const float* rp = ip + yy*256;
      const float4 c = *(const float4*)&rp[x0];
      const float left  = (x0 > 0)   ? rp[x0-1] : 0.f;
      const float right = (x0 < 252) ? rp[x0+4] : 0.f;
      const float w0 = wp[(dy+1)*3+0], w1 = wp[(dy+1)*3+1], w2 = wp[(dy+1)*3+2];
      a0 = fmaf(left, w0, a0); a0 = fmaf(c.x, w1, a0); a0 = fmaf(c.y, w2, a0);
      a1 = fmaf(c.x,  w0, a1); a1 = fmaf(c.y, w1, a1); a1 = fmaf(c.z, w2, a1);
      a2 = fmaf(c.y,  w0, a2); a2 = fmaf(c.z, w1, a2); a2 = fmaf(c.w, w2, a2);
      a3 = fmaf(c.z,  w0, a3); a3 = fmaf(c.w, w1, a3); a3 = fmaf(right, w2, a3);
    }
    const int xl = q*4;
    tile[ci*65 + xl    ] = a0;
    tile[ci*65 + xl + 1] = a1;
    tile[ci*65 + xl + 2] = a2;
    tile[ci*65 + xl + 3] = a3;
  }
  __syncthreads();
  const int blk = (y >> 6)*4 + xb;
  float* obase = vs + ((long)b*4096 + (long)(y & 63)*64) * 1536 + blk*96;
  #pragma unroll
  for (int i = 0; i < 24; i++) {
    const int idx = i*256 + t;
    const int nl = idx / 96, ci = idx % 96;
    obase[(long)nl*1536 + ci] = tile[ci*65 + nl];
  }
}

// ---------------- depthwise 4x4 stride 4 pad 1 (256->64) ----------------
__global__ __launch_bounds__(256) void dw4x4s4(
    const float* __restrict__ in, const float* __restrict__ w,
    float* __restrict__ out)
{
  const int t = threadIdx.x;
  const int op = blockIdx.x * 256 + t;
  const int ch = blockIdx.y, b = blockIdx.z;
  const int oy = op >> 6, ox = op & 63;
  const float* ip = in + (long)(b*192 + ch) * HW;
  const float* wp = w + ch*16;
  float acc = 0.f;
  #pragma unroll
  for (int ty = 0; ty < 4; ty++) {
    int iy = 4*oy + ty - 1;
    if (iy < 0 || iy > 255) continue;
    #pragma unroll
    for (int tx = 0; tx < 4; tx++) {
      int ix = 4*ox + tx - 1;
      if (ix < 0 || ix > 255) continue;
      acc = fmaf(ip[iy*256 + ix], wp[ty*4 + tx], acc);
    }
  }
  out[(long)(b*192 + ch) * 4096 + op] = acc;
}

// ---------------- l2 norm over 192 channels + transpose to (B,4096,192) ----
__global__ __launch_bounds__(256) void l2n192(
    const float* __restrict__ in, float* __restrict__ out)
{
  const int t = threadIdx.x;
  const int wid = t >> 6, lane = t & 63;
  const int gw = blockIdx.x * 4 + wid;
  const int b = gw >> 12, n = gw & 4095;
  const float* ip = in + (long)b * 786432;
  float v0 = ip[(long)(lane      ) * 4096 + n];
  float v1 = ip[(long)(lane +  64) * 4096 + n];
  float v2 = ip[(long)(lane + 128) * 4096 + n];
  float ss = v0*v0 + v1*v1 + v2*v2;
  #pragma unroll
  for (int s = 1; s < 64; s <<= 1) ss += __shfl_xor(ss, s, 64);
  float nrm = fmaxf(sqrtf(ss), 1e-12f);
  float* op = out + ((long)b*4096 + n) * 192;
  op[lane      ] = v0 / nrm;
  op[lane +  64] = v1 / nrm;
  op[lane + 128] = v2 / nrm;
}

// ---------------- split fp32 -> (hi,lo) bf16 planes ----------------
__global__ __launch_bounds__(256) void bf16split(
    const float* __restrict__ in, unsigned short* __restrict__ outp)
{
  const int i = blockIdx.x * 256 + threadIdx.x;
  const int n = i / 192, k = i % 192;
  float f = in[i];
  __hip_bfloat16 h = __float2bfloat16(f);
  float hf = __bfloat162float(h);
  __hip_bfloat16 l = __float2bfloat16(f - hf);
  outp[(long)n*384 + k]       = *(unsigned short*)&h;
  outp[(long)n*384 + 192 + k] = *(unsigned short*)&l;
}

// ---------------- attention QK^T via split-bf16 MFMA (one batch) ------------
#define LDSROW 40
__global__ __launch_bounds__(256) void attn_qk_mfma(
    const unsigned short* __restrict__ Qsp, const unsigned short* __restrict__ Ksp,
    float* __restrict__ attn, const float* __restrict__ tp)
{
  __shared__ unsigned short qs[256*LDSROW];
  __shared__ unsigned short ks[256*LDSROW];
  const int t = threadIdx.x;
  const int lane = t & 63, w = t >> 6;
  const int n0 = blockIdx.x * 128;
  const int m0 = blockIdx.y * 128;
  const int wr = (w >> 1) * 64, wc = (w & 1) * 64;
  f32x4 acc[4][4] = {};
  const int srow = t & 127;
  const int shl  = t >> 7;
  const unsigned short* qsrc = Qsp + (long)(n0 + srow) * 384 + shl * 192;
  const unsigned short* ksrc = Ksp + (long)(m0 + srow) * 384 + shl * 192;
  unsigned short* qdst = qs + (shl*128 + srow) * LDSROW;
  unsigned short* kdst = ks + (shl*128 + srow) * LDSROW;
  const int fr = lane & 15;
  const int fk = lane >> 4;
  for (int s = 0; s < 6; s++) {
    __syncthreads();
    #pragma unroll
    for (int j = 0; j < 4; j++) {
      *(bf16x8*)(qdst + j*8) = *(const bf16x8*)(qsrc + s*32 + j*8);
      *(bf16x8*)(kdst + j*8) = *(const bf16x8*)(ksrc + s*32 + j*8);
    }
    __syncthreads();
    bf16x8 ah[4], al[4], bh[4], bl[4];
    #pragma unroll
    for (int i = 0; i < 4; i++) {
      ah[i] = *(const bf16x8*)(qs + (      wr + i*16 + fr) * LDSROW + fk*8);
      al[i] = *(const bf16x8*)(qs + (128 + wr + i*16 + fr) * LDSROW + fk*8);
      bh[i] = *(const bf16x8*)(ks + (      wc + i*16 + fr) * LDSROW + fk*8);
      bl[i] = *(const bf16x8*)(ks + (128 + wc + i*16 + fr) * LDSROW + fk*8);
    }
    #pragma unroll
    for (int i = 0; i < 4; i++)
      #pragma unroll
      for (int j = 0; j < 4; j++) {
        acc[i][j] = __builtin_amdgcn_mfma_f32_16x16x32_bf16(ah[i], bh[j], acc[i][j], 0, 0, 0);
        acc[i][j] = __builtin_amdgcn_mfma_f32_16x16x32_bf16(ah[i], bl[j], acc[i][j], 0, 0, 0);
        acc[i][j] = __builtin_amdgcn_mfma_f32_16x16x32_bf16(al[i], bh[j], acc[i][j], 0, 0, 0);
      }
  }
  const float temp = tp[0];
  #pragma unroll
  for (int i = 0; i < 4; i++)
    #pragma unroll
    for (int j = 0; j < 4; j++)
      #pragma unroll
      for (int r = 0; r < 4; r++) {
        const int nn = n0 + wr + i*16 + (lane >> 4)*4 + r;
        const int mm = m0 + wc + j*16 + (lane & 15);
        attn[(long)nn*4096 + mm] = acc[i][j][r] * temp;
      }
}

// ------- top-5 + local mask + softmax + sparse out -------
#define CAP 128
__global__ __launch_bounds__(256) void attn_out_k(
    const float* __restrict__ attn, const float* __restrict__ vs,
    float* __restrict__ outr)
{
  __shared__ float row[4096];
  __shared__ float top5[256*5];
  __shared__ int   lm[CAP];
  __shared__ float lw[CAP];
  __shared__ float ses[CAP];
  __shared__ float redf[8];
  __shared__ int   scan[256];
  const int t = threadIdx.x;
  const int n = blockIdx.x;
  const float* ar = attn + (long)n * 4096;
  #pragma unroll
  for (int k = 0; k < 16; k++) row[k*256 + t] = ar[k*256 + t];
  __syncthreads();
  float t0=-INFINITY,t1=-INFINITY,t2=-INFINITY,t3=-INFINITY,t4=-INFINITY;
  #pragma unroll
  for (int k = 0; k < 16; k++) {
    float v = row[k*256 + t];
    if (v > t4) {
      if (v > t0)      { t4=t3; t3=t2; t2=t1; t1=t0; t0=v; }
      else if (v > t1) { t4=t3; t3=t2; t2=t1; t1=v; }
      else if (v > t2) { t4=t3; t3=t2; t2=v; }
      else if (v > t3) { t4=t3; t3=v; }
      else             { t4=v; }
    }
  }
  top5[t*5+0]=t0; top5[t*5+1]=t1; top5[t*5+2]=t2; top5[t*5+3]=t3; top5[t*5+4]=t4;
  __syncthreads();
  for (int s = 128; s >= 1; s >>= 1) {
    if (t < s) {
      float* A = &top5[t*5];
      const float* B = &top5[(t+s)*5];
      float m[5]; int i = 0, j = 0;
      #pragma unroll
      for (int k = 0; k < 5; k++) {
        float av = A[i], bv = B[j];
        if (av >= bv) { m[k] = av; i++; } else { m[k] = bv; j++; }
      }
      #pragma unroll
      for (int k = 0; k < 5; k++) A[k] = m[k];
    }
    __syncthreads();
  }
  const float kth = top5[4];
  const int y = n >> 6, x = n & 63;
  int myc = 0;
  float wmax = -INFINITY;
  #pragma unroll
  for (int k = 0; k < 16; k++) {
    int m = k*256 + t;
    float a = row[m];
    int c = ((a >= kth) ? 1 : 0) +
            (((iabs_(y - (m >> 6)) + iabs_(x - (m & 63))) <= 4) ? 1 : 0);
    float wv = a * (float)c;
    if (wv != 0.0f) { myc++; wmax = fmaxf(wmax, wv); }
  }
  scan[t] = myc;
  __syncthreads();
  for (int s = 1; s < 256; s <<= 1) {
    int v = (t >= s) ? scan[t-s] : 0;
    __syncthreads();
    scan[t] += v;
    __syncthreads();
  }
  const int base = scan[t] - myc;
  const int cnt = scan[255];
  {
    int idx = base;
    #pragma unroll
    for (int k = 0; k < 16; k++) {
      int m = k*256 + t;
      float a = row[m];
      int c = ((a >= kth) ? 1 : 0) +
              (((iabs_(y - (m >> 6)) + iabs_(x - (m & 63))) <= 4) ? 1 : 0);
      float wv = a * (float)c;
      if (wv != 0.0f && idx < CAP) { lm[idx] = m; lw[idx] = wv; idx++; }
    }
  }
  #pragma unroll
  for (int s = 1; s < 64; s <<= 1) wmax = fmaxf(wmax, __shfl_xor(wmax, s, 64));
  if ((t & 63) == 0) redf[t >> 6] = wmax;
  __syncthreads();
  const float gmax = fmaxf(fmaxf(redf[0], redf[1]), fmaxf(redf[2], redf[3]));
  __syncthreads();
  if (t < cnt && t < CAP) ses[t] = expf(lw[t] - gmax);
  __syncthreads();
  float ps = (t < cnt && t < CAP) ? ses[t] : 0.f;
  #pragma unroll
  for (int s = 1; s < 64; s <<= 1) ps += __shfl_xor(ps, s, 64);
  if ((t & 63) == 0) redf[4 + (t >> 6)] = ps;
  __syncthreads();
  const float S = redf[4] + redf[5] + redf[6] + redf[7];
  const float invS = 1.0f / S;
  float a0=0,a1=0,a2=0,a3=0,a4=0,a5=0;
  const int ecnt = (cnt < CAP) ? cnt : CAP;
  for (int e = 0; e < ecnt; e++) {
    float se = ses[e] * invS;
    const float* vr = vs + (long)lm[e] * 1536;
    a0 = fmaf(se, vr[        t], a0);
    a1 = fmaf(se, vr[ 256 + t], a1);
    a2 = fmaf(se, vr[ 512 + t], a2);
    a3 = fmaf(se, vr[ 768 + t], a3);
    a4 = fmaf(se, vr[1024 + t], a4);
    a5 = fmaf(se, vr[1280 + t], a5);
  }
  float* orow = outr + (long)n * 1536;
  orow[        t] = a0;
  orow[ 256 + t] = a1;
  orow[ 512 + t] = a2;
  orow[ 768 + t] = a3;
  orow[1024 + t] = a4;
  orow[1280 + t] = a5;
}

// ---------------- per-channel l2 norm over 65536 (fhr q2/k2) ----------------
__global__ __launch_bounds__(1024) void l2n_sp(
    const float* __restrict__ in, float* __restrict__ out)
{
  const int ch = blockIdx.x, b = blockIdx.y, t = threadIdx.x;
  const float* ip = in + ((long)b*96 + ch) * HW;
  float ss = 0.f;
  for (int i = t; i < 65536; i += 1024) { float v = ip[i]; ss = fmaf(v, v, ss); }
  __shared__ float red[16];
  #pragma unroll
  for (int s = 1; s < 64; s <<= 1) ss += __shfl_xor(ss, s, 64);
  if ((t & 63) == 0) red[t >> 6] = ss;
  __syncthreads();
  if (t == 0) {
    float s2 = 0.f;
    for (int i = 0; i < 16; i++) s2 += red[i];
    red[0] = fmaxf(sqrtf(s2), 1e-12f);
  }
  __syncthreads();
  const float nrm = red[0];
  float* op = out + ((long)b*96 + ch) * HW;
  for (int i = t; i < 65536; i += 1024) op[i] = ip[i] / nrm;
}

// -------- a2 stage 1: partial Gram (12x12) over 4096-elem chunks ------------
#define A2_NCH 16
__global__ __launch_bounds__(256) void a2_part(
    const float* __restrict__ q2n, const float* __restrict__ k2n,
    float* __restrict__ part)
{
  __shared__ float sh[24*260];
  const int t = threadIdx.x;
  const int ch = blockIdx.x, h = blockIdx.y, b = blockIdx.z;
  const long base = ((long)b*96 + h*12) * HW + ch*4096;
  const int c = t / 12, d = t - (t/12)*12;
  float acc = 0.f;
  for (int sub = 0; sub < 16; sub++) {
    __syncthreads();
    #pragma unroll
    for (int j = 0; j < 6; j++) {
      const int v = j*256 + t;
      const int row = v >> 6;
      const int col4 = v & 63;
      const float* src = (row < 12)
        ? q2n + base + (long)row*HW + sub*256 + col4*4
        : k2n + base + (long)(row-12)*HW + sub*256 + col4*4;
      *(float4*)&sh[row*260 + col4*4] = *(const float4*)src;
    }
    __syncthreads();
    if (t < 144) {
      const float* qr = &sh[c*260];
      const float* kr = &sh[(12+d)*260];
      #pragma unroll
      for (int i4 = 0; i4 < 64; i4++) {
        float4 qv = *(const float4*)&qr[i4*4];
        float4 kv = *(const float4*)&kr[i4*4];
        acc = fmaf(qv.x, kv.x, acc);
        acc = fmaf(qv.y, kv.y, acc);
        acc = fmaf(qv.z, kv.z, acc);
        acc = fmaf(qv.w, kv.w, acc);
      }
    }
  }
  if (t < 144)
    part[(((long)b*8 + h)*A2_NCH + ch)*144 + t] = acc;
}

// -------- a2 stage 2 --------
__global__ __launch_bounds__(256) void a2_fin(
    const float* __restrict__ part, const float* __restrict__ temp,
    float* __restrict__ a2s)
{
  __shared__ float m[144];
  const int t = threadIdx.x;
  const int h = blockIdx.x, b = blockIdx.y;
  if (t < 144) {
    float s = 0.f;
    const float* pp = part + (((long)b*8 + h)*A2_NCH)*144 + t;
    #pragma unroll
    for (int ch = 0; ch < A2_NCH; ch++) s += pp[ch*144];
    m[t] = s * temp[h];
  }
  __syncthreads();
  if (t < 12) {
    float mx = -INFINITY;
    #pragma unroll
    for (int d = 0; d < 12; d++) mx = fmaxf(mx, m[t*12+d]);
    float e[12], sum = 0.f;
    #pragma unroll
    for (int d = 0; d < 12; d++) { e[d] = expf(m[t*12+d]-mx); sum += e[d]; }
    float inv = 1.0f/sum;
    float* op = a2s + (((long)b*8 + h)*12 + t)*12;
    #pragma unroll
    for (int d = 0; d < 12; d++) op[d] = e[d]*inv;
  }
}

// ---------------- o2pre = a2 @ v2 ----------------
__global__ __launch_bounds__(256) void o2pre_kern(
    const float* __restrict__ a2s, const float* __restrict__ v2,
    float* __restrict__ o2p)
{
  const int t = threadIdx.x;
  const int n = blockIdx.x * 256 + t;
  const int bh = blockIdx.y, b = bh >> 3, h = bh & 7;
  const float* a = a2s + (long)bh * 144;
  const float* vb = v2 + ((long)b*96 + h*12) * HW;
  float vv[12];
  #pragma unroll
  for (int d = 0; d < 12; d++) vv[d] = vb[(long)d*HW + n];
  float* ob = o2p + ((long)b*96 + h*12) * HW;
  #pragma unroll
  for (int c = 0; c < 12; c++) {
    float s = 0.f;
    #pragma unroll
    for (int d = 0; d < 12; d++) s = fmaf(a[c*12 + d], vv[d], s);
    ob[(long)c*HW + n] = s;
  }
}

extern "C" void kernel_launch(void* const* d_in, const int* in_sizes, int n_in,
                              void* d_out, int out_size, void* d_ws, size_t ws_size,
                              hipStream_t stream) {
  const float* x        = (const float*)d_in[0];
  const float* qk_w     = (const float*)d_in[1];
  const float* qk_dw    = (const float*)d_in[2];
  const float* v_w      = (const float*)d_in[3];
  const float* v_dw     = (const float*)d_in[4];
  const float* k2_w     = (const float*)d_in[5];
  const float* k2_dw    = (const float*)d_in[6];
  const float* q2_w     = (const float*)d_in[7];
  const float* q2_dw    = (const float*)d_in[8];
  const float* proj_w   = (const float*)d_in[9];
  const float* sab_temp = (const float*)d_in[10];
  const float* fqkv_w   = (const float*)d_in[11];
  const float* fqkv_dw  = (const float*)d_in[12];
  const float* fproj_w  = (const float*)d_in[13];
  const float* fhr_temp = (const float*)d_in[14];
  float* out = (float*)d_out;
  float* ws  = (float*)d_ws;

  float* O2  = out;
  float* KS  = out + 12582912;
  float* VS  = out + 14155776;
  float* K2N = out + 26738688;
  float* V2  = out + 39321600;

  float* A0   = ws;
  float* A1   = ws + 25165824;
  float* QD   = ws + 50331648;
  float* KD   = ws + 51904512;
  float* QN   = ws + 53477376;
  float* A2S  = ws + 55050240;
  float* PART = ws + 55052544;
  unsigned short* QSP = (unsigned short*)(A0 + 16777216);
  unsigned short* KSP = (unsigned short*)(A0 + 16777216 + 786432);
  unsigned short* WHL = (unsigned short*)QN;

  dim3 b256(256), b1024(1024);

  wsplit<<<dim3(432), b256, 0, stream>>>(qk_w, v_w, q2_w, k2_w, proj_w, fqkv_w, fproj_w, WHL);
  conv1x1_mfma<<<dim3(512,2), b256, 0, stream>>>(x, 96L*HW, WHL, 0, A0, 192L*HW, 12, 0);
  dw3x3v<<<dim3(64,192,2), b256, 0, stream>>>(A0, qk_dw, A1, 192);
  conv1x1_mfma<<<dim3(512,2), b256, 0, stream>>>(x, 96L*HW, WHL, 192, A0, 96L*HW, 6, 0);
  dw3x3_vs<<<dim3(1024,2), b256, 0, stream>>>(A0, v_dw, VS);
  conv1x1_mfma<<<dim3(512,2), b256, 0, stream>>>(A1, 192L*HW, WHL, 288, A0, 192L*HW, 12, 0);
  dw4x4s4<<<dim3(16,192,2), b256, 0, stream>>>(A0, q2_dw, QD);
  conv1x1_mfma<<<dim3(512,2), b256, 0, stream>>>(A1 + 96L*HW, 192L*HW, WHL, 480, A0, 192L*HW, 12, 0);
  dw4x4s4<<<dim3(16,192,2), b256, 0, stream>>>(A0, k2_dw, KD);
  l2n192<<<dim3(2048), b256, 0, stream>>>(QD, QN);
  l2n192<<<dim3(2048), b256, 0, stream>>>(KD, KS);
  for (int b = 0; b < 2; b++) {
    bf16split<<<dim3(3072), b256, 0, stream>>>(QN + (long)b*786432, QSP);
    bf16split<<<dim3(3072), b256, 0, stream>>>(KS + (long)b*786432, KSP);
    attn_qk_mfma<<<dim3(32,32), b256, 0, stream>>>(QSP, KSP, A0, sab_temp);
    attn_out_k<<<dim3(4096), b256, 0, stream>>>(
        A0, VS + (long)b*6291456, A1 + (long)b*6291456);
  }
  wsplit<<<dim3(432), b256, 0, stream>>>(qk_w, v_w, q2_w, k2_w, proj_w, fqkv_w, fproj_w, WHL);
  conv1x1_mfma<<<dim3(512,2), b256, 0, stream>>>(A1, 6291456L, WHL, 672, A0, 96L*HW, 6, 1);
  float* PRE  = A0 + 12582912;
  float* DW1  = A1 + 12582912;
  float* Q2NB = A1;
  conv1x1_mfma<<<dim3(512,2), b256, 0, stream>>>(A0, 96L*HW, WHL, 768, PRE, 96L*HW, 6, 0);
  dw3x3v<<<dim3(64,96,2), b256, 0, stream>>>(PRE, fqkv_dw,        DW1, 96);
  l2n_sp<<<dim3(96,2), b1024, 0, stream>>>(DW1, Q2NB);
  conv1x1_mfma<<<dim3(512,2), b256, 0, stream>>>(A0, 96L*HW, WHL, 864, PRE, 96L*HW, 6, 0);
  dw3x3v<<<dim3(64,96,2), b256, 0, stream>>>(PRE, fqkv_dw +  864, DW1, 96);
  l2n_sp<<<dim3(96,2), b1024, 0, stream>>>(DW1, K2N);
  conv1x1_mfma<<<dim3(512,2), b256, 0, stream>>>(A0, 96L*HW, WHL, 960, PRE, 96L*HW, 6, 0);
  dw3x3v<<<dim3(64,96,2), b256, 0, stream>>>(PRE, fqkv_dw + 1728, V2, 96);
  a2_part<<<dim3(A2_NCH,8,2), b256, 0, stream>>>(Q2NB, K2N, PART);
  a2_fin<<<dim3(8,2), b256, 0, stream>>>(PART, fhr_temp, A2S);
  o2pre_kern<<<dim3(256,16), b256, 0, stream>>>(A2S, V2, A0);
  conv1x1_mfma<<<dim3(512,2), b256, 0, stream>>>(A0, 96L*HW, WHL, 1056, O2, 96L*HW, 6, 0);
}

// Round 11
// 903.547 us; speedup vs baseline: 2.1281x; 1.0162x over previous
//
#include <hip/hip_runtime.h>
#include <hip/hip_bf16.h>
#include <math.h>

#define HW 65536L

typedef __attribute__((ext_vector_type(8))) short bf16x8;
typedef __attribute__((ext_vector_type(4))) float f32x4;

__device__ __forceinline__ int iabs_(int v) { return v < 0 ? -v : v; }

// ---- split all 1x1 weights into (hi,lo) bf16 planes: whl[2][1152][96] ----
__global__ __launch_bounds__(256) void wsplit(
    const float* __restrict__ qk, const float* __restrict__ v,
    const float* __restrict__ q2, const float* __restrict__ k2,
    const float* __restrict__ pj, const float* __restrict__ fq,
    const float* __restrict__ fp, unsigned short* __restrict__ whl)
{
  const int e = blockIdx.x*256 + threadIdx.x;
  if (e >= 110592) return;
  const int row = e / 96, col = e - row*96;
  float f;
  if      (row <  192) f = qk[e];
  else if (row <  288) f = v [(row-192)*96+col];
  else if (row <  480) f = q2[(row-288)*96+col];
  else if (row <  672) f = k2[(row-480)*96+col];
  else if (row <  768) f = pj[(row-672)*96+col];
  else if (row < 1056) f = fq[(row-768)*96+col];
  else                 f = fp[(row-1056)*96+col];
  __hip_bfloat16 h = __float2bfloat16(f);
  float hf = __bfloat162float(h);
  __hip_bfloat16 l = __float2bfloat16(f - hf);
  whl[e]          = *(unsigned short*)&h;
  whl[110592 + e] = *(unsigned short*)&l;
}

// ---------------- conv 1x1 via split-bf16 MFMA (R10: packed trunc staging) ---
#define BLDS 104
__global__ __launch_bounds__(256) void conv1x1_mfma(
    const float* __restrict__ in, long in_bstride,
    const unsigned short* __restrict__ whl, int wrow0,
    float* __restrict__ out, long out_bstride,
    int mtiles, int mode)
{
  __shared__ unsigned short bhs[128*BLDS];
  __shared__ unsigned short bls[128*BLDS];
  const int t = threadIdx.x;
  const int p0 = blockIdx.x * 128;
  const int b = blockIdx.y;
  if (mode == 0) {
    #pragma unroll
    for (int it = 0; it < 12; it++) {
      const int idx = it*256 + t;           // 0..3071
      const int g = idx >> 7;               // 4-channel group 0..23
      const int pix = idx & 127;
      const float* src = in + (long)b*in_bstride + (long)(g*4)*HW + p0 + pix;
      unsigned hh[4], ll[4];
      #pragma unroll
      for (int j = 0; j < 4; j++) {
        float f = src[(long)j*HW];
        unsigned u = __float_as_uint(f);
        hh[j] = u >> 16;                                   // trunc-split hi
        float lof = f - __uint_as_float(u & 0xFFFF0000u);  // exact residue
        __hip_bfloat16 lb = __float2bfloat16(lof);
        ll[j] = *(unsigned short*)&lb;
      }
      uint2 hv, lv;
      hv.x = hh[0] | (hh[1] << 16); hv.y = hh[2] | (hh[3] << 16);
      lv.x = ll[0] | (ll[1] << 16); lv.y = ll[2] | (ll[3] << 16);
      *(uint2*)(bhs + pix*BLDS + g*4) = hv;
      *(uint2*)(bls + pix*BLDS + g*4) = lv;
    }
  } else {
    const int pp = t >> 1, half = (t & 1)*48;
    const int p = p0 + pp;
    const int py = p >> 8, px = p & 255;
    const float* src = in + (long)b*in_bstride
        + ((long)((py & 63)*64 + (px & 63))*16 + ((py >> 6)*4 + (px >> 6)))*96 + half;
    #pragma unroll
    for (int j4 = 0; j4 < 12; j4++) {
      float4 v4 = *(const float4*)&src[j4*4];
      float fv[4] = {v4.x, v4.y, v4.z, v4.w};
      unsigned hh[4], ll[4];
      #pragma unroll
      for (int u4 = 0; u4 < 4; u4++) {
        unsigned u = __float_as_uint(fv[u4]);
        hh[u4] = u >> 16;
        float lof = fv[u4] - __uint_as_float(u & 0xFFFF0000u);
        __hip_bfloat16 lb = __float2bfloat16(lof);
        ll[u4] = *(unsigned short*)&lb;
      }
      uint2 hv, lv;
      hv.x = hh[0] | (hh[1] << 16); hv.y = hh[2] | (hh[3] << 16);
      lv.x = ll[0] | (ll[1] << 16); lv.y = ll[2] | (ll[3] << 16);
      *(uint2*)(bhs + pp*BLDS + half + j4*4) = hv;
      *(uint2*)(bls + pp*BLDS + half + j4*4) = lv;
    }
  }
  __syncthreads();
  const int lane = t & 63, w = t >> 6;
  const int fr = lane & 15, fk = lane >> 4;
  bf16x8 Bh[2][3], Bl[2][3];
  #pragma unroll
  for (int nt = 0; nt < 2; nt++)
    #pragma unroll
    for (int kt = 0; kt < 3; kt++) {
      const int pix = w*32 + nt*16 + fr;
      Bh[nt][kt] = *(const bf16x8*)(bhs + pix*BLDS + kt*32 + fk*8);
      Bl[nt][kt] = *(const bf16x8*)(bls + pix*BLDS + kt*32 + fk*8);
    }
  float* dst = out + (long)b*out_bstride + p0 + w*32;
  for (int m = 0; m < mtiles; m++) {
    const long wbase = (long)(wrow0 + m*16 + fr)*96 + fk*8;
    bf16x8 Ah[3], Al[3];
    #pragma unroll
    for (int kt = 0; kt < 3; kt++) {
      Ah[kt] = *(const bf16x8*)(whl + wbase + kt*32);
      Al[kt] = *(const bf16x8*)(whl + 110592 + wbase + kt*32);
    }
    f32x4 acc[2] = {};
    #pragma unroll
    for (int nt = 0; nt < 2; nt++)
      #pragma unroll
      for (int kt = 0; kt < 3; kt++) {
        acc[nt] = __builtin_amdgcn_mfma_f32_16x16x32_bf16(Ah[kt], Bh[nt][kt], acc[nt], 0, 0, 0);
        acc[nt] = __builtin_amdgcn_mfma_f32_16x16x32_bf16(Ah[kt], Bl[nt][kt], acc[nt], 0, 0, 0);
        acc[nt] = __builtin_amdgcn_mfma_f32_16x16x32_bf16(Al[kt], Bh[nt][kt], acc[nt], 0, 0, 0);
      }
    #pragma unroll
    for (int nt = 0; nt < 2; nt++)
      #pragma unroll
      for (int r = 0; r < 4; r++)
        dst[(long)(m*16 + fk*4 + r)*HW + nt*16 + fr] = acc[nt][r];
  }
}

// -------- depthwise 3x3 pad 1, 4-wide vectorized (R10: split in/out CH) -----
__global__ __launch_bounds__(256) void dw3x3v(
    const float* __restrict__ in, int inCH, const float* __restrict__ w,
    float* __restrict__ out, int outCH)
{
  const int t = threadIdx.x;
  const int p4 = blockIdx.x * 256 + t;
  const int ch = blockIdx.y, b = blockIdx.z;
  const int y = p4 >> 6, x0 = (p4 & 63) << 2;
  const float* ip = in + ((long)b*inCH + ch) * HW;
  const float* wp = w + ch*9;
  float a0 = 0.f, a1 = 0.f, a2 = 0.f, a3 = 0.f;
  #pragma unroll
  for (int dy = -1; dy <= 1; dy++) {
    const int yy = y + dy;
    if (yy < 0 || yy > 255) continue;
    const float* rp = ip + yy*256;
    const float4 c = *(const float4*)&rp[x0];
    const float left  = (x0 > 0)   ? rp[x0-1] : 0.f;
    const float right = (x0 < 252) ? rp[x0+4] : 0.f;
    const float w0 = wp[(dy+1)*3+0], w1 = wp[(dy+1)*3+1], w2 = wp[(dy+1)*3+2];
    a0 = fmaf(left, w0, a0); a0 = fmaf(c.x, w1, a0); a0 = fmaf(c.y, w2, a0);
    a1 = fmaf(c.x,  w0, a1); a1 = fmaf(c.y, w1, a1); a1 = fmaf(c.z, w2, a1);
    a2 = fmaf(c.y,  w0, a2); a2 = fmaf(c.z, w1, a2); a2 = fmaf(c.w, w2, a2);
    a3 = fmaf(c.z,  w0, a3); a3 = fmaf(c.w, w1, a3); a3 = fmaf(right, w2, a3);
  }
  float4 o; o.x = a0; o.y = a1; o.z = a2; o.w = a3;
  *(float4*)&out[((long)b*outCH + ch)*HW + y*256 + x0] = o;
}

// ------- depthwise 3x3 fused with v_s permutation (4-wide compute) ----
__global__ __launch_bounds__(256) void dw3x3_vs(
    const float* __restrict__ in, const float* __restrict__ w,
    float* __restrict__ vs)
{
  __shared__ float tile[96*65];
  const int t = threadIdx.x;
  const int gb = blockIdx.x;
  const int b = blockIdx.y;
  const int y = gb >> 2, xb = gb & 3;
  #pragma unroll
  for (int i = 0; i < 6; i++) {
    const int idx = i*256 + t;
    const int ci = idx >> 4, q = idx & 15;
    const int x0 = xb*64 + q*4;
    const float* ip = in + ((long)b*96 + ci) * HW;
    const float* wp = w + ci*9;
    float a0 = 0.f, a1 = 0.f, a2 = 0.f, a3 = 0.f;
    #pragma unroll
    for (int dy = -1; dy <= 1; dy++) {
      const int yy = y + dy;
      if (yy < 0 || yy > 255) continue;
      const float* rp = ip + yy*256;
      const float4 c = *(const float4*)&rp[x0];
      const float left  = (x0 > 0)   ? rp[x0-1] : 0.f;
      const float right = (x0 < 252) ? rp[x0+4] : 0.f;
      const float w0 = wp[(dy+1)*3+0], w1 = wp[(dy+1)*3+1], w2 = wp[(dy+1)*3+2];
      a0 = fmaf(left, w0, a0); a0 = fmaf(c.x, w1, a0); a0 = fmaf(c.y, w2, a0);
      a1 = fmaf(c.x,  w0, a1); a1 = fmaf(c.y, w1, a1); a1 = fmaf(c.z, w2, a1);
      a2 = fmaf(c.y,  w0, a2); a2 = fmaf(c.z, w1, a2); a2 = fmaf(c.w, w2, a2);
      a3 = fmaf(c.z,  w0, a3); a3 = fmaf(c.w, w1, a3); a3 = fmaf(right, w2, a3);
    }
    const int xl = q*4;
    tile[ci*65 + xl    ] = a0;
    tile[ci*65 + xl + 1] = a1;
    tile[ci*65 + xl + 2] = a2;
    tile[ci*65 + xl + 3] = a3;
  }
  __syncthreads();
  const int blk = (y >> 6)*4 + xb;
  float* obase = vs + ((long)b*4096 + (long)(y & 63)*64) * 1536 + blk*96;
  #pragma unroll
  for (int i = 0; i < 24; i++) {
    const int idx = i*256 + t;
    const int nl = idx / 96, ci = idx % 96;
    obase[(long)nl*1536 + ci] = tile[ci*65 + nl];
  }
}

// ---------------- depthwise 4x4 stride 4 pad 1 (256->64) ----------------
__global__ __launch_bounds__(256) void dw4x4s4(
    const float* __restrict__ in, const float* __restrict__ w,
    float* __restrict__ out)
{
  const int t = threadIdx.x;
  const int op = blockIdx.x * 256 + t;
  const int ch = blockIdx.y, b = blockIdx.z;
  const int oy = op >> 6, ox = op & 63;
  const float* ip = in + (long)(b*192 + ch) * HW;
  const float* wp = w + ch*16;
  float acc = 0.f;
  #pragma unroll
  for (int ty = 0; ty < 4; ty++) {
    int iy = 4*oy + ty - 1;
    if (iy < 0 || iy > 255) continue;
    #pragma unroll
    for (int tx = 0; tx < 4; tx++) {
      int ix = 4*ox + tx - 1;
      if (ix < 0 || ix > 255) continue;
      acc = fmaf(ip[iy*256 + ix], wp[ty*4 + tx], acc);
    }
  }
  out[(long)(b*192 + ch) * 4096 + op] = acc;
}

// ---------------- l2 norm over 192 channels + transpose to (B,4096,192) ----
__global__ __launch_bounds__(256) void l2n192(
    const float* __restrict__ in, float* __restrict__ out)
{
  const int t = threadIdx.x;
  const int wid = t >> 6, lane = t & 63;
  const int gw = blockIdx.x * 4 + wid;
  const int b = gw >> 12, n = gw & 4095;
  const float* ip = in + (long)b * 786432;
  float v0 = ip[(long)(lane      ) * 4096 + n];
  float v1 = ip[(long)(lane +  64) * 4096 + n];
  float v2 = ip[(long)(lane + 128) * 4096 + n];
  float ss = v0*v0 + v1*v1 + v2*v2;
  #pragma unroll
  for (int s = 1; s < 64; s <<= 1) ss += __shfl_xor(ss, s, 64);
  float nrm = fmaxf(sqrtf(ss), 1e-12f);
  float* op = out + ((long)b*4096 + n) * 192;
  op[lane      ] = v0 / nrm;
  op[lane +  64] = v1 / nrm;
  op[lane + 128] = v2 / nrm;
}

// ---------------- split fp32 -> (hi,lo) bf16 planes ----------------
__global__ __launch_bounds__(256) void bf16split(
    const float* __restrict__ in, unsigned short* __restrict__ outp)
{
  const int i = blockIdx.x * 256 + threadIdx.x;
  const int n = i / 192, k = i % 192;
  float f = in[i];
  __hip_bfloat16 h = __float2bfloat16(f);
  float hf = __bfloat162float(h);
  __hip_bfloat16 l = __float2bfloat16(f - hf);
  outp[(long)n*384 + k]       = *(unsigned short*)&h;
  outp[(long)n*384 + 192 + k] = *(unsigned short*)&l;
}

// ---------------- attention QK^T via split-bf16 MFMA (one batch) ------------
#define LDSROW 40
__global__ __launch_bounds__(256) void attn_qk_mfma(
    const unsigned short* __restrict__ Qsp, const unsigned short* __restrict__ Ksp,
    float* __restrict__ attn, const float* __restrict__ tp)
{
  __shared__ unsigned short qs[256*LDSROW];
  __shared__ unsigned short ks[256*LDSROW];
  const int t = threadIdx.x;
  const int lane = t & 63, w = t >> 6;
  const int n0 = blockIdx.x * 128;
  const int m0 = blockIdx.y * 128;
  const int wr = (w >> 1) * 64, wc = (w & 1) * 64;
  f32x4 acc[4][4] = {};
  const int srow = t & 127;
  const int shl  = t >> 7;
  const unsigned short* qsrc = Qsp + (long)(n0 + srow) * 384 + shl * 192;
  const unsigned short* ksrc = Ksp + (long)(m0 + srow) * 384 + shl * 192;
  unsigned short* qdst = qs + (shl*128 + srow) * LDSROW;
  unsigned short* kdst = ks + (shl*128 + srow) * LDSROW;
  const int fr = lane & 15;
  const int fk = lane >> 4;
  for (int s = 0; s < 6; s++) {
    __syncthreads();
    #pragma unroll
    for (int j = 0; j < 4; j++) {
      *(bf16x8*)(qdst + j*8) = *(const bf16x8*)(qsrc + s*32 + j*8);
      *(bf16x8*)(kdst + j*8) = *(const bf16x8*)(ksrc + s*32 + j*8);
    }
    __syncthreads();
    bf16x8 ah[4], al[4], bh[4], bl[4];
    #pragma unroll
    for (int i = 0; i < 4; i++) {
      ah[i] = *(const bf16x8*)(qs + (      wr + i*16 + fr) * LDSROW + fk*8);
      al[i] = *(const bf16x8*)(qs + (128 + wr + i*16 + fr) * LDSROW + fk*8);
      bh[i] = *(const bf16x8*)(ks + (      wc + i*16 + fr) * LDSROW + fk*8);
      bl[i] = *(const bf16x8*)(ks + (128 + wc + i*16 + fr) * LDSROW + fk*8);
    }
    #pragma unroll
    for (int i = 0; i < 4; i++)
      #pragma unroll
      for (int j = 0; j < 4; j++) {
        acc[i][j] = __builtin_amdgcn_mfma_f32_16x16x32_bf16(ah[i], bh[j], acc[i][j], 0, 0, 0);
        acc[i][j] = __builtin_amdgcn_mfma_f32_16x16x32_bf16(ah[i], bl[j], acc[i][j], 0, 0, 0);
        acc[i][j] = __builtin_amdgcn_mfma_f32_16x16x32_bf16(al[i], bh[j], acc[i][j], 0, 0, 0);
      }
  }
  const float temp = tp[0];
  #pragma unroll
  for (int i = 0; i < 4; i++)
    #pragma unroll
    for (int j = 0; j < 4; j++)
      #pragma unroll
      for (int r = 0; r < 4; r++) {
        const int nn = n0 + wr + i*16 + (lane >> 4)*4 + r;
        const int mm = m0 + wc + j*16 + (lane & 15);
        attn[(long)nn*4096 + mm] = acc[i][j][r] * temp;
      }
}

// ------- top-5 + local mask + softmax + sparse out -------
#define CAP 128
__global__ __launch_bounds__(256) void attn_out_k(
    const float* __restrict__ attn, const float* __restrict__ vs,
    float* __restrict__ outr)
{
  __shared__ float row[4096];
  __shared__ float top5[256*5];
  __shared__ int   lm[CAP];
  __shared__ float lw[CAP];
  __shared__ float ses[CAP];
  __shared__ float redf[8];
  __shared__ int   scan[256];
  const int t = threadIdx.x;
  const int n = blockIdx.x;
  const float* ar = attn + (long)n * 4096;
  #pragma unroll
  for (int k = 0; k < 16; k++) row[k*256 + t] = ar[k*256 + t];
  __syncthreads();
  float t0=-INFINITY,t1=-INFINITY,t2=-INFINITY,t3=-INFINITY,t4=-INFINITY;
  #pragma unroll
  for (int k = 0; k < 16; k++) {
    float v = row[k*256 + t];
    if (v > t4) {
      if (v > t0)      { t4=t3; t3=t2; t2=t1; t1=t0; t0=v; }
      else if (v > t1) { t4=t3; t3=t2; t2=t1; t1=v; }
      else if (v > t2) { t4=t3; t3=t2; t2=v; }
      else if (v > t3) { t4=t3; t3=v; }
      else             { t4=v; }
    }
  }
  top5[t*5+0]=t0; top5[t*5+1]=t1; top5[t*5+2]=t2; top5[t*5+3]=t3; top5[t*5+4]=t4;
  __syncthreads();
  for (int s = 128; s >= 1; s >>= 1) {
    if (t < s) {
      float* A = &top5[t*5];
      const float* B = &top5[(t+s)*5];
      float m[5]; int i = 0, j = 0;
      #pragma unroll
      for (int k = 0; k < 5; k++) {
        float av = A[i], bv = B[j];
        if (av >= bv) { m[k] = av; i++; } else { m[k] = bv; j++; }
      }
      #pragma unroll
      for (int k = 0; k < 5; k++) A[k] = m[k];
    }
    __syncthreads();
  }
  const float kth = top5[4];
  const int y = n >> 6, x = n & 63;
  int myc = 0;
  float wmax = -INFINITY;
  #pragma unroll
  for (int k = 0; k < 16; k++) {
    int m = k*256 + t;
    float a = row[m];
    int c = ((a >= kth) ? 1 : 0) +
            (((iabs_(y - (m >> 6)) + iabs_(x - (m & 63))) <= 4) ? 1 : 0);
    float wv = a * (float)c;
    if (wv != 0.0f) { myc++; wmax = fmaxf(wmax, wv); }
  }
  scan[t] = myc;
  __syncthreads();
  for (int s = 1; s < 256; s <<= 1) {
    int v = (t >= s) ? scan[t-s] : 0;
    __syncthreads();
    scan[t] += v;
    __syncthreads();
  }
  const int base = scan[t] - myc;
  const int cnt = scan[255];
  {
    int idx = base;
    #pragma unroll
    for (int k = 0; k < 16; k++) {
      int m = k*256 + t;
      float a = row[m];
      int c = ((a >= kth) ? 1 : 0) +
              (((iabs_(y - (m >> 6)) + iabs_(x - (m & 63))) <= 4) ? 1 : 0);
      float wv = a * (float)c;
      if (wv != 0.0f && idx < CAP) { lm[idx] = m; lw[idx] = wv; idx++; }
    }
  }
  #pragma unroll
  for (int s = 1; s < 64; s <<= 1) wmax = fmaxf(wmax, __shfl_xor(wmax, s, 64));
  if ((t & 63) == 0) redf[t >> 6] = wmax;
  __syncthreads();
  const float gmax = fmaxf(fmaxf(redf[0], redf[1]), fmaxf(redf[2], redf[3]));
  __syncthreads();
  if (t < cnt && t < CAP) ses[t] = expf(lw[t] - gmax);
  __syncthreads();
  float ps = (t < cnt && t < CAP) ? ses[t] : 0.f;
  #pragma unroll
  for (int s = 1; s < 64; s <<= 1) ps += __shfl_xor(ps, s, 64);
  if ((t & 63) == 0) redf[4 + (t >> 6)] = ps;
  __syncthreads();
  const float S = redf[4] + redf[5] + redf[6] + redf[7];
  const float invS = 1.0f / S;
  float a0=0,a1=0,a2=0,a3=0,a4=0,a5=0;
  const int ecnt = (cnt < CAP) ? cnt : CAP;
  for (int e = 0; e < ecnt; e++) {
    float se = ses[e] * invS;
    const float* vr = vs + (long)lm[e] * 1536;
    a0 = fmaf(se, vr[        t], a0);
    a1 = fmaf(se, vr[ 256 + t], a1);
    a2 = fmaf(se, vr[ 512 + t], a2);
    a3 = fmaf(se, vr[ 768 + t], a3);
    a4 = fmaf(se, vr[1024 + t], a4);
    a5 = fmaf(se, vr[1280 + t], a5);
  }
  float* orow = outr + (long)n * 1536;
  orow[        t] = a0;
  orow[ 256 + t] = a1;
  orow[ 512 + t] = a2;
  orow[ 768 + t] = a3;
  orow[1024 + t] = a4;
  orow[1280 + t] = a5;
}

// ------- per-channel l2 norm over 65536 (fhr q2/k2); in-place safe -------
__global__ __launch_bounds__(1024) void l2n_sp(
    const float* __restrict__ in, float* __restrict__ out)
{
  const int ch = blockIdx.x, b = blockIdx.y, t = threadIdx.x;
  const float* ip = in + ((long)b*96 + ch) * HW;
  float ss = 0.f;
  for (int i = t; i < 65536; i += 1024) { float v = ip[i]; ss = fmaf(v, v, ss); }
  __shared__ float red[16];
  #pragma unroll
  for (int s = 1; s < 64; s <<= 1) ss += __shfl_xor(ss, s, 64);
  if ((t & 63) == 0) red[t >> 6] = ss;
  __syncthreads();
  if (t == 0) {
    float s2 = 0.f;
    for (int i = 0; i < 16; i++) s2 += red[i];
    red[0] = fmaxf(sqrtf(s2), 1e-12f);
  }
  __syncthreads();
  const float nrm = red[0];
  float* op = out + ((long)b*96 + ch) * HW;
  for (int i = t; i < 65536; i += 1024) op[i] = ip[i] / nrm;
}

// -------- a2 stage 1: partial Gram (12x12) over 4096-elem chunks ------------
#define A2_NCH 16
__global__ __launch_bounds__(256) void a2_part(
    const float* __restrict__ q2n, const float* __restrict__ k2n,
    float* __restrict__ part)
{
  __shared__ float sh[24*260];
  const int t = threadIdx.x;
  const int ch = blockIdx.x, h = blockIdx.y, b = blockIdx.z;
  const long base = ((long)b*96 + h*12) * HW + ch*4096;
  const int c = t / 12, d = t - (t/12)*12;
  float acc = 0.f;
  for (int sub = 0; sub < 16; sub++) {
    __syncthreads();
    #pragma unroll
    for (int j = 0; j < 6; j++) {
      const int v = j*256 + t;
      const int row = v >> 6;
      const int col4 = v & 63;
      const float* src = (row < 12)
        ? q2n + base + (long)row*HW + sub*256 + col4*4
        : k2n + base + (long)(row-12)*HW + sub*256 + col4*4;
      *(float4*)&sh[row*260 + col4*4] = *(const float4*)src;
    }
    __syncthreads();
    if (t < 144) {
      const float* qr = &sh[c*260];
      const float* kr = &sh[(12+d)*260];
      #pragma unroll
      for (int i4 = 0; i4 < 64; i4++) {
        float4 qv = *(const float4*)&qr[i4*4];
        float4 kv = *(const float4*)&kr[i4*4];
        acc = fmaf(qv.x, kv.x, acc);
        acc = fmaf(qv.y, kv.y, acc);
        acc = fmaf(qv.z, kv.z, acc);
        acc = fmaf(qv.w, kv.w, acc);
      }
    }
  }
  if (t < 144)
    part[(((long)b*8 + h)*A2_NCH + ch)*144 + t] = acc;
}

// -------- a2 stage 2 --------
__global__ __launch_bounds__(256) void a2_fin(
    const float* __restrict__ part, const float* __restrict__ temp,
    float* __restrict__ a2s)
{
  __shared__ float m[144];
  const int t = threadIdx.x;
  const int h = blockIdx.x, b = blockIdx.y;
  if (t < 144) {
    float s = 0.f;
    const float* pp = part + (((long)b*8 + h)*A2_NCH)*144 + t;
    #pragma unroll
    for (int ch = 0; ch < A2_NCH; ch++) s += pp[ch*144];
    m[t] = s * temp[h];
  }
  __syncthreads();
  if (t < 12) {
    float mx = -INFINITY;
    #pragma unroll
    for (int d = 0; d < 12; d++) mx = fmaxf(mx, m[t*12+d]);
    float e[12], sum = 0.f;
    #pragma unroll
    for (int d = 0; d < 12; d++) { e[d] = expf(m[t*12+d]-mx); sum += e[d]; }
    float inv = 1.0f/sum;
    float* op = a2s + (((long)b*8 + h)*12 + t)*12;
    #pragma unroll
    for (int d = 0; d < 12; d++) op[d] = e[d]*inv;
  }
}

// ---------------- o2pre = a2 @ v2 ----------------
__global__ __launch_bounds__(256) void o2pre_kern(
    const float* __restrict__ a2s, const float* __restrict__ v2,
    float* __restrict__ o2p)
{
  const int t = threadIdx.x;
  const int n = blockIdx.x * 256 + t;
  const int bh = blockIdx.y, b = bh >> 3, h = bh & 7;
  const float* a = a2s + (long)bh * 144;
  const float* vb = v2 + ((long)b*96 + h*12) * HW;
  float vv[12];
  #pragma unroll
  for (int d = 0; d < 12; d++) vv[d] = vb[(long)d*HW + n];
  float* ob = o2p + ((long)b*96 + h*12) * HW;
  #pragma unroll
  for (int c = 0; c < 12; c++) {
    float s = 0.f;
    #pragma unroll
    for (int d = 0; d < 12; d++) s = fmaf(a[c*12 + d], vv[d], s);
    ob[(long)c*HW + n] = s;
  }
}

extern "C" void kernel_launch(void* const* d_in, const int* in_sizes, int n_in,
                              void* d_out, int out_size, void* d_ws, size_t ws_size,
                              hipStream_t stream) {
  const float* x        = (const float*)d_in[0];
  const float* qk_w     = (const float*)d_in[1];
  const float* qk_dw    = (const float*)d_in[2];
  const float* v_w      = (const float*)d_in[3];
  const float* v_dw     = (const float*)d_in[4];
  const float* k2_w     = (const float*)d_in[5];
  const float* k2_dw    = (const float*)d_in[6];
  const float* q2_w     = (const float*)d_in[7];
  const float* q2_dw    = (const float*)d_in[8];
  const float* proj_w   = (const float*)d_in[9];
  const float* sab_temp = (const float*)d_in[10];
  const float* fqkv_w   = (const float*)d_in[11];
  const float* fqkv_dw  = (const float*)d_in[12];
  const float* fproj_w  = (const float*)d_in[13];
  const float* fhr_temp = (const float*)d_in[14];
  float* out = (float*)d_out;
  float* ws  = (float*)d_ws;

  float* O2  = out;
  float* KS  = out + 12582912;
  float* VS  = out + 14155776;
  float* K2N = out + 26738688;
  float* V2  = out + 39321600;

  float* A0   = ws;
  float* A1   = ws + 25165824;
  float* QD   = ws + 50331648;
  float* KD   = ws + 51904512;
  float* QN   = ws + 53477376;
  float* A2S  = ws + 55050240;
  float* PART = ws + 55052544;
  unsigned short* QSP = (unsigned short*)(A0 + 16777216);
  unsigned short* KSP = (unsigned short*)(A0 + 16777216 + 786432);
  unsigned short* WHL = (unsigned short*)QN;
  // fhr-phase layout (after attention): ALN = ws[0:12.58M], PRE = ws[12.58M:50.33M]
  float* ALN = ws;
  float* PRE = ws + 12582912;
  float* OB  = ws + 12582912;   // o2pre output (PRE dead by then)

  dim3 b256(256), b1024(1024);

  wsplit<<<dim3(432), b256, 0, stream>>>(qk_w, v_w, q2_w, k2_w, proj_w, fqkv_w, fproj_w, WHL);
  conv1x1_mfma<<<dim3(512,2), b256, 0, stream>>>(x, 96L*HW, WHL, 0, A0, 192L*HW, 12, 0);
  dw3x3v<<<dim3(64,192,2), b256, 0, stream>>>(A0, 192, qk_dw, A1, 192);
  conv1x1_mfma<<<dim3(512,2), b256, 0, stream>>>(x, 96L*HW, WHL, 192, A0, 96L*HW, 6, 0);
  dw3x3_vs<<<dim3(1024,2), b256, 0, stream>>>(A0, v_dw, VS);
  conv1x1_mfma<<<dim3(512,2), b256, 0, stream>>>(A1, 192L*HW, WHL, 288, A0, 192L*HW, 12, 0);
  dw4x4s4<<<dim3(16,192,2), b256, 0, stream>>>(A0, q2_dw, QD);
  conv1x1_mfma<<<dim3(512,2), b256, 0, stream>>>(A1 + 96L*HW, 192L*HW, WHL, 480, A0, 192L*HW, 12, 0);
  dw4x4s4<<<dim3(16,192,2), b256, 0, stream>>>(A0, k2_dw, KD);
  l2n192<<<dim3(2048), b256, 0, stream>>>(QD, QN);
  l2n192<<<dim3(2048), b256, 0, stream>>>(KD, KS);
  for (int b = 0; b < 2; b++) {
    bf16split<<<dim3(3072), b256, 0, stream>>>(QN + (long)b*786432, QSP);
    bf16split<<<dim3(3072), b256, 0, stream>>>(KS + (long)b*786432, KSP);
    attn_qk_mfma<<<dim3(32,32), b256, 0, stream>>>(QSP, KSP, A0, sab_temp);
    attn_out_k<<<dim3(4096), b256, 0, stream>>>(
        A0, VS + (long)b*6291456, A1 + (long)b*6291456);
  }
  // re-split weights (QN slot was clobbered by step 9)
  wsplit<<<dim3(432), b256, 0, stream>>>(qk_w, v_w, q2_w, k2_w, proj_w, fqkv_w, fproj_w, WHL);
  // 12) aligned = 1x1(permuted attn-out, proj_w) -> ALN = ws[0:12.58M]
  conv1x1_mfma<<<dim3(512,2), b256, 0, stream>>>(A1, 6291456L, WHL, 672, ALN, 96L*HW, 6, 1);
  // 13) FUSED fhr qkv conv: Cout=288 -> PRE (ws[12.58M:50.33M])
  conv1x1_mfma<<<dim3(512,2), b256, 0, stream>>>(ALN, 96L*HW, WHL, 768, PRE, 288L*HW, 18, 0);
  // 14) three depthwise passes on PRE channel groups (ALN dead -> reuse for q2dw)
  dw3x3v<<<dim3(64,96,2), b256, 0, stream>>>(PRE,            288, fqkv_dw,        ALN, 96);
  dw3x3v<<<dim3(64,96,2), b256, 0, stream>>>(PRE +  96L*HW, 288, fqkv_dw +  864, K2N, 96);
  dw3x3v<<<dim3(64,96,2), b256, 0, stream>>>(PRE + 192L*HW, 288, fqkv_dw + 1728, V2,  96);
  // 15) l2 norms in place
  l2n_sp<<<dim3(96,2), b1024, 0, stream>>>(ALN, ALN);
  l2n_sp<<<dim3(96,2), b1024, 0, stream>>>(K2N, K2N);
  // 16) a2 two-stage
  a2_part<<<dim3(A2_NCH,8,2), b256, 0, stream>>>(ALN, K2N, PART);
  a2_fin<<<dim3(8,2), b256, 0, stream>>>(PART, fhr_temp, A2S);
  // 17) o2pre -> OB (PRE region, dead)
  o2pre_kern<<<dim3(256,16), b256, 0, stream>>>(A2S, V2, OB);
  // 18) o2 = 1x1(o2pre, fproj_w) -> d_out
  conv1x1_mfma<<<dim3(512,2), b256, 0, stream>>>(OB, 96L*HW, WHL, 1056, O2, 96L*HW, 6, 0);
}

// Round 12
// 897.608 us; speedup vs baseline: 2.1422x; 1.0066x over previous
//
#include <hip/hip_runtime.h>
#include <hip/hip_bf16.h>
#include <math.h>

#define HW 65536L

typedef __attribute__((ext_vector_type(8))) short bf16x8;
typedef __attribute__((ext_vector_type(4))) float f32x4;

__device__ __forceinline__ int iabs_(int v) { return v < 0 ? -v : v; }

// ---- split all 1x1 weights into (hi,lo) bf16 planes: whl[2][1152][96] ----
__global__ __launch_bounds__(256) void wsplit(
    const float* __restrict__ qk, const float* __restrict__ v,
    const float* __restrict__ q2, const float* __restrict__ k2,
    const float* __restrict__ pj, const float* __restrict__ fq,
    const float* __restrict__ fp, unsigned short* __restrict__ whl)
{
  const int e = blockIdx.x*256 + threadIdx.x;
  if (e >= 110592) return;
  const int row = e / 96, col = e - row*96;
  float f;
  if      (row <  192) f = qk[e];
  else if (row <  288) f = v [(row-192)*96+col];
  else if (row <  480) f = q2[(row-288)*96+col];
  else if (row <  672) f = k2[(row-480)*96+col];
  else if (row <  768) f = pj[(row-672)*96+col];
  else if (row < 1056) f = fq[(row-768)*96+col];
  else                 f = fp[(row-1056)*96+col];
  __hip_bfloat16 h = __float2bfloat16(f);
  float hf = __bfloat162float(h);
  __hip_bfloat16 l = __float2bfloat16(f - hf);
  whl[e]          = *(unsigned short*)&h;
  whl[110592 + e] = *(unsigned short*)&l;
}

// ---------------- conv 1x1 via split-bf16 MFMA (packed trunc staging) ---
#define BLDS 104
__global__ __launch_bounds__(256) void conv1x1_mfma(
    const float* __restrict__ in, long in_bstride,
    const unsigned short* __restrict__ whl, int wrow0,
    float* __restrict__ out, long out_bstride,
    int mtiles, int mode)
{
  __shared__ unsigned short bhs[128*BLDS];
  __shared__ unsigned short bls[128*BLDS];
  const int t = threadIdx.x;
  const int p0 = blockIdx.x * 128;
  const int b = blockIdx.y;
  if (mode == 0) {
    #pragma unroll
    for (int it = 0; it < 12; it++) {
      const int idx = it*256 + t;
      const int g = idx >> 7;
      const int pix = idx & 127;
      const float* src = in + (long)b*in_bstride + (long)(g*4)*HW + p0 + pix;
      unsigned hh[4], ll[4];
      #pragma unroll
      for (int j = 0; j < 4; j++) {
        float f = src[(long)j*HW];
        unsigned u = __float_as_uint(f);
        hh[j] = u >> 16;
        float lof = f - __uint_as_float(u & 0xFFFF0000u);
        __hip_bfloat16 lb = __float2bfloat16(lof);
        ll[j] = *(unsigned short*)&lb;
      }
      uint2 hv, lv;
      hv.x = hh[0] | (hh[1] << 16); hv.y = hh[2] | (hh[3] << 16);
      lv.x = ll[0] | (ll[1] << 16); lv.y = ll[2] | (ll[3] << 16);
      *(uint2*)(bhs + pix*BLDS + g*4) = hv;
      *(uint2*)(bls + pix*BLDS + g*4) = lv;
    }
  } else {
    const int pp = t >> 1, half = (t & 1)*48;
    const int p = p0 + pp;
    const int py = p >> 8, px = p & 255;
    const float* src = in + (long)b*in_bstride
        + ((long)((py & 63)*64 + (px & 63))*16 + ((py >> 6)*4 + (px >> 6)))*96 + half;
    #pragma unroll
    for (int j4 = 0; j4 < 12; j4++) {
      float4 v4 = *(const float4*)&src[j4*4];
      float fv[4] = {v4.x, v4.y, v4.z, v4.w};
      unsigned hh[4], ll[4];
      #pragma unroll
      for (int u4 = 0; u4 < 4; u4++) {
        unsigned u = __float_as_uint(fv[u4]);
        hh[u4] = u >> 16;
        float lof = fv[u4] - __uint_as_float(u & 0xFFFF0000u);
        __hip_bfloat16 lb = __float2bfloat16(lof);
        ll[u4] = *(unsigned short*)&lb;
      }
      uint2 hv, lv;
      hv.x = hh[0] | (hh[1] << 16); hv.y = hh[2] | (hh[3] << 16);
      lv.x = ll[0] | (ll[1] << 16); lv.y = ll[2] | (ll[3] << 16);
      *(uint2*)(bhs + pp*BLDS + half + j4*4) = hv;
      *(uint2*)(bls + pp*BLDS + half + j4*4) = lv;
    }
  }
  __syncthreads();
  const int lane = t & 63, w = t >> 6;
  const int fr = lane & 15, fk = lane >> 4;
  bf16x8 Bh[2][3], Bl[2][3];
  #pragma unroll
  for (int nt = 0; nt < 2; nt++)
    #pragma unroll
    for (int kt = 0; kt < 3; kt++) {
      const int pix = w*32 + nt*16 + fr;
      Bh[nt][kt] = *(const bf16x8*)(bhs + pix*BLDS + kt*32 + fk*8);
      Bl[nt][kt] = *(const bf16x8*)(bls + pix*BLDS + kt*32 + fk*8);
    }
  float* dst = out + (long)b*out_bstride + p0 + w*32;
  for (int m = 0; m < mtiles; m++) {
    const long wbase = (long)(wrow0 + m*16 + fr)*96 + fk*8;
    bf16x8 Ah[3], Al[3];
    #pragma unroll
    for (int kt = 0; kt < 3; kt++) {
      Ah[kt] = *(const bf16x8*)(whl + wbase + kt*32);
      Al[kt] = *(const bf16x8*)(whl + 110592 + wbase + kt*32);
    }
    f32x4 acc[2] = {};
    #pragma unroll
    for (int nt = 0; nt < 2; nt++)
      #pragma unroll
      for (int kt = 0; kt < 3; kt++) {
        acc[nt] = __builtin_amdgcn_mfma_f32_16x16x32_bf16(Ah[kt], Bh[nt][kt], acc[nt], 0, 0, 0);
        acc[nt] = __builtin_amdgcn_mfma_f32_16x16x32_bf16(Ah[kt], Bl[nt][kt], acc[nt], 0, 0, 0);
        acc[nt] = __builtin_amdgcn_mfma_f32_16x16x32_bf16(Al[kt], Bh[nt][kt], acc[nt], 0, 0, 0);
      }
    #pragma unroll
    for (int nt = 0; nt < 2; nt++)
      #pragma unroll
      for (int r = 0; r < 4; r++)
        dst[(long)(m*16 + fk*4 + r)*HW + nt*16 + fr] = acc[nt][r];
  }
}

// -------- depthwise 3x3 pad 1, 4-wide vectorized --------
__global__ __launch_bounds__(256) void dw3x3v(
    const float* __restrict__ in, int inCH, const float* __restrict__ w,
    float* __restrict__ out, int outCH)
{
  const int t = threadIdx.x;
  const int p4 = blockIdx.x * 256 + t;
  const int ch = blockIdx.y, b = blockIdx.z;
  const int y = p4 >> 6, x0 = (p4 & 63) << 2;
  const float* ip = in + ((long)b*inCH + ch) * HW;
  const float* wp = w + ch*9;
  float a0 = 0.f, a1 = 0.f, a2 = 0.f, a3 = 0.f;
  #pragma unroll
  for (int dy = -1; dy <= 1; dy++) {
    const int yy = y + dy;
    if (yy < 0 || yy > 255) continue;
    const float* rp = ip + yy*256;
    const float4 c = *(const float4*)&rp[x0];
    const float left  = (x0 > 0)   ? rp[x0-1] : 0.f;
    const float right = (x0 < 252) ? rp[x0+4] : 0.f;
    const float w0 = wp[(dy+1)*3+0], w1 = wp[(dy+1)*3+1], w2 = wp[(dy+1)*3+2];
    a0 = fmaf(left, w0, a0); a0 = fmaf(c.x, w1, a0); a0 = fmaf(c.y, w2, a0);
    a1 = fmaf(c.x,  w0, a1); a1 = fmaf(c.y, w1, a1); a1 = fmaf(c.z, w2, a1);
    a2 = fmaf(c.y,  w0, a2); a2 = fmaf(c.z, w1, a2); a2 = fmaf(c.w, w2, a2);
    a3 = fmaf(c.z,  w0, a3); a3 = fmaf(c.w, w1, a3); a3 = fmaf(right, w2, a3);
  }
  float4 o; o.x = a0; o.y = a1; o.z = a2; o.w = a3;
  *(float4*)&out[((long)b*outCH + ch)*HW + y*256 + x0] = o;
}

// ------- depthwise 3x3 fused with v_s permutation (4-wide compute) ----
__global__ __launch_bounds__(256) void dw3x3_vs(
    const float* __restrict__ in, const float* __restrict__ w,
    float* __restrict__ vs)
{
  __shared__ float tile[96*65];
  const int t = threadIdx.x;
  const int gb = blockIdx.x;
  const int b = blockIdx.y;
  const int y = gb >> 2, xb = gb & 3;
  #pragma unroll
  for (int i = 0; i < 6; i++) {
    const int idx = i*256 + t;
    const int ci = idx >> 4, q = idx & 15;
    const int x0 = xb*64 + q*4;
    const float* ip = in + ((long)b*96 + ci) * HW;
    const float* wp = w + ci*9;
    float a0 = 0.f, a1 = 0.f, a2 = 0.f, a3 = 0.f;
    #pragma unroll
    for (int dy = -1; dy <= 1; dy++) {
      const int yy = y + dy;
      if (yy < 0 || yy > 255) continue;
      const float* rp = ip + yy*256;
      const float4 c = *(const float4*)&rp[x0];
      const float left  = (x0 > 0)   ? rp[x0-1] : 0.f;
      const float right = (x0 < 252) ? rp[x0+4] : 0.f;
      const float w0 = wp[(dy+1)*3+0], w1 = wp[(dy+1)*3+1], w2 = wp[(dy+1)*3+2];
      a0 = fmaf(left, w0, a0); a0 = fmaf(c.x, w1, a0); a0 = fmaf(c.y, w2, a0);
      a1 = fmaf(c.x,  w0, a1); a1 = fmaf(c.y, w1, a1); a1 = fmaf(c.z, w2, a1);
      a2 = fmaf(c.y,  w0, a2); a2 = fmaf(c.z, w1, a2); a2 = fmaf(c.w, w2, a2);
      a3 = fmaf(c.z,  w0, a3); a3 = fmaf(c.w, w1, a3); a3 = fmaf(right, w2, a3);
    }
    const int xl = q*4;
    tile[ci*65 + xl    ] = a0;
    tile[ci*65 + xl + 1] = a1;
    tile[ci*65 + xl + 2] = a2;
    tile[ci*65 + xl + 3] = a3;
  }
  __syncthreads();
  const int blk = (y >> 6)*4 + xb;
  float* obase = vs + ((long)b*4096 + (long)(y & 63)*64) * 1536 + blk*96;
  #pragma unroll
  for (int i = 0; i < 24; i++) {
    const int idx = i*256 + t;
    const int nl = idx / 96, ci = idx % 96;
    obase[(long)nl*1536 + ci] = tile[ci*65 + nl];
  }
}

// ---- depthwise 4x4 stride 4 pad 1 (256->64), 4-wide vectorized (R12) ----
__global__ __launch_bounds__(256) void dw4x4s4v(
    const float* __restrict__ in, const float* __restrict__ w,
    float* __restrict__ out)
{
  const int t = threadIdx.x;
  const int p = blockIdx.x*256 + t;        // 0..1023: oy*16 + qx
  const int ch = blockIdx.y, b = blockIdx.z;
  const int oy = p >> 4, qx = p & 15;
  const int x0 = qx*16;
  const float* ip = in + (long)(b*192 + ch) * HW;
  const float* wp = w + ch*16;
  float a0 = 0.f, a1 = 0.f, a2 = 0.f, a3 = 0.f;
  #pragma unroll
  for (int ty = 0; ty < 4; ty++) {
    const int iy = 4*oy + ty - 1;
    if (iy < 0 || iy > 255) continue;
    const float* rp = ip + iy*256;
    float r[17];
    r[0] = (x0 > 0) ? rp[x0-1] : 0.f;
    #pragma unroll
    for (int k = 0; k < 4; k++) {
      float4 v4 = *(const float4*)&rp[x0 + k*4];
      r[1+k*4+0]=v4.x; r[1+k*4+1]=v4.y; r[1+k*4+2]=v4.z; r[1+k*4+3]=v4.w;
    }
    const float w0=wp[ty*4+0], w1=wp[ty*4+1], w2=wp[ty*4+2], w3=wp[ty*4+3];
    a0=fmaf(r[ 0],w0,a0); a0=fmaf(r[ 1],w1,a0); a0=fmaf(r[ 2],w2,a0); a0=fmaf(r[ 3],w3,a0);
    a1=fmaf(r[ 4],w0,a1); a1=fmaf(r[ 5],w1,a1); a1=fmaf(r[ 6],w2,a1); a1=fmaf(r[ 7],w3,a1);
    a2=fmaf(r[ 8],w0,a2); a2=fmaf(r[ 9],w1,a2); a2=fmaf(r[10],w2,a2); a2=fmaf(r[11],w3,a2);
    a3=fmaf(r[12],w0,a3); a3=fmaf(r[13],w1,a3); a3=fmaf(r[14],w2,a3); a3=fmaf(r[15],w3,a3);
  }
  float4 o; o.x=a0; o.y=a1; o.z=a2; o.w=a3;
  *(float4*)&out[(long)(b*192 + ch)*4096 + oy*64 + qx*4] = o;
}

// ---------------- l2 norm over 192 channels + transpose to (B,4096,192) ----
__global__ __launch_bounds__(256) void l2n192(
    const float* __restrict__ in, float* __restrict__ out)
{
  const int t = threadIdx.x;
  const int wid = t >> 6, lane = t & 63;
  const int gw = blockIdx.x * 4 + wid;
  const int b = gw >> 12, n = gw & 4095;
  const float* ip = in + (long)b * 786432;
  float v0 = ip[(long)(lane      ) * 4096 + n];
  float v1 = ip[(long)(lane +  64) * 4096 + n];
  float v2 = ip[(long)(lane + 128) * 4096 + n];
  float ss = v0*v0 + v1*v1 + v2*v2;
  #pragma unroll
  for (int s = 1; s < 64; s <<= 1) ss += __shfl_xor(ss, s, 64);
  float nrm = fmaxf(sqrtf(ss), 1e-12f);
  float* op = out + ((long)b*4096 + n) * 192;
  op[lane      ] = v0 / nrm;
  op[lane +  64] = v1 / nrm;
  op[lane + 128] = v2 / nrm;
}

// ---------------- split fp32 -> (hi,lo) bf16 planes ----------------
__global__ __launch_bounds__(256) void bf16split(
    const float* __restrict__ in, unsigned short* __restrict__ outp)
{
  const int i = blockIdx.x * 256 + threadIdx.x;
  const int n = i / 192, k = i % 192;
  float f = in[i];
  __hip_bfloat16 h = __float2bfloat16(f);
  float hf = __bfloat162float(h);
  __hip_bfloat16 l = __float2bfloat16(f - hf);
  outp[(long)n*384 + k]       = *(unsigned short*)&h;
  outp[(long)n*384 + 192 + k] = *(unsigned short*)&l;
}

// ---------------- attention QK^T via split-bf16 MFMA (one batch) ------------
#define LDSROW 40
__global__ __launch_bounds__(256) void attn_qk_mfma(
    const unsigned short* __restrict__ Qsp, const unsigned short* __restrict__ Ksp,
    float* __restrict__ attn, const float* __restrict__ tp)
{
  __shared__ unsigned short qs[256*LDSROW];
  __shared__ unsigned short ks[256*LDSROW];
  const int t = threadIdx.x;
  const int lane = t & 63, w = t >> 6;
  const int n0 = blockIdx.x * 128;
  const int m0 = blockIdx.y * 128;
  const int wr = (w >> 1) * 64, wc = (w & 1) * 64;
  f32x4 acc[4][4] = {};
  const int srow = t & 127;
  const int shl  = t >> 7;
  const unsigned short* qsrc = Qsp + (long)(n0 + srow) * 384 + shl * 192;
  const unsigned short* ksrc = Ksp + (long)(m0 + srow) * 384 + shl * 192;
  unsigned short* qdst = qs + (shl*128 + srow) * LDSROW;
  unsigned short* kdst = ks + (shl*128 + srow) * LDSROW;
  const int fr = lane & 15;
  const int fk = lane >> 4;
  for (int s = 0; s < 6; s++) {
    __syncthreads();
    #pragma unroll
    for (int j = 0; j < 4; j++) {
      *(bf16x8*)(qdst + j*8) = *(const bf16x8*)(qsrc + s*32 + j*8);
      *(bf16x8*)(kdst + j*8) = *(const bf16x8*)(ksrc + s*32 + j*8);
    }
    __syncthreads();
    bf16x8 ah[4], al[4], bh[4], bl[4];
    #pragma unroll
    for (int i = 0; i < 4; i++) {
      ah[i] = *(const bf16x8*)(qs + (      wr + i*16 + fr) * LDSROW + fk*8);
      al[i] = *(const bf16x8*)(qs + (128 + wr + i*16 + fr) * LDSROW + fk*8);
      bh[i] = *(const bf16x8*)(ks + (      wc + i*16 + fr) * LDSROW + fk*8);
      bl[i] = *(const bf16x8*)(ks + (128 + wc + i*16 + fr) * LDSROW + fk*8);
    }
    #pragma unroll
    for (int i = 0; i < 4; i++)
      #pragma unroll
      for (int j = 0; j < 4; j++) {
        acc[i][j] = __builtin_amdgcn_mfma_f32_16x16x32_bf16(ah[i], bh[j], acc[i][j], 0, 0, 0);
        acc[i][j] = __builtin_amdgcn_mfma_f32_16x16x32_bf16(ah[i], bl[j], acc[i][j], 0, 0, 0);
        acc[i][j] = __builtin_amdgcn_mfma_f32_16x16x32_bf16(al[i], bh[j], acc[i][j], 0, 0, 0);
      }
  }
  const float temp = tp[0];
  #pragma unroll
  for (int i = 0; i < 4; i++)
    #pragma unroll
    for (int j = 0; j < 4; j++)
      #pragma unroll
      for (int r = 0; r < 4; r++) {
        const int nn = n0 + wr + i*16 + (lane >> 4)*4 + r;
        const int mm = m0 + wc + j*16 + (lane & 15);
        attn[(long)nn*4096 + mm] = acc[i][j][r] * temp;
      }
}

// ------- top-5 + local mask + softmax + sparse out (R12: wave scan) -------
#define CAP 128
__global__ __launch_bounds__(256) void attn_out_k(
    const float* __restrict__ attn, const float* __restrict__ vs,
    float* __restrict__ outr)
{
  __shared__ float row[4096];
  __shared__ float top5[256*5];
  __shared__ int   lm[CAP];
  __shared__ float lw[CAP];
  __shared__ float ses[CAP];
  __shared__ float redf[8];
  __shared__ int   wsum[4];
  const int t = threadIdx.x;
  const int n = blockIdx.x;
  const float* ar = attn + (long)n * 4096;
  #pragma unroll
  for (int k = 0; k < 16; k++) row[k*256 + t] = ar[k*256 + t];
  __syncthreads();
  float t0=-INFINITY,t1=-INFINITY,t2=-INFINITY,t3=-INFINITY,t4=-INFINITY;
  #pragma unroll
  for (int k = 0; k < 16; k++) {
    float v = row[k*256 + t];
    if (v > t4) {
      if (v > t0)      { t4=t3; t3=t2; t2=t1; t1=t0; t0=v; }
      else if (v > t1) { t4=t3; t3=t2; t2=t1; t1=v; }
      else if (v > t2) { t4=t3; t3=t2; t2=v; }
      else if (v > t3) { t4=t3; t3=v; }
      else             { t4=v; }
    }
  }
  top5[t*5+0]=t0; top5[t*5+1]=t1; top5[t*5+2]=t2; top5[t*5+3]=t3; top5[t*5+4]=t4;
  __syncthreads();
  for (int s = 128; s >= 1; s >>= 1) {
    if (t < s) {
      float* A = &top5[t*5];
      const float* B = &top5[(t+s)*5];
      float m[5]; int i = 0, j = 0;
      #pragma unroll
      for (int k = 0; k < 5; k++) {
        float av = A[i], bv = B[j];
        if (av >= bv) { m[k] = av; i++; } else { m[k] = bv; j++; }
      }
      #pragma unroll
      for (int k = 0; k < 5; k++) A[k] = m[k];
    }
    __syncthreads();
  }
  const float kth = top5[4];
  const int y = n >> 6, x = n & 63;
  int myc = 0;
  float wmax = -INFINITY;
  #pragma unroll
  for (int k = 0; k < 16; k++) {
    int m = k*256 + t;
    float a = row[m];
    int c = ((a >= kth) ? 1 : 0) +
            (((iabs_(y - (m >> 6)) + iabs_(x - (m & 63))) <= 4) ? 1 : 0);
    float wv = a * (float)c;
    if (wv != 0.0f) { myc++; wmax = fmaxf(wmax, wv); }
  }
  // wave-level inclusive scan + cross-wave combine (1 barrier)
  int inc = myc;
  #pragma unroll
  for (int s = 1; s < 64; s <<= 1) {
    int v = __shfl_up(inc, s, 64);
    if ((t & 63) >= s) inc += v;
  }
  if ((t & 63) == 63) wsum[t >> 6] = inc;
  __syncthreads();
  int pre = 0;
  #pragma unroll
  for (int wj = 0; wj < 4; wj++) pre += (wj < (t >> 6)) ? wsum[wj] : 0;
  const int base = pre + inc - myc;
  const int cnt = wsum[0] + wsum[1] + wsum[2] + wsum[3];
  {
    int idx = base;
    #pragma unroll
    for (int k = 0; k < 16; k++) {
      int m = k*256 + t;
      float a = row[m];
      int c = ((a >= kth) ? 1 : 0) +
              (((iabs_(y - (m >> 6)) + iabs_(x - (m & 63))) <= 4) ? 1 : 0);
      float wv = a * (float)c;
      if (wv != 0.0f && idx < CAP) { lm[idx] = m; lw[idx] = wv; idx++; }
    }
  }
  #pragma unroll
  for (int s = 1; s < 64; s <<= 1) wmax = fmaxf(wmax, __shfl_xor(wmax, s, 64));
  if ((t & 63) == 0) redf[t >> 6] = wmax;
  __syncthreads();
  const float gmax = fmaxf(fmaxf(redf[0], redf[1]), fmaxf(redf[2], redf[3]));
  __syncthreads();
  if (t < cnt && t < CAP) ses[t] = expf(lw[t] - gmax);
  __syncthreads();
  float ps = (t < cnt && t < CAP) ? ses[t] : 0.f;
  #pragma unroll
  for (int s = 1; s < 64; s <<= 1) ps += __shfl_xor(ps, s, 64);
  if ((t & 63) == 0) redf[4 + (t >> 6)] = ps;
  __syncthreads();
  const float S = redf[4] + redf[5] + redf[6] + redf[7];
  const float invS = 1.0f / S;
  float a0=0,a1=0,a2=0,a3=0,a4=0,a5=0;
  const int ecnt = (cnt < CAP) ? cnt : CAP;
  for (int e = 0; e < ecnt; e++) {
    float se = ses[e] * invS;
    const float* vr = vs + (long)lm[e] * 1536;
    a0 = fmaf(se, vr[        t], a0);
    a1 = fmaf(se, vr[ 256 + t], a1);
    a2 = fmaf(se, vr[ 512 + t], a2);
    a3 = fmaf(se, vr[ 768 + t], a3);
    a4 = fmaf(se, vr[1024 + t], a4);
    a5 = fmaf(se, vr[1280 + t], a5);
  }
  float* orow = outr + (long)n * 1536;
  orow[        t] = a0;
  orow[ 256 + t] = a1;
  orow[ 512 + t] = a2;
  orow[ 768 + t] = a3;
  orow[1024 + t] = a4;
  orow[1280 + t] = a5;
}

// ------- per-channel l2 norm over 65536 (fhr k2); in-place safe -------
__global__ __launch_bounds__(1024) void l2n_sp(
    const float* __restrict__ in, float* __restrict__ out)
{
  const int ch = blockIdx.x, b = blockIdx.y, t = threadIdx.x;
  const float* ip = in + ((long)b*96 + ch) * HW;
  float ss = 0.f;
  for (int i = t; i < 65536; i += 1024) { float v = ip[i]; ss = fmaf(v, v, ss); }
  __shared__ float red[16];
  #pragma unroll
  for (int s = 1; s < 64; s <<= 1) ss += __shfl_xor(ss, s, 64);
  if ((t & 63) == 0) red[t >> 6] = ss;
  __syncthreads();
  if (t == 0) {
    float s2 = 0.f;
    for (int i = 0; i < 16; i++) s2 += red[i];
    red[0] = fmaxf(sqrtf(s2), 1e-12f);
  }
  __syncthreads();
  const float nrm = red[0];
  float* op = out + ((long)b*96 + ch) * HW;
  for (int i = t; i < 65536; i += 1024) op[i] = ip[i] / nrm;
}

// -------- a2 stage 1 (R12): raw-q Gram + q sum-of-squares partials ----------
// q2n = RAW q2 depthwise output; k2n = normalized k2. G[c][d] = q_c . k_d,
// qq[c] = q_c . q_c. Normalization folded into a2_fin.
#define A2_NCH 16
__global__ __launch_bounds__(256) void a2_part(
    const float* __restrict__ q2n, const float* __restrict__ k2n,
    float* __restrict__ part, float* __restrict__ qqpart)
{
  __shared__ float sh[24*260];
  const int t = threadIdx.x;
  const int ch = blockIdx.x, h = blockIdx.y, b = blockIdx.z;
  const long base = ((long)b*96 + h*12) * HW + ch*4096;
  const int c = t / 12, d = t - (t/12)*12;
  float acc = 0.f;
  float qq = 0.f;
  for (int sub = 0; sub < 16; sub++) {
    __syncthreads();
    #pragma unroll
    for (int j = 0; j < 6; j++) {
      const int v = j*256 + t;
      const int row = v >> 6;
      const int col4 = v & 63;
      const float* src = (row < 12)
        ? q2n + base + (long)row*HW + sub*256 + col4*4
        : k2n + base + (long)(row-12)*HW + sub*256 + col4*4;
      *(float4*)&sh[row*260 + col4*4] = *(const float4*)src;
    }
    __syncthreads();
    if (t < 144) {
      const float* qr = &sh[c*260];
      const float* kr = &sh[(12+d)*260];
      #pragma unroll
      for (int i4 = 0; i4 < 64; i4++) {
        float4 qv = *(const float4*)&qr[i4*4];
        float4 kv = *(const float4*)&kr[i4*4];
        acc = fmaf(qv.x, kv.x, acc);
        acc = fmaf(qv.y, kv.y, acc);
        acc = fmaf(qv.z, kv.z, acc);
        acc = fmaf(qv.w, kv.w, acc);
      }
    } else if (t < 156) {
      const float* qr = &sh[(t-144)*260];
      #pragma unroll
      for (int i4 = 0; i4 < 64; i4++) {
        float4 qv = *(const float4*)&qr[i4*4];
        qq = fmaf(qv.x, qv.x, qq);
        qq = fmaf(qv.y, qv.y, qq);
        qq = fmaf(qv.z, qv.z, qq);
        qq = fmaf(qv.w, qv.w, qq);
      }
    }
  }
  if (t < 144)
    part[(((long)b*8 + h)*A2_NCH + ch)*144 + t] = acc;
  else if (t < 156)
    qqpart[(((long)b*8 + h)*A2_NCH + ch)*12 + (t-144)] = qq;
}

// -------- a2 stage 2 (R12): fold q-normalization --------
__global__ __launch_bounds__(256) void a2_fin(
    const float* __restrict__ part, const float* __restrict__ qqpart,
    const float* __restrict__ temp, float* __restrict__ a2s)
{
  __shared__ float m[144];
  __shared__ float qn[12];
  const int t = threadIdx.x;
  const int h = blockIdx.x, b = blockIdx.y;
  if (t < 144) {
    float s = 0.f;
    const float* pp = part + (((long)b*8 + h)*A2_NCH)*144 + t;
    #pragma unroll
    for (int ch = 0; ch < A2_NCH; ch++) s += pp[ch*144];
    m[t] = s;
  } else if (t < 156) {
    float s = 0.f;
    const float* pp = qqpart + (((long)b*8 + h)*A2_NCH)*12 + (t-144);
    #pragma unroll
    for (int ch = 0; ch < A2_NCH; ch++) s += pp[ch*12];
    qn[t-144] = fmaxf(sqrtf(s), 1e-12f);
  }
  __syncthreads();
  if (t < 12) {
    const float tv = temp[h];
    const float scale = tv / qn[t];
    float mx = -INFINITY;
    float a[12];
    #pragma unroll
    for (int d = 0; d < 12; d++) { a[d] = m[t*12+d] * scale; mx = fmaxf(mx, a[d]); }
    float e[12], sum = 0.f;
    #pragma unroll
    for (int d = 0; d < 12; d++) { e[d] = expf(a[d]-mx); sum += e[d]; }
    float inv = 1.0f/sum;
    float* op = a2s + (((long)b*8 + h)*12 + t)*12;
    #pragma unroll
    for (int d = 0; d < 12; d++) op[d] = e[d]*inv;
  }
}

// ---------------- o2pre = a2 @ v2 ----------------
__global__ __launch_bounds__(256) void o2pre_kern(
    const float* __restrict__ a2s, const float* __restrict__ v2,
    float* __restrict__ o2p)
{
  const int t = threadIdx.x;
  const int n = blockIdx.x * 256 + t;
  const int bh = blockIdx.y, b = bh >> 3, h = bh & 7;
  const float* a = a2s + (long)bh * 144;
  const float* vb = v2 + ((long)b*96 + h*12) * HW;
  float vv[12];
  #pragma unroll
  for (int d = 0; d < 12; d++) vv[d] = vb[(long)d*HW + n];
  float* ob = o2p + ((long)b*96 + h*12) * HW;
  #pragma unroll
  for (int c = 0; c < 12; c++) {
    float s = 0.f;
    #pragma unroll
    for (int d = 0; d < 12; d++) s = fmaf(a[c*12 + d], vv[d], s);
    ob[(long)c*HW + n] = s;
  }
}

extern "C" void kernel_launch(void* const* d_in, const int* in_sizes, int n_in,
                              void* d_out, int out_size, void* d_ws, size_t ws_size,
                              hipStream_t stream) {
  const float* x        = (const float*)d_in[0];
  const float* qk_w     = (const float*)d_in[1];
  const float* qk_dw    = (const float*)d_in[2];
  const float* v_w      = (const float*)d_in[3];
  const float* v_dw     = (const float*)d_in[4];
  const float* k2_w     = (const float*)d_in[5];
  const float* k2_dw    = (const float*)d_in[6];
  const float* q2_w     = (const float*)d_in[7];
  const float* q2_dw    = (const float*)d_in[8];
  const float* proj_w   = (const float*)d_in[9];
  const float* sab_temp = (const float*)d_in[10];
  const float* fqkv_w   = (const float*)d_in[11];
  const float* fqkv_dw  = (const float*)d_in[12];
  const float* fproj_w  = (const float*)d_in[13];
  const float* fhr_temp = (const float*)d_in[14];
  float* out = (float*)d_out;
  float* ws  = (float*)d_ws;

  float* O2  = out;
  float* KS  = out + 12582912;
  float* VS  = out + 14155776;
  float* K2N = out + 26738688;
  float* V2  = out + 39321600;

  float* A0   = ws;
  float* A1   = ws + 25165824;
  float* QD   = ws + 50331648;
  float* KD   = ws + 51904512;
  float* QN   = ws + 53477376;
  float* A2S  = ws + 55050240;
  float* PART = ws + 55052544;
  unsigned short* QSP = (unsigned short*)(A0 + 16777216);
  unsigned short* KSP = (unsigned short*)(A0 + 16777216 + 786432);
  unsigned short* WHL = (unsigned short*)QN;
  // fhr-phase layout: ALN = ws[0:12.58M] (raw q2-dw), PRE = ws[12.58M:50.33M]
  float* ALN = ws;
  float* PRE = ws + 12582912;
  float* OB  = ws + 12582912;
  float* QQP = QD;   // qq partials (QD dead in fhr phase): 16ch*16bh*12 floats

  dim3 b256(256), b1024(1024);

  wsplit<<<dim3(432), b256, 0, stream>>>(qk_w, v_w, q2_w, k2_w, proj_w, fqkv_w, fproj_w, WHL);
  conv1x1_mfma<<<dim3(512,2), b256, 0, stream>>>(x, 96L*HW, WHL, 0, A0, 192L*HW, 12, 0);
  dw3x3v<<<dim3(64,192,2), b256, 0, stream>>>(A0, 192, qk_dw, A1, 192);
  conv1x1_mfma<<<dim3(512,2), b256, 0, stream>>>(x, 96L*HW, WHL, 192, A0, 96L*HW, 6, 0);
  dw3x3_vs<<<dim3(1024,2), b256, 0, stream>>>(A0, v_dw, VS);
  conv1x1_mfma<<<dim3(512,2), b256, 0, stream>>>(A1, 192L*HW, WHL, 288, A0, 192L*HW, 12, 0);
  dw4x4s4v<<<dim3(4,192,2), b256, 0, stream>>>(A0, q2_dw, QD);
  conv1x1_mfma<<<dim3(512,2), b256, 0, stream>>>(A1 + 96L*HW, 192L*HW, WHL, 480, A0, 192L*HW, 12, 0);
  dw4x4s4v<<<dim3(4,192,2), b256, 0, stream>>>(A0, k2_dw, KD);
  l2n192<<<dim3(2048), b256, 0, stream>>>(QD, QN);
  l2n192<<<dim3(2048), b256, 0, stream>>>(KD, KS);
  for (int b = 0; b < 2; b++) {
    bf16split<<<dim3(3072), b256, 0, stream>>>(QN + (long)b*786432, QSP);
    bf16split<<<dim3(3072), b256, 0, stream>>>(KS + (long)b*786432, KSP);
    attn_qk_mfma<<<dim3(32,32), b256, 0, stream>>>(QSP, KSP, A0, sab_temp);
    attn_out_k<<<dim3(4096), b256, 0, stream>>>(
        A0, VS + (long)b*6291456, A1 + (long)b*6291456);
  }
  // re-split weights (QN slot was clobbered)
  wsplit<<<dim3(432), b256, 0, stream>>>(qk_w, v_w, q2_w, k2_w, proj_w, fqkv_w, fproj_w, WHL);
  // aligned = 1x1(permuted attn-out, proj_w) -> ALN
  conv1x1_mfma<<<dim3(512,2), b256, 0, stream>>>(A1, 6291456L, WHL, 672, ALN, 96L*HW, 6, 1);
  // FUSED fhr qkv conv: Cout=288 -> PRE
  conv1x1_mfma<<<dim3(512,2), b256, 0, stream>>>(ALN, 96L*HW, WHL, 768, PRE, 288L*HW, 18, 0);
  // three depthwise passes on PRE channel groups; ALN reused for raw q2-dw
  dw3x3v<<<dim3(64,96,2), b256, 0, stream>>>(PRE,            288, fqkv_dw,        ALN, 96);
  dw3x3v<<<dim3(64,96,2), b256, 0, stream>>>(PRE +  96L*HW, 288, fqkv_dw +  864, K2N, 96);
  dw3x3v<<<dim3(64,96,2), b256, 0, stream>>>(PRE + 192L*HW, 288, fqkv_dw + 1728, V2,  96);
  // normalize k2 only (output); q2 normalization folded into a2
  l2n_sp<<<dim3(96,2), b1024, 0, stream>>>(K2N, K2N);
  // a2 two-stage with q-norm fold
  a2_part<<<dim3(A2_NCH,8,2), b256, 0, stream>>>(ALN, K2N, PART, QQP);
  a2_fin<<<dim3(8,2), b256, 0, stream>>>(PART, QQP, fhr_temp, A2S);
  // o2pre -> OB (PRE region, dead)
  o2pre_kern<<<dim3(256,16), b256, 0, stream>>>(A2S, V2, OB);
  // o2 = 1x1(o2pre, fproj_w) -> d_out
  conv1x1_mfma<<<dim3(512,2), b256, 0, stream>>>(OB, 96L*HW, WHL, 1056, O2, 96L*HW, 6, 0);
}

// Round 13
// 871.479 us; speedup vs baseline: 2.2064x; 1.0300x over previous
//
#include <hip/hip_runtime.h>
#include <hip/hip_bf16.h>
#include <math.h>

#define HW 65536L

typedef __attribute__((ext_vector_type(8))) short bf16x8;
typedef __attribute__((ext_vector_type(4))) float f32x4;

__device__ __forceinline__ int iabs_(int v) { return v < 0 ? -v : v; }

// ---- split all 1x1 weights into (hi,lo) bf16 planes: whl[2][1152][96] ----
__global__ __launch_bounds__(256) void wsplit(
    const float* __restrict__ qk, const float* __restrict__ v,
    const float* __restrict__ q2, const float* __restrict__ k2,
    const float* __restrict__ pj, const float* __restrict__ fq,
    const float* __restrict__ fp, unsigned short* __restrict__ whl)
{
  const int e = blockIdx.x*256 + threadIdx.x;
  if (e >= 110592) return;
  const int row = e / 96, col = e - row*96;
  float f;
  if      (row <  192) f = qk[e];
  else if (row <  288) f = v [(row-192)*96+col];
  else if (row <  480) f = q2[(row-288)*96+col];
  else if (row <  672) f = k2[(row-480)*96+col];
  else if (row <  768) f = pj[(row-672)*96+col];
  else if (row < 1056) f = fq[(row-768)*96+col];
  else                 f = fp[(row-1056)*96+col];
  __hip_bfloat16 h = __float2bfloat16(f);
  float hf = __bfloat162float(h);
  __hip_bfloat16 l = __float2bfloat16(f - hf);
  whl[e]          = *(unsigned short*)&h;
  whl[110592 + e] = *(unsigned short*)&l;
}

// ------- conv 1x1 via split-bf16 MFMA (R13: dual-out, uint4 staging) -------
// m-tile < msplit -> out1; else -> out2 (channel index restarts at 0).
#define BLDS 104
__global__ __launch_bounds__(256) void conv1x1_mfma(
    const float* __restrict__ in, long in_bstride,
    const unsigned short* __restrict__ whl, int wrow0,
    float* __restrict__ out, long out_bstride,
    float* __restrict__ out2, long out2_bstride, int msplit,
    int mtiles, int mode)
{
  __shared__ unsigned short bhs[128*BLDS];
  __shared__ unsigned short bls[128*BLDS];
  const int t = threadIdx.x;
  const int p0 = blockIdx.x * 128;
  const int b = blockIdx.y;
  if (mode == 0) {
    #pragma unroll
    for (int it = 0; it < 6; it++) {
      const int idx = it*256 + t;            // 0..1535
      const int g8 = idx >> 7;               // 8-channel group 0..11
      const int pix = idx & 127;
      const float* src = in + (long)b*in_bstride + (long)(g8*8)*HW + p0 + pix;
      unsigned hh[8], ll[8];
      #pragma unroll
      for (int j = 0; j < 8; j++) {
        float f = src[(long)j*HW];
        unsigned u = __float_as_uint(f);
        hh[j] = u >> 16;
        float lof = f - __uint_as_float(u & 0xFFFF0000u);
        __hip_bfloat16 lb = __float2bfloat16(lof);
        ll[j] = *(unsigned short*)&lb;
      }
      uint4 hv, lv;
      hv.x = hh[0]|(hh[1]<<16); hv.y = hh[2]|(hh[3]<<16);
      hv.z = hh[4]|(hh[5]<<16); hv.w = hh[6]|(hh[7]<<16);
      lv.x = ll[0]|(ll[1]<<16); lv.y = ll[2]|(ll[3]<<16);
      lv.z = ll[4]|(ll[5]<<16); lv.w = ll[6]|(ll[7]<<16);
      *(uint4*)(bhs + pix*BLDS + g8*8) = hv;
      *(uint4*)(bls + pix*BLDS + g8*8) = lv;
    }
  } else {
    const int pp = t >> 1, half = (t & 1)*48;
    const int p = p0 + pp;
    const int py = p >> 8, px = p & 255;
    const float* src = in + (long)b*in_bstride
        + ((long)((py & 63)*64 + (px & 63))*16 + ((py >> 6)*4 + (px >> 6)))*96 + half;
    #pragma unroll
    for (int j4 = 0; j4 < 12; j4++) {
      float4 v4 = *(const float4*)&src[j4*4];
      float fv[4] = {v4.x, v4.y, v4.z, v4.w};
      unsigned hh[4], ll[4];
      #pragma unroll
      for (int u4 = 0; u4 < 4; u4++) {
        unsigned u = __float_as_uint(fv[u4]);
        hh[u4] = u >> 16;
        float lof = fv[u4] - __uint_as_float(u & 0xFFFF0000u);
        __hip_bfloat16 lb = __float2bfloat16(lof);
        ll[u4] = *(unsigned short*)&lb;
      }
      uint2 hv, lv;
      hv.x = hh[0] | (hh[1] << 16); hv.y = hh[2] | (hh[3] << 16);
      lv.x = ll[0] | (ll[1] << 16); lv.y = ll[2] | (ll[3] << 16);
      *(uint2*)(bhs + pp*BLDS + half + j4*4) = hv;
      *(uint2*)(bls + pp*BLDS + half + j4*4) = lv;
    }
  }
  __syncthreads();
  const int lane = t & 63, w = t >> 6;
  const int fr = lane & 15, fk = lane >> 4;
  bf16x8 Bh[2][3], Bl[2][3];
  #pragma unroll
  for (int nt = 0; nt < 2; nt++)
    #pragma unroll
    for (int kt = 0; kt < 3; kt++) {
      const int pix = w*32 + nt*16 + fr;
      Bh[nt][kt] = *(const bf16x8*)(bhs + pix*BLDS + kt*32 + fk*8);
      Bl[nt][kt] = *(const bf16x8*)(bls + pix*BLDS + kt*32 + fk*8);
    }
  for (int m = 0; m < mtiles; m++) {
    const long wbase = (long)(wrow0 + m*16 + fr)*96 + fk*8;
    bf16x8 Ah[3], Al[3];
    #pragma unroll
    for (int kt = 0; kt < 3; kt++) {
      Ah[kt] = *(const bf16x8*)(whl + wbase + kt*32);
      Al[kt] = *(const bf16x8*)(whl + 110592 + wbase + kt*32);
    }
    f32x4 acc[2] = {};
    #pragma unroll
    for (int nt = 0; nt < 2; nt++)
      #pragma unroll
      for (int kt = 0; kt < 3; kt++) {
        acc[nt] = __builtin_amdgcn_mfma_f32_16x16x32_bf16(Ah[kt], Bh[nt][kt], acc[nt], 0, 0, 0);
        acc[nt] = __builtin_amdgcn_mfma_f32_16x16x32_bf16(Ah[kt], Bl[nt][kt], acc[nt], 0, 0, 0);
        acc[nt] = __builtin_amdgcn_mfma_f32_16x16x32_bf16(Al[kt], Bh[nt][kt], acc[nt], 0, 0, 0);
      }
    const int mo = (m < msplit) ? m : (m - msplit);
    float* dst = ((m < msplit) ? out + (long)b*out_bstride
                               : out2 + (long)b*out2_bstride) + p0 + w*32;
    #pragma unroll
    for (int nt = 0; nt < 2; nt++)
      #pragma unroll
      for (int r = 0; r < 4; r++)
        dst[(long)(mo*16 + fk*4 + r)*HW + nt*16 + fr] = acc[nt][r];
  }
}

// -------- depthwise 3x3 pad 1, 4-wide vectorized --------
__global__ __launch_bounds__(256) void dw3x3v(
    const float* __restrict__ in, int inCH, const float* __restrict__ w,
    float* __restrict__ out, int outCH)
{
  const int t = threadIdx.x;
  const int p4 = blockIdx.x * 256 + t;
  const int ch = blockIdx.y, b = blockIdx.z;
  const int y = p4 >> 6, x0 = (p4 & 63) << 2;
  const float* ip = in + ((long)b*inCH + ch) * HW;
  const float* wp = w + ch*9;
  float a0 = 0.f, a1 = 0.f, a2 = 0.f, a3 = 0.f;
  #pragma unroll
  for (int dy = -1; dy <= 1; dy++) {
    const int yy = y + dy;
    if (yy < 0 || yy > 255) continue;
    const float* rp = ip + yy*256;
    const float4 c = *(const float4*)&rp[x0];
    const float left  = (x0 > 0)   ? rp[x0-1] : 0.f;
    const float right = (x0 < 252) ? rp[x0+4] : 0.f;
    const float w0 = wp[(dy+1)*3+0], w1 = wp[(dy+1)*3+1], w2 = wp[(dy+1)*3+2];
    a0 = fmaf(left, w0, a0); a0 = fmaf(c.x, w1, a0); a0 = fmaf(c.y, w2, a0);
    a1 = fmaf(c.x,  w0, a1); a1 = fmaf(c.y, w1, a1); a1 = fmaf(c.z, w2, a1);
    a2 = fmaf(c.y,  w0, a2); a2 = fmaf(c.z, w1, a2); a2 = fmaf(c.w, w2, a2);
    a3 = fmaf(c.z,  w0, a3); a3 = fmaf(c.w, w1, a3); a3 = fmaf(right, w2, a3);
  }
  float4 o; o.x = a0; o.y = a1; o.z = a2; o.w = a3;
  *(float4*)&out[((long)b*outCH + ch)*HW + y*256 + x0] = o;
}

// ------- depthwise 3x3 fused with v_s permutation (4-wide compute) ----
__global__ __launch_bounds__(256) void dw3x3_vs(
    const float* __restrict__ in, const float* __restrict__ w,
    float* __restrict__ vs)
{
  __shared__ float tile[96*65];
  const int t = threadIdx.x;
  const int gb = blockIdx.x;
  const int b = blockIdx.y;
  const int y = gb >> 2, xb = gb & 3;
  #pragma unroll
  for (int i = 0; i < 6; i++) {
    const int idx = i*256 + t;
    const int ci = idx >> 4, q = idx & 15;
    const int x0 = xb*64 + q*4;
    const float* ip = in + ((long)b*96 + ci) * HW;
    const float* wp = w + ci*9;
    float a0 = 0.f, a1 = 0.f, a2 = 0.f, a3 = 0.f;
    #pragma unroll
    for (int dy = -1; dy <= 1; dy++) {
      const int yy = y + dy;
      if (yy < 0 || yy > 255) continue;
      const float* rp = ip + yy*256;
      const float4 c = *(const float4*)&rp[x0];
      const float left  = (x0 > 0)   ? rp[x0-1] : 0.f;
      const float right = (x0 < 252) ? rp[x0+4] : 0.f;
      const float w0 = wp[(dy+1)*3+0], w1 = wp[(dy+1)*3+1], w2 = wp[(dy+1)*3+2];
      a0 = fmaf(left, w0, a0); a0 = fmaf(c.x, w1, a0); a0 = fmaf(c.y, w2, a0);
      a1 = fmaf(c.x,  w0, a1); a1 = fmaf(c.y, w1, a1); a1 = fmaf(c.z, w2, a1);
      a2 = fmaf(c.y,  w0, a2); a2 = fmaf(c.z, w1, a2); a2 = fmaf(c.w, w2, a2);
      a3 = fmaf(c.z,  w0, a3); a3 = fmaf(c.w, w1, a3); a3 = fmaf(right, w2, a3);
    }
    const int xl = q*4;
    tile[ci*65 + xl    ] = a0;
    tile[ci*65 + xl + 1] = a1;
    tile[ci*65 + xl + 2] = a2;
    tile[ci*65 + xl + 3] = a3;
  }
  __syncthreads();
  const int blk = (y >> 6)*4 + xb;
  float* obase = vs + ((long)b*4096 + (long)(y & 63)*64) * 1536 + blk*96;
  #pragma unroll
  for (int i = 0; i < 24; i++) {
    const int idx = i*256 + t;
    const int nl = idx / 96, ci = idx % 96;
    obase[(long)nl*1536 + ci] = tile[ci*65 + nl];
  }
}

// ---- depthwise 4x4 stride 4 pad 1 (256->64), 4-wide vectorized ----
__global__ __launch_bounds__(256) void dw4x4s4v(
    const float* __restrict__ in, const float* __restrict__ w,
    float* __restrict__ out)
{
  const int t = threadIdx.x;
  const int p = blockIdx.x*256 + t;
  const int ch = blockIdx.y, b = blockIdx.z;
  const int oy = p >> 4, qx = p & 15;
  const int x0 = qx*16;
  const float* ip = in + (long)(b*192 + ch) * HW;
  const float* wp = w + ch*16;
  float a0 = 0.f, a1 = 0.f, a2 = 0.f, a3 = 0.f;
  #pragma unroll
  for (int ty = 0; ty < 4; ty++) {
    const int iy = 4*oy + ty - 1;
    if (iy < 0 || iy > 255) continue;
    const float* rp = ip + iy*256;
    float r[17];
    r[0] = (x0 > 0) ? rp[x0-1] : 0.f;
    #pragma unroll
    for (int k = 0; k < 4; k++) {
      float4 v4 = *(const float4*)&rp[x0 + k*4];
      r[1+k*4+0]=v4.x; r[1+k*4+1]=v4.y; r[1+k*4+2]=v4.z; r[1+k*4+3]=v4.w;
    }
    const float w0=wp[ty*4+0], w1=wp[ty*4+1], w2=wp[ty*4+2], w3=wp[ty*4+3];
    a0=fmaf(r[ 0],w0,a0); a0=fmaf(r[ 1],w1,a0); a0=fmaf(r[ 2],w2,a0); a0=fmaf(r[ 3],w3,a0);
    a1=fmaf(r[ 4],w0,a1); a1=fmaf(r[ 5],w1,a1); a1=fmaf(r[ 6],w2,a1); a1=fmaf(r[ 7],w3,a1);
    a2=fmaf(r[ 8],w0,a2); a2=fmaf(r[ 9],w1,a2); a2=fmaf(r[10],w2,a2); a2=fmaf(r[11],w3,a2);
    a3=fmaf(r[12],w0,a3); a3=fmaf(r[13],w1,a3); a3=fmaf(r[14],w2,a3); a3=fmaf(r[15],w3,a3);
  }
  float4 o; o.x=a0; o.y=a1; o.z=a2; o.w=a3;
  *(float4*)&out[(long)(b*192 + ch)*4096 + oy*64 + qx*4] = o;
}

// ---------------- l2 norm over 192 channels + transpose (R13: both ops) ----
// gw2: 0..8191 -> QD->QN, 8192..16383 -> KD->KS
__global__ __launch_bounds__(256) void l2n192(
    const float* __restrict__ inA, float* __restrict__ outA,
    const float* __restrict__ inB, float* __restrict__ outB)
{
  const int t = threadIdx.x;
  const int wid = t >> 6, lane = t & 63;
  const int gw2 = blockIdx.x * 4 + wid;
  const int sel = gw2 >> 13;
  const int gw = gw2 & 8191;
  const int b = gw >> 12, n = gw & 4095;
  const float* ip = (sel ? inB : inA) + (long)b * 786432;
  float v0 = ip[(long)(lane      ) * 4096 + n];
  float v1 = ip[(long)(lane +  64) * 4096 + n];
  float v2 = ip[(long)(lane + 128) * 4096 + n];
  float ss = v0*v0 + v1*v1 + v2*v2;
  #pragma unroll
  for (int s = 1; s < 64; s <<= 1) ss += __shfl_xor(ss, s, 64);
  float nrm = fmaxf(sqrtf(ss), 1e-12f);
  float* op = (sel ? outB : outA) + ((long)b*4096 + n) * 192;
  op[lane      ] = v0 / nrm;
  op[lane +  64] = v1 / nrm;
  op[lane + 128] = v2 / nrm;
}

// ---------------- split fp32 -> (hi,lo) bf16 planes ----------------
__global__ __launch_bounds__(256) void bf16split(
    const float* __restrict__ in, unsigned short* __restrict__ outp)
{
  const int i = blockIdx.x * 256 + threadIdx.x;
  const int n = i / 192, k = i % 192;
  float f = in[i];
  __hip_bfloat16 h = __float2bfloat16(f);
  float hf = __bfloat162float(h);
  __hip_bfloat16 l = __float2bfloat16(f - hf);
  outp[(long)n*384 + k]       = *(unsigned short*)&h;
  outp[(long)n*384 + 192 + k] = *(unsigned short*)&l;
}

// ---------------- attention QK^T via split-bf16 MFMA (one batch) ------------
#define LDSROW 40
__global__ __launch_bounds__(256) void attn_qk_mfma(
    const unsigned short* __restrict__ Qsp, const unsigned short* __restrict__ Ksp,
    float* __restrict__ attn, const float* __restrict__ tp)
{
  __shared__ unsigned short qs[256*LDSROW];
  __shared__ unsigned short ks[256*LDSROW];
  const int t = threadIdx.x;
  const int lane = t & 63, w = t >> 6;
  const int n0 = blockIdx.x * 128;
  const int m0 = blockIdx.y * 128;
  const int wr = (w >> 1) * 64, wc = (w & 1) * 64;
  f32x4 acc[4][4] = {};
  const int srow = t & 127;
  const int shl  = t >> 7;
  const unsigned short* qsrc = Qsp + (long)(n0 + srow) * 384 + shl * 192;
  const unsigned short* ksrc = Ksp + (long)(m0 + srow) * 384 + shl * 192;
  unsigned short* qdst = qs + (shl*128 + srow) * LDSROW;
  unsigned short* kdst = ks + (shl*128 + srow) * LDSROW;
  const int fr = lane & 15;
  const int fk = lane >> 4;
  for (int s = 0; s < 6; s++) {
    __syncthreads();
    #pragma unroll
    for (int j = 0; j < 4; j++) {
      *(bf16x8*)(qdst + j*8) = *(const bf16x8*)(qsrc + s*32 + j*8);
      *(bf16x8*)(kdst + j*8) = *(const bf16x8*)(ksrc + s*32 + j*8);
    }
    __syncthreads();
    bf16x8 ah[4], al[4], bh[4], bl[4];
    #pragma unroll
    for (int i = 0; i < 4; i++) {
      ah[i] = *(const bf16x8*)(qs + (      wr + i*16 + fr) * LDSROW + fk*8);
      al[i] = *(const bf16x8*)(qs + (128 + wr + i*16 + fr) * LDSROW + fk*8);
      bh[i] = *(const bf16x8*)(ks + (      wc + i*16 + fr) * LDSROW + fk*8);
      bl[i] = *(const bf16x8*)(ks + (128 + wc + i*16 + fr) * LDSROW + fk*8);
    }
    #pragma unroll
    for (int i = 0; i < 4; i++)
      #pragma unroll
      for (int j = 0; j < 4; j++) {
        acc[i][j] = __builtin_amdgcn_mfma_f32_16x16x32_bf16(ah[i], bh[j], acc[i][j], 0, 0, 0);
        acc[i][j] = __builtin_amdgcn_mfma_f32_16x16x32_bf16(ah[i], bl[j], acc[i][j], 0, 0, 0);
        acc[i][j] = __builtin_amdgcn_mfma_f32_16x16x32_bf16(al[i], bh[j], acc[i][j], 0, 0, 0);
      }
  }
  const float temp = tp[0];
  #pragma unroll
  for (int i = 0; i < 4; i++)
    #pragma unroll
    for (int j = 0; j < 4; j++)
      #pragma unroll
      for (int r = 0; r < 4; r++) {
        const int nn = n0 + wr + i*16 + (lane >> 4)*4 + r;
        const int mm = m0 + wc + j*16 + (lane & 15);
        attn[(long)nn*4096 + mm] = acc[i][j][r] * temp;
      }
}

// ------- top-5 + local mask + softmax + sparse out -------
#define CAP 128
__global__ __launch_bounds__(256) void attn_out_k(
    const float* __restrict__ attn, const float* __restrict__ vs,
    float* __restrict__ outr)
{
  __shared__ float row[4096];
  __shared__ float top5[256*5];
  __shared__ int   lm[CAP];
  __shared__ float lw[CAP];
  __shared__ float ses[CAP];
  __shared__ float redf[8];
  __shared__ int   wsum[4];
  const int t = threadIdx.x;
  const int n = blockIdx.x;
  const float* ar = attn + (long)n * 4096;
  #pragma unroll
  for (int k = 0; k < 16; k++) row[k*256 + t] = ar[k*256 + t];
  __syncthreads();
  float t0=-INFINITY,t1=-INFINITY,t2=-INFINITY,t3=-INFINITY,t4=-INFINITY;
  #pragma unroll
  for (int k = 0; k < 16; k++) {
    float v = row[k*256 + t];
    if (v > t4) {
      if (v > t0)      { t4=t3; t3=t2; t2=t1; t1=t0; t0=v; }
      else if (v > t1) { t4=t3; t3=t2; t2=t1; t1=v; }
      else if (v > t2) { t4=t3; t3=t2; t2=v; }
      else if (v > t3) { t4=t3; t3=v; }
      else             { t4=v; }
    }
  }
  top5[t*5+0]=t0; top5[t*5+1]=t1; top5[t*5+2]=t2; top5[t*5+3]=t3; top5[t*5+4]=t4;
  __syncthreads();
  for (int s = 128; s >= 1; s >>= 1) {
    if (t < s) {
      float* A = &top5[t*5];
      const float* B = &top5[(t+s)*5];
      float m[5]; int i = 0, j = 0;
      #pragma unroll
      for (int k = 0; k < 5; k++) {
        float av = A[i], bv = B[j];
        if (av >= bv) { m[k] = av; i++; } else { m[k] = bv; j++; }
      }
      #pragma unroll
      for (int k = 0; k < 5; k++) A[k] = m[k];
    }
    __syncthreads();
  }
  const float kth = top5[4];
  const int y = n >> 6, x = n & 63;
  int myc = 0;
  float wmax = -INFINITY;
  #pragma unroll
  for (int k = 0; k < 16; k++) {
    int m = k*256 + t;
    float a = row[m];
    int c = ((a >= kth) ? 1 : 0) +
            (((iabs_(y - (m >> 6)) + iabs_(x - (m & 63))) <= 4) ? 1 : 0);
    float wv = a * (float)c;
    if (wv != 0.0f) { myc++; wmax = fmaxf(wmax, wv); }
  }
  int inc = myc;
  #pragma unroll
  for (int s = 1; s < 64; s <<= 1) {
    int v = __shfl_up(inc, s, 64);
    if ((t & 63) >= s) inc += v;
  }
  if ((t & 63) == 63) wsum[t >> 6] = inc;
  __syncthreads();
  int pre = 0;
  #pragma unroll
  for (int wj = 0; wj < 4; wj++) pre += (wj < (t >> 6)) ? wsum[wj] : 0;
  const int base = pre + inc - myc;
  const int cnt = wsum[0] + wsum[1] + wsum[2] + wsum[3];
  {
    int idx = base;
    #pragma unroll
    for (int k = 0; k < 16; k++) {
      int m = k*256 + t;
      float a = row[m];
      int c = ((a >= kth) ? 1 : 0) +
              (((iabs_(y - (m >> 6)) + iabs_(x - (m & 63))) <= 4) ? 1 : 0);
      float wv = a * (float)c;
      if (wv != 0.0f && idx < CAP) { lm[idx] = m; lw[idx] = wv; idx++; }
    }
  }
  #pragma unroll
  for (int s = 1; s < 64; s <<= 1) wmax = fmaxf(wmax, __shfl_xor(wmax, s, 64));
  if ((t & 63) == 0) redf[t >> 6] = wmax;
  __syncthreads();
  const float gmax = fmaxf(fmaxf(redf[0], redf[1]), fmaxf(redf[2], redf[3]));
  __syncthreads();
  if (t < cnt && t < CAP) ses[t] = expf(lw[t] - gmax);
  __syncthreads();
  float ps = (t < cnt && t < CAP) ? ses[t] : 0.f;
  #pragma unroll
  for (int s = 1; s < 64; s <<= 1) ps += __shfl_xor(ps, s, 64);
  if ((t & 63) == 0) redf[4 + (t >> 6)] = ps;
  __syncthreads();
  const float S = redf[4] + redf[5] + redf[6] + redf[7];
  const float invS = 1.0f / S;
  float a0=0,a1=0,a2=0,a3=0,a4=0,a5=0;
  const int ecnt = (cnt < CAP) ? cnt : CAP;
  for (int e = 0; e < ecnt; e++) {
    float se = ses[e] * invS;
    const float* vr = vs + (long)lm[e] * 1536;
    a0 = fmaf(se, vr[        t], a0);
    a1 = fmaf(se, vr[ 256 + t], a1);
    a2 = fmaf(se, vr[ 512 + t], a2);
    a3 = fmaf(se, vr[ 768 + t], a3);
    a4 = fmaf(se, vr[1024 + t], a4);
    a5 = fmaf(se, vr[1280 + t], a5);
  }
  float* orow = outr + (long)n * 1536;
  orow[        t] = a0;
  orow[ 256 + t] = a1;
  orow[ 512 + t] = a2;
  orow[ 768 + t] = a3;
  orow[1024 + t] = a4;
  orow[1280 + t] = a5;
}

// ------- per-channel l2 norm over 65536 (fhr k2); in-place safe -------
__global__ __launch_bounds__(1024) void l2n_sp(
    const float* __restrict__ in, float* __restrict__ out)
{
  const int ch = blockIdx.x, b = blockIdx.y, t = threadIdx.x;
  const float* ip = in + ((long)b*96 + ch) * HW;
  float ss = 0.f;
  for (int i = t; i < 65536; i += 1024) { float v = ip[i]; ss = fmaf(v, v, ss); }
  __shared__ float red[16];
  #pragma unroll
  for (int s = 1; s < 64; s <<= 1) ss += __shfl_xor(ss, s, 64);
  if ((t & 63) == 0) red[t >> 6] = ss;
  __syncthreads();
  if (t == 0) {
    float s2 = 0.f;
    for (int i = 0; i < 16; i++) s2 += red[i];
    red[0] = fmaxf(sqrtf(s2), 1e-12f);
  }
  __syncthreads();
  const float nrm = red[0];
  float* op = out + ((long)b*96 + ch) * HW;
  for (int i = t; i < 65536; i += 1024) op[i] = ip[i] / nrm;
}

// -------- a2 stage 1: raw-q Gram + q sum-of-squares partials ----------
#define A2_NCH 16
__global__ __launch_bounds__(256) void a2_part(
    const float* __restrict__ q2n, const float* __restrict__ k2n,
    float* __restrict__ part, float* __restrict__ qqpart)
{
  __shared__ float sh[24*260];
  const int t = threadIdx.x;
  const int ch = blockIdx.x, h = blockIdx.y, b = blockIdx.z;
  const long base = ((long)b*96 + h*12) * HW + ch*4096;
  const int c = t / 12, d = t - (t/12)*12;
  float acc = 0.f;
  float qq = 0.f;
  for (int sub = 0; sub < 16; sub++) {
    __syncthreads();
    #pragma unroll
    for (int j = 0; j < 6; j++) {
      const int v = j*256 + t;
      const int row = v >> 6;
      const int col4 = v & 63;
      const float* src = (row < 12)
        ? q2n + base + (long)row*HW + sub*256 + col4*4
        : k2n + base + (long)(row-12)*HW + sub*256 + col4*4;
      *(float4*)&sh[row*260 + col4*4] = *(const float4*)src;
    }
    __syncthreads();
    if (t < 144) {
      const float* qr = &sh[c*260];
      const float* kr = &sh[(12+d)*260];
      #pragma unroll
      for (int i4 = 0; i4 < 64; i4++) {
        float4 qv = *(const float4*)&qr[i4*4];
        float4 kv = *(const float4*)&kr[i4*4];
        acc = fmaf(qv.x, kv.x, acc);
        acc = fmaf(qv.y, kv.y, acc);
        acc = fmaf(qv.z, kv.z, acc);
        acc = fmaf(qv.w, kv.w, acc);
      }
    } else if (t < 156) {
      const float* qr = &sh[(t-144)*260];
      #pragma unroll
      for (int i4 = 0; i4 < 64; i4++) {
        float4 qv = *(const float4*)&qr[i4*4];
        qq = fmaf(qv.x, qv.x, qq);
        qq = fmaf(qv.y, qv.y, qq);
        qq = fmaf(qv.z, qv.z, qq);
        qq = fmaf(qv.w, qv.w, qq);
      }
    }
  }
  if (t < 144)
    part[(((long)b*8 + h)*A2_NCH + ch)*144 + t] = acc;
  else if (t < 156)
    qqpart[(((long)b*8 + h)*A2_NCH + ch)*12 + (t-144)] = qq;
}

// -------- a2 stage 2: fold q-normalization --------
__global__ __launch_bounds__(256) void a2_fin(
    const float* __restrict__ part, const float* __restrict__ qqpart,
    const float* __restrict__ temp, float* __restrict__ a2s)
{
  __shared__ float m[144];
  __shared__ float qn[12];
  const int t = threadIdx.x;
  const int h = blockIdx.x, b = blockIdx.y;
  if (t < 144) {
    float s = 0.f;
    const float* pp = part + (((long)b*8 + h)*A2_NCH)*144 + t;
    #pragma unroll
    for (int ch = 0; ch < A2_NCH; ch++) s += pp[ch*144];
    m[t] = s;
  } else if (t < 156) {
    float s = 0.f;
    const float* pp = qqpart + (((long)b*8 + h)*A2_NCH)*12 + (t-144);
    #pragma unroll
    for (int ch = 0; ch < A2_NCH; ch++) s += pp[ch*12];
    qn[t-144] = fmaxf(sqrtf(s), 1e-12f);
  }
  __syncthreads();
  if (t < 12) {
    const float tv = temp[h];
    const float scale = tv / qn[t];
    float mx = -INFINITY;
    float a[12];
    #pragma unroll
    for (int d = 0; d < 12; d++) { a[d] = m[t*12+d] * scale; mx = fmaxf(mx, a[d]); }
    float e[12], sum = 0.f;
    #pragma unroll
    for (int d = 0; d < 12; d++) { e[d] = expf(a[d]-mx); sum += e[d]; }
    float inv = 1.0f/sum;
    float* op = a2s + (((long)b*8 + h)*12 + t)*12;
    #pragma unroll
    for (int d = 0; d < 12; d++) op[d] = e[d]*inv;
  }
}

// ---------------- o2pre = a2 @ v2 ----------------
__global__ __launch_bounds__(256) void o2pre_kern(
    const float* __restrict__ a2s, const float* __restrict__ v2,
    float* __restrict__ o2p)
{
  const int t = threadIdx.x;
  const int n = blockIdx.x * 256 + t;
  const int bh = blockIdx.y, b = bh >> 3, h = bh & 7;
  const float* a = a2s + (long)bh * 144;
  const float* vb = v2 + ((long)b*96 + h*12) * HW;
  float vv[12];
  #pragma unroll
  for (int d = 0; d < 12; d++) vv[d] = vb[(long)d*HW + n];
  float* ob = o2p + ((long)b*96 + h*12) * HW;
  #pragma unroll
  for (int c = 0; c < 12; c++) {
    float s = 0.f;
    #pragma unroll
    for (int d = 0; d < 12; d++) s = fmaf(a[c*12 + d], vv[d], s);
    ob[(long)c*HW + n] = s;
  }
}

extern "C" void kernel_launch(void* const* d_in, const int* in_sizes, int n_in,
                              void* d_out, int out_size, void* d_ws, size_t ws_size,
                              hipStream_t stream) {
  const float* x        = (const float*)d_in[0];
  const float* qk_w     = (const float*)d_in[1];
  const float* qk_dw    = (const float*)d_in[2];
  const float* v_w      = (const float*)d_in[3];
  const float* v_dw     = (const float*)d_in[4];
  const float* k2_w     = (const float*)d_in[5];
  const float* k2_dw    = (const float*)d_in[6];
  const float* q2_w     = (const float*)d_in[7];
  const float* q2_dw    = (const float*)d_in[8];
  const float* proj_w   = (const float*)d_in[9];
  const float* sab_temp = (const float*)d_in[10];
  const float* fqkv_w   = (const float*)d_in[11];
  const float* fqkv_dw  = (const float*)d_in[12];
  const float* fproj_w  = (const float*)d_in[13];
  const float* fhr_temp = (const float*)d_in[14];
  float* out = (float*)d_out;
  float* ws  = (float*)d_ws;

  float* O2  = out;
  float* KS  = out + 12582912;
  float* VS  = out + 14155776;
  float* K2N = out + 26738688;
  float* V2  = out + 39321600;

  float* A0   = ws;
  float* A1   = ws + 25165824;
  float* QD   = ws + 50331648;
  float* KD   = ws + 51904512;
  float* QN   = ws + 53477376;
  float* A2S  = ws + 55050240;
  float* PART = ws + 55052544;
  unsigned short* QSP = (unsigned short*)(A0 + 16777216);
  unsigned short* KSP = (unsigned short*)(A0 + 16777216 + 786432);
  unsigned short* WHL = (unsigned short*)QN;
  float* ALN = ws;
  float* PRE = ws + 12582912;
  float* OB  = ws + 12582912;
  float* QQP = QD;

  dim3 b256(256), b1024(1024);

  wsplit<<<dim3(432), b256, 0, stream>>>(qk_w, v_w, q2_w, k2_w, proj_w, fqkv_w, fproj_w, WHL);
  // 1+3 fused) qk-conv (192ch -> A0) + v-conv (96ch -> A1[0:12.58M]), Cout=288
  conv1x1_mfma<<<dim3(512,2), b256, 0, stream>>>(
      x, 96L*HW, WHL, 0, A0, 192L*HW, A1, 96L*HW, 12, 18, 0);
  // 4) v_s = permute(dw3x3(v-out)) -> d_out  (consumes A1 before dw3x3v overwrites)
  dw3x3_vs<<<dim3(1024,2), b256, 0, stream>>>(A1, v_dw, VS);
  // 2) qk = dw3x3(qk-out) -> A1 (2,192,HW)
  dw3x3v<<<dim3(64,192,2), b256, 0, stream>>>(A0, 192, qk_dw, A1, 192);
  // 5) q2pre = 1x1(q, q2_w) -> A0
  conv1x1_mfma<<<dim3(512,2), b256, 0, stream>>>(
      A1, 192L*HW, WHL, 288, A0, 192L*HW, A0, 192L*HW, 12, 12, 0);
  dw4x4s4v<<<dim3(4,192,2), b256, 0, stream>>>(A0, q2_dw, QD);
  // 7) k2pre = 1x1(k, k2_w) -> A0
  conv1x1_mfma<<<dim3(512,2), b256, 0, stream>>>(
      A1 + 96L*HW, 192L*HW, WHL, 480, A0, 192L*HW, A0, 192L*HW, 12, 12, 0);
  dw4x4s4v<<<dim3(4,192,2), b256, 0, stream>>>(A0, k2_dw, KD);
  // 9/10) merged l2norm+transpose
  l2n192<<<dim3(4096), b256, 0, stream>>>(QD, QN, KD, KS);
  for (int b = 0; b < 2; b++) {
    bf16split<<<dim3(3072), b256, 0, stream>>>(QN + (long)b*786432, QSP);
    bf16split<<<dim3(3072), b256, 0, stream>>>(KS + (long)b*786432, KSP);
    attn_qk_mfma<<<dim3(32,32), b256, 0, stream>>>(QSP, KSP, A0, sab_temp);
    attn_out_k<<<dim3(4096), b256, 0, stream>>>(
        A0, VS + (long)b*6291456, A1 + (long)b*6291456);
  }
  wsplit<<<dim3(432), b256, 0, stream>>>(qk_w, v_w, q2_w, k2_w, proj_w, fqkv_w, fproj_w, WHL);
  // 12) aligned = 1x1(permuted attn-out, proj_w) -> ALN
  conv1x1_mfma<<<dim3(512,2), b256, 0, stream>>>(
      A1, 6291456L, WHL, 672, ALN, 96L*HW, ALN, 96L*HW, 6, 6, 1);
  // 13) fused fhr qkv conv: Cout=288 -> PRE
  conv1x1_mfma<<<dim3(512,2), b256, 0, stream>>>(
      ALN, 96L*HW, WHL, 768, PRE, 288L*HW, PRE, 288L*HW, 18, 18, 0);
  dw3x3v<<<dim3(64,96,2), b256, 0, stream>>>(PRE,            288, fqkv_dw,        ALN, 96);
  dw3x3v<<<dim3(64,96,2), b256, 0, stream>>>(PRE +  96L*HW, 288, fqkv_dw +  864, K2N, 96);
  dw3x3v<<<dim3(64,96,2), b256, 0, stream>>>(PRE + 192L*HW, 288, fqkv_dw + 1728, V2,  96);
  l2n_sp<<<dim3(96,2), b1024, 0, stream>>>(K2N, K2N);
  a2_part<<<dim3(A2_NCH,8,2), b256, 0, stream>>>(ALN, K2N, PART, QQP);
  a2_fin<<<dim3(8,2), b256, 0, stream>>>(PART, QQP, fhr_temp, A2S);
  o2pre_kern<<<dim3(256,16), b256, 0, stream>>>(A2S, V2, OB);
  conv1x1_mfma<<<dim3(512,2), b256, 0, stream>>>(
      OB, 96L*HW, WHL, 1056, O2, 96L*HW, O2, 96L*HW, 6, 6, 0);
}

// Round 15
// 831.318 us; speedup vs baseline: 2.3130x; 1.0483x over previous
//
#include <hip/hip_runtime.h>
#include <hip/hip_bf16.h>
#include <math.h>

#define HW 65536L

typedef __attribute__((ext_vector_type(8))) short bf16x8;
typedef __attribute__((ext_vector_type(4))) float f32x4;

__device__ __forceinline__ int iabs_(int v) { return v < 0 ? -v : v; }

__device__ __forceinline__ void rtn_split(float f, unsigned short* h, unsigned short* l) {
  __hip_bfloat16 hb = __float2bfloat16(f);
  float hf = __bfloat162float(hb);
  __hip_bfloat16 lb = __float2bfloat16(f - hf);
  *h = *(unsigned short*)&hb;
  *l = *(unsigned short*)&lb;
}

// ---- split static 1x1 weights into (hi,lo) bf16 planes: whl[2][1152][96] ----
// rows: qk 0..191 | v 192..287 | q2 288..479 | k2 480..671 | (768..1055 = wcomp1)
__global__ __launch_bounds__(256) void wsplit(
    const float* __restrict__ qk, const float* __restrict__ v,
    const float* __restrict__ q2, const float* __restrict__ k2,
    unsigned short* __restrict__ whl)
{
  const int e = blockIdx.x*256 + threadIdx.x;
  if (e >= 64512) return;                    // rows 0..671
  const int row = e / 96, col = e - row*96;
  float f;
  if      (row <  192) f = qk[e];
  else if (row <  288) f = v [(row-192)*96+col];
  else if (row <  480) f = q2[(row-288)*96+col];
  else                 f = k2[(row-480)*96+col];
  rtn_split(f, &whl[e], &whl[110592 + e]);
}

// ---- compose CF = fqkv(288x96) @ proj(96x96) -> WHL rows 768..1055 ----
__global__ __launch_bounds__(256) void wcomp1(
    const float* __restrict__ fq, const float* __restrict__ pj,
    unsigned short* __restrict__ whl)
{
  const int e = blockIdx.x*256 + threadIdx.x;
  if (e >= 27648) return;
  const int row = e / 96, col = e - row*96;
  float s = 0.f;
  #pragma unroll 8
  for (int c = 0; c < 96; c++) s = fmaf(fq[row*96 + c], pj[c*96 + col], s);
  rtn_split(s, &whl[(768+row)*96 + col], &whl[110592 + (768+row)*96 + col]);
}

// ---- compose W2[b] = fproj(96x96) @ blockdiag(a2[b]) -> per-batch hi/lo ----
__global__ __launch_bounds__(256) void wcomp2(
    const float* __restrict__ fp, const float* __restrict__ a2s,
    unsigned short* __restrict__ w2)
{
  const int e = blockIdx.x*256 + threadIdx.x;   // 0..9215
  const int b = blockIdx.y;
  if (e >= 9216) return;
  const int co = e / 96, dg = e - co*96;
  const int h = dg / 12, d = dg - h*12;
  const float* ab = a2s + (((long)b*8 + h)*12)*12 + d;
  const float* fpb = fp + co*96 + h*12;
  float s = 0.f;
  #pragma unroll
  for (int c = 0; c < 12; c++) s = fmaf(fpb[c], ab[c*12], s);
  rtn_split(s, &w2[(long)b*9216 + e], &w2[18432 + (long)b*9216 + e]);
}

// ------- conv 1x1 via split-bf16 MFMA (R15: 3-way output split) -------
// m < ms1 -> out1; m < ms2 -> out2 (idx m-ms1); else out3 (idx m-ms2).
#define BLDS 104
__global__ __launch_bounds__(256) void conv1x1_mfma(
    const float* __restrict__ in, long in_bstride,
    const unsigned short* __restrict__ whl_hi, const unsigned short* __restrict__ whl_lo,
    long wbstride, int wrow0,
    float* __restrict__ out, long out_bstride,
    float* __restrict__ out2, long out2_bstride,
    float* __restrict__ out3, long out3_bstride,
    int ms1, int ms2, int mtiles, int mode)
{
  __shared__ unsigned short bhs[128*BLDS];
  __shared__ unsigned short bls[128*BLDS];
  const int t = threadIdx.x;
  const int p0 = blockIdx.x * 128;
  const int b = blockIdx.y;
  if (mode == 0) {
    #pragma unroll
    for (int it = 0; it < 6; it++) {
      const int idx = it*256 + t;
      const int g8 = idx >> 7;
      const int pix = idx & 127;
      const float* src = in + (long)b*in_bstride + (long)(g8*8)*HW + p0 + pix;
      unsigned hh[8], ll[8];
      #pragma unroll
      for (int j = 0; j < 8; j++) {
        float f = src[(long)j*HW];
        unsigned u = __float_as_uint(f);
        hh[j] = u >> 16;
        float lof = f - __uint_as_float(u & 0xFFFF0000u);
        __hip_bfloat16 lb = __float2bfloat16(lof);
        ll[j] = *(unsigned short*)&lb;
      }
      uint4 hv, lv;
      hv.x = hh[0]|(hh[1]<<16); hv.y = hh[2]|(hh[3]<<16);
      hv.z = hh[4]|(hh[5]<<16); hv.w = hh[6]|(hh[7]<<16);
      lv.x = ll[0]|(ll[1]<<16); lv.y = ll[2]|(ll[3]<<16);
      lv.z = ll[4]|(ll[5]<<16); lv.w = ll[6]|(ll[7]<<16);
      *(uint4*)(bhs + pix*BLDS + g8*8) = hv;
      *(uint4*)(bls + pix*BLDS + g8*8) = lv;
    }
  } else {
    const int pp = t >> 1, half = (t & 1)*48;
    const int p = p0 + pp;
    const int py = p >> 8, px = p & 255;
    const float* src = in + (long)b*in_bstride
        + ((long)((py & 63)*64 + (px & 63))*16 + ((py >> 6)*4 + (px >> 6)))*96 + half;
    #pragma unroll
    for (int j4 = 0; j4 < 12; j4++) {
      float4 v4 = *(const float4*)&src[j4*4];
      float fv[4] = {v4.x, v4.y, v4.z, v4.w};
      unsigned hh[4], ll[4];
      #pragma unroll
      for (int u4 = 0; u4 < 4; u4++) {
        unsigned u = __float_as_uint(fv[u4]);
        hh[u4] = u >> 16;
        float lof = fv[u4] - __uint_as_float(u & 0xFFFF0000u);
        __hip_bfloat16 lb = __float2bfloat16(lof);
        ll[u4] = *(unsigned short*)&lb;
      }
      uint2 hv, lv;
      hv.x = hh[0] | (hh[1] << 16); hv.y = hh[2] | (hh[3] << 16);
      lv.x = ll[0] | (ll[1] << 16); lv.y = ll[2] | (ll[3] << 16);
      *(uint2*)(bhs + pp*BLDS + half + j4*4) = hv;
      *(uint2*)(bls + pp*BLDS + half + j4*4) = lv;
    }
  }
  __syncthreads();
  const int lane = t & 63, w = t >> 6;
  const int fr = lane & 15, fk = lane >> 4;
  bf16x8 Bh[2][3], Bl[2][3];
  #pragma unroll
  for (int nt = 0; nt < 2; nt++)
    #pragma unroll
    for (int kt = 0; kt < 3; kt++) {
      const int pix = w*32 + nt*16 + fr;
      Bh[nt][kt] = *(const bf16x8*)(bhs + pix*BLDS + kt*32 + fk*8);
      Bl[nt][kt] = *(const bf16x8*)(bls + pix*BLDS + kt*32 + fk*8);
    }
  const long wb = (long)b*wbstride;
  for (int m = 0; m < mtiles; m++) {
    const long wbase = wb + (long)(wrow0 + m*16 + fr)*96 + fk*8;
    bf16x8 Ah[3], Al[3];
    #pragma unroll
    for (int kt = 0; kt < 3; kt++) {
      Ah[kt] = *(const bf16x8*)(whl_hi + wbase + kt*32);
      Al[kt] = *(const bf16x8*)(whl_lo + wbase + kt*32);
    }
    f32x4 acc[2] = {};
    #pragma unroll
    for (int nt = 0; nt < 2; nt++)
      #pragma unroll
      for (int kt = 0; kt < 3; kt++) {
        acc[nt] = __builtin_amdgcn_mfma_f32_16x16x32_bf16(Ah[kt], Bh[nt][kt], acc[nt], 0, 0, 0);
        acc[nt] = __builtin_amdgcn_mfma_f32_16x16x32_bf16(Ah[kt], Bl[nt][kt], acc[nt], 0, 0, 0);
        acc[nt] = __builtin_amdgcn_mfma_f32_16x16x32_bf16(Al[kt], Bh[nt][kt], acc[nt], 0, 0, 0);
      }
    int mo; float* dst;
    if (m < ms1)      { mo = m;       dst = out  + (long)b*out_bstride; }
    else if (m < ms2) { mo = m - ms1; dst = out2 + (long)b*out2_bstride; }
    else              { mo = m - ms2; dst = out3 + (long)b*out3_bstride; }
    dst += p0 + w*32;
    #pragma unroll
    for (int nt = 0; nt < 2; nt++)
      #pragma unroll
      for (int r = 0; r < 4; r++)
        dst[(long)(mo*16 + fk*4 + r)*HW + nt*16 + fr] = acc[nt][r];
  }
}

// -------- depthwise 3x3 pad 1, 4-wide vectorized --------
__global__ __launch_bounds__(256) void dw3x3v(
    const float* __restrict__ in, int inCH, const float* __restrict__ w,
    float* __restrict__ out, int outCH)
{
  const int t = threadIdx.x;
  const int p4 = blockIdx.x * 256 + t;
  const int ch = blockIdx.y, b = blockIdx.z;
  const int y = p4 >> 6, x0 = (p4 & 63) << 2;
  const float* ip = in + ((long)b*inCH + ch) * HW;
  const float* wp = w + ch*9;
  float a0 = 0.f, a1 = 0.f, a2 = 0.f, a3 = 0.f;
  #pragma unroll
  for (int dy = -1; dy <= 1; dy++) {
    const int yy = y + dy;
    if (yy < 0 || yy > 255) continue;
    const float* rp = ip + yy*256;
    const float4 c = *(const float4*)&rp[x0];
    const float left  = (x0 > 0)   ? rp[x0-1] : 0.f;
    const float right = (x0 < 252) ? rp[x0+4] : 0.f;
    const float w0 = wp[(dy+1)*3+0], w1 = wp[(dy+1)*3+1], w2 = wp[(dy+1)*3+2];
    a0 = fmaf(left, w0, a0); a0 = fmaf(c.x, w1, a0); a0 = fmaf(c.y, w2, a0);
    a1 = fmaf(c.x,  w0, a1); a1 = fmaf(c.y, w1, a1); a1 = fmaf(c.z, w2, a1);
    a2 = fmaf(c.y,  w0, a2); a2 = fmaf(c.z, w1, a2); a2 = fmaf(c.w, w2, a2);
    a3 = fmaf(c.z,  w0, a3); a3 = fmaf(c.w, w1, a3); a3 = fmaf(right, w2, a3);
  }
  float4 o; o.x = a0; o.y = a1; o.z = a2; o.w = a3;
  *(float4*)&out[((long)b*outCH + ch)*HW + y*256 + x0] = o;
}

// ------- depthwise 3x3 fused with v_s permutation (4-wide compute) ----
__global__ __launch_bounds__(256) void dw3x3_vs(
    const float* __restrict__ in, const float* __restrict__ w,
    float* __restrict__ vs)
{
  __shared__ float tile[96*65];
  const int t = threadIdx.x;
  const int gb = blockIdx.x;
  const int b = blockIdx.y;
  const int y = gb >> 2, xb = gb & 3;
  #pragma unroll
  for (int i = 0; i < 6; i++) {
    const int idx = i*256 + t;
    const int ci = idx >> 4, q = idx & 15;
    const int x0 = xb*64 + q*4;
    const float* ip = in + ((long)b*96 + ci) * HW;
    const float* wp = w + ci*9;
    float a0 = 0.f, a1 = 0.f, a2 = 0.f, a3 = 0.f;
    #pragma unroll
    for (int dy = -1; dy <= 1; dy++) {
      const int yy = y + dy;
      if (yy < 0 || yy > 255) continue;
      const float* rp = ip + yy*256;
      const float4 c = *(const float4*)&rp[x0];
      const float left  = (x0 > 0)   ? rp[x0-1] : 0.f;
      const float right = (x0 < 252) ? rp[x0+4] : 0.f;
      const float w0 = wp[(dy+1)*3+0], w1 = wp[(dy+1)*3+1], w2 = wp[(dy+1)*3+2];
      a0 = fmaf(left, w0, a0); a0 = fmaf(c.x, w1, a0); a0 = fmaf(c.y, w2, a0);
      a1 = fmaf(c.x,  w0, a1); a1 = fmaf(c.y, w1, a1); a1 = fmaf(c.z, w2, a1);
      a2 = fmaf(c.y,  w0, a2); a2 = fmaf(c.z, w1, a2); a2 = fmaf(c.w, w2, a2);
      a3 = fmaf(c.z,  w0, a3); a3 = fmaf(c.w, w1, a3); a3 = fmaf(right, w2, a3);
    }
    const int xl = q*4;
    tile[ci*65 + xl    ] = a0;
    tile[ci*65 + xl + 1] = a1;
    tile[ci*65 + xl + 2] = a2;
    tile[ci*65 + xl + 3] = a3;
  }
  __syncthreads();
  const int blk = (y >> 6)*4 + xb;
  float* obase = vs + ((long)b*4096 + (long)(y & 63)*64) * 1536 + blk*96;
  #pragma unroll
  for (int i = 0; i < 24; i++) {
    const int idx = i*256 + t;
    const int nl = idx / 96, ci = idx % 96;
    obase[(long)nl*1536 + ci] = tile[ci*65 + nl];
  }
}

// ---- depthwise 4x4 stride 4 pad 1 (256->64), 4-wide vectorized ----
__global__ __launch_bounds__(256) void dw4x4s4v(
    const float* __restrict__ in, const float* __restrict__ w,
    float* __restrict__ out)
{
  const int t = threadIdx.x;
  const int p = blockIdx.x*256 + t;
  const int ch = blockIdx.y, b = blockIdx.z;
  const int oy = p >> 4, qx = p & 15;
  const int x0 = qx*16;
  const float* ip = in + (long)(b*192 + ch) * HW;
  const float* wp = w + ch*16;
  float a0 = 0.f, a1 = 0.f, a2 = 0.f, a3 = 0.f;
  #pragma unroll
  for (int ty = 0; ty < 4; ty++) {
    const int iy = 4*oy + ty - 1;
    if (iy < 0 || iy > 255) continue;
    const float* rp = ip + iy*256;
    float r[17];
    r[0] = (x0 > 0) ? rp[x0-1] : 0.f;
    #pragma unroll
    for (int k = 0; k < 4; k++) {
      float4 v4 = *(const float4*)&rp[x0 + k*4];
      r[1+k*4+0]=v4.x; r[1+k*4+1]=v4.y; r[1+k*4+2]=v4.z; r[1+k*4+3]=v4.w;
    }
    const float w0=wp[ty*4+0], w1=wp[ty*4+1], w2=wp[ty*4+2], w3=wp[ty*4+3];
    a0=fmaf(r[ 0],w0,a0); a0=fmaf(r[ 1],w1,a0); a0=fmaf(r[ 2],w2,a0); a0=fmaf(r[ 3],w3,a0);
    a1=fmaf(r[ 4],w0,a1); a1=fmaf(r[ 5],w1,a1); a1=fmaf(r[ 6],w2,a1); a1=fmaf(r[ 7],w3,a1);
    a2=fmaf(r[ 8],w0,a2); a2=fmaf(r[ 9],w1,a2); a2=fmaf(r[10],w2,a2); a2=fmaf(r[11],w3,a2);
    a3=fmaf(r[12],w0,a3); a3=fmaf(r[13],w1,a3); a3=fmaf(r[14],w2,a3); a3=fmaf(r[15],w3,a3);
  }
  float4 o; o.x=a0; o.y=a1; o.z=a2; o.w=a3;
  *(float4*)&out[(long)(b*192 + ch)*4096 + oy*64 + qx*4] = o;
}

// ---------------- l2 norm over 192 channels + transpose (both q & k) ----
__global__ __launch_bounds__(256) void l2n192(
    const float* __restrict__ inA, float* __restrict__ outA,
    const float* __restrict__ inB, float* __restrict__ outB)
{
  const int t = threadIdx.x;
  const int wid = t >> 6, lane = t & 63;
  const int gw2 = blockIdx.x * 4 + wid;
  const int sel = gw2 >> 13;
  const int gw = gw2 & 8191;
  const int b = gw >> 12, n = gw & 4095;
  const float* ip = (sel ? inB : inA) + (long)b * 786432;
  float v0 = ip[(long)(lane      ) * 4096 + n];
  float v1 = ip[(long)(lane +  64) * 4096 + n];
  float v2 = ip[(long)(lane + 128) * 4096 + n];
  float ss = v0*v0 + v1*v1 + v2*v2;
  #pragma unroll
  for (int s = 1; s < 64; s <<= 1) ss += __shfl_xor(ss, s, 64);
  float nrm = fmaxf(sqrtf(ss), 1e-12f);
  float* op = (sel ? outB : outA) + ((long)b*4096 + n) * 192;
  op[lane      ] = v0 / nrm;
  op[lane +  64] = v1 / nrm;
  op[lane + 128] = v2 / nrm;
}

// ---------------- split fp32 -> (hi,lo) bf16 planes ----------------
__global__ __launch_bounds__(256) void bf16split(
    const float* __restrict__ in, unsigned short* __restrict__ outp)
{
  const int i = blockIdx.x * 256 + threadIdx.x;
  const int n = i / 192, k = i % 192;
  float f = in[i];
  unsigned short h, l;
  rtn_split(f, &h, &l);
  outp[(long)n*384 + k]       = h;
  outp[(long)n*384 + 192 + k] = l;
}

// ---------------- attention QK^T via split-bf16 MFMA (one batch) ------------
#define LDSROW 40
__global__ __launch_bounds__(256) void attn_qk_mfma(
    const unsigned short* __restrict__ Qsp, const unsigned short* __restrict__ Ksp,
    float* __restrict__ attn, const float* __restrict__ tp)
{
  __shared__ unsigned short qs[256*LDSROW];
  __shared__ unsigned short ks[256*LDSROW];
  const int t = threadIdx.x;
  const int lane = t & 63, w = t >> 6;
  const int n0 = blockIdx.x * 128;
  const int m0 = blockIdx.y * 128;
  const int wr = (w >> 1) * 64, wc = (w & 1) * 64;
  f32x4 acc[4][4] = {};
  const int srow = t & 127;
  const int shl  = t >> 7;
  const unsigned short* qsrc = Qsp + (long)(n0 + srow) * 384 + shl * 192;
  const unsigned short* ksrc = Ksp + (long)(m0 + srow) * 384 + shl * 192;
  unsigned short* qdst = qs + (shl*128 + srow) * LDSROW;
  unsigned short* kdst = ks + (shl*128 + srow) * LDSROW;
  const int fr = lane & 15;
  const int fk = lane >> 4;
  for (int s = 0; s < 6; s++) {
    __syncthreads();
    #pragma unroll
    for (int j = 0; j < 4; j++) {
      *(bf16x8*)(qdst + j*8) = *(const bf16x8*)(qsrc + s*32 + j*8);
      *(bf16x8*)(kdst + j*8) = *(const bf16x8*)(ksrc + s*32 + j*8);
    }
    __syncthreads();
    bf16x8 ah[4], al[4], bh[4], bl[4];
    #pragma unroll
    for (int i = 0; i < 4; i++) {
      ah[i] = *(const bf16x8*)(qs + (      wr + i*16 + fr) * LDSROW + fk*8);
      al[i] = *(const bf16x8*)(qs + (128 + wr + i*16 + fr) * LDSROW + fk*8);
      bh[i] = *(const bf16x8*)(ks + (      wc + i*16 + fr) * LDSROW + fk*8);
      bl[i] = *(const bf16x8*)(ks + (128 + wc + i*16 + fr) * LDSROW + fk*8);
    }
    #pragma unroll
    for (int i = 0; i < 4; i++)
      #pragma unroll
      for (int j = 0; j < 4; j++) {
        acc[i][j] = __builtin_amdgcn_mfma_f32_16x16x32_bf16(ah[i], bh[j], acc[i][j], 0, 0, 0);
        acc[i][j] = __builtin_amdgcn_mfma_f32_16x16x32_bf16(ah[i], bl[j], acc[i][j], 0, 0, 0);
        acc[i][j] = __builtin_amdgcn_mfma_f32_16x16x32_bf16(al[i], bh[j], acc[i][j], 0, 0, 0);
      }
  }
  const float temp = tp[0];
  #pragma unroll
  for (int i = 0; i < 4; i++)
    #pragma unroll
    for (int j = 0; j < 4; j++)
      #pragma unroll
      for (int r = 0; r < 4; r++) {
        const int nn = n0 + wr + i*16 + (lane >> 4)*4 + r;
        const int mm = m0 + wc + j*16 + (lane & 15);
        attn[(long)nn*4096 + mm] = acc[i][j][r] * temp;
      }
}

// ------- top-5 + local mask + softmax + sparse out -------
#define CAP 128
__global__ __launch_bounds__(256) void attn_out_k(
    const float* __restrict__ attn, const float* __restrict__ vs,
    float* __restrict__ outr)
{
  __shared__ float row[4096];
  __shared__ float top5[256*5];
  __shared__ int   lm[CAP];
  __shared__ float lw[CAP];
  __shared__ float ses[CAP];
  __shared__ float redf[8];
  __shared__ int   wsum[4];
  const int t = threadIdx.x;
  const int n = blockIdx.x;
  const float* ar = attn + (long)n * 4096;
  #pragma unroll
  for (int k = 0; k < 16; k++) row[k*256 + t] = ar[k*256 + t];
  __syncthreads();
  float t0=-INFINITY,t1=-INFINITY,t2=-INFINITY,t3=-INFINITY,t4=-INFINITY;
  #pragma unroll
  for (int k = 0; k < 16; k++) {
    float v = row[k*256 + t];
    if (v > t4) {
      if (v > t0)      { t4=t3; t3=t2; t2=t1; t1=t0; t0=v; }
      else if (v > t1) { t4=t3; t3=t2; t2=t1; t1=v; }
      else if (v > t2) { t4=t3; t3=t2; t2=v; }
      else if (v > t3) { t4=t3; t3=v; }
      else             { t4=v; }
    }
  }
  top5[t*5+0]=t0; top5[t*5+1]=t1; top5[t*5+2]=t2; top5[t*5+3]=t3; top5[t*5+4]=t4;
  __syncthreads();
  for (int s = 128; s >= 1; s >>= 1) {
    if (t < s) {
      float* A = &top5[t*5];
      const float* B = &top5[(t+s)*5];
      float m[5]; int i = 0, j = 0;
      #pragma unroll
      for (int k = 0; k < 5; k++) {
        float av = A[i], bv = B[j];
        if (av >= bv) { m[k] = av; i++; } else { m[k] = bv; j++; }
      }
      #pragma unroll
      for (int k = 0; k < 5; k++) A[k] = m[k];
    }
    __syncthreads();
  }
  const float kth = top5[4];
  const int y = n >> 6, x = n & 63;
  int myc = 0;
  float wmax = -INFINITY;
  #pragma unroll
  for (int k = 0; k < 16; k++) {
    int m = k*256 + t;
    float a = row[m];
    int c = ((a >= kth) ? 1 : 0) +
            (((iabs_(y - (m >> 6)) + iabs_(x - (m & 63))) <= 4) ? 1 : 0);
    float wv = a * (float)c;
    if (wv != 0.0f) { myc++; wmax = fmaxf(wmax, wv); }
  }
  int inc = myc;
  #pragma unroll
  for (int s = 1; s < 64; s <<= 1) {
    int v = __shfl_up(inc, s, 64);
    if ((t & 63) >= s) inc += v;
  }
  if ((t & 63) == 63) wsum[t >> 6] = inc;
  __syncthreads();
  int pre = 0;
  #pragma unroll
  for (int wj = 0; wj < 4; wj++) pre += (wj < (t >> 6)) ? wsum[wj] : 0;
  const int base = pre + inc - myc;
  const int cnt = wsum[0] + wsum[1] + wsum[2] + wsum[3];
  {
    int idx = base;
    #pragma unroll
    for (int k = 0; k < 16; k++) {
      int m = k*256 + t;
      float a = row[m];
      int c = ((a >= kth) ? 1 : 0) +
              (((iabs_(y - (m >> 6)) + iabs_(x - (m & 63))) <= 4) ? 1 : 0);
      float wv = a * (float)c;
      if (wv != 0.0f && idx < CAP) { lm[idx] = m; lw[idx] = wv; idx++; }
    }
  }
  #pragma unroll
  for (int s = 1; s < 64; s <<= 1) wmax = fmaxf(wmax, __shfl_xor(wmax, s, 64));
  if ((t & 63) == 0) redf[t >> 6] = wmax;
  __syncthreads();
  const float gmax = fmaxf(fmaxf(redf[0], redf[1]), fmaxf(redf[2], redf[3]));
  __syncthreads();
  if (t < cnt && t < CAP) ses[t] = expf(lw[t] - gmax);
  __syncthreads();
  float ps = (t < cnt && t < CAP) ? ses[t] : 0.f;
  #pragma unroll
  for (int s = 1; s < 64; s <<= 1) ps += __shfl_xor(ps, s, 64);
  if ((t & 63) == 0) redf[4 + (t >> 6)] = ps;
  __syncthreads();
  const float S = redf[4] + redf[5] + redf[6] + redf[7];
  const float invS = 1.0f / S;
  float a0=0,a1=0,a2=0,a3=0,a4=0,a5=0;
  const int ecnt = (cnt < CAP) ? cnt : CAP;
  for (int e = 0; e < ecnt; e++) {
    float se = ses[e] * invS;
    const float* vr = vs + (long)lm[e] * 1536;
    a0 = fmaf(se, vr[        t], a0);
    a1 = fmaf(se, vr[ 256 + t], a1);
    a2 = fmaf(se, vr[ 512 + t], a2);
    a3 = fmaf(se, vr[ 768 + t], a3);
    a4 = fmaf(se, vr[1024 + t], a4);
    a5 = fmaf(se, vr[1280 + t], a5);
  }
  float* orow = outr + (long)n * 1536;
  orow[        t] = a0;
  orow[ 256 + t] = a1;
  orow[ 512 + t] = a2;
  orow[ 768 + t] = a3;
  orow[1024 + t] = a4;
  orow[1280 + t] = a5;
}

// ------- per-channel l2 norm over 65536 (fhr k2); in-place safe -------
__global__ __launch_bounds__(1024) void l2n_sp(
    const float* __restrict__ in, float* __restrict__ out)
{
  const int ch = blockIdx.x, b = blockIdx.y, t = threadIdx.x;
  const float* ip = in + ((long)b*96 + ch) * HW;
  float ss = 0.f;
  for (int i = t; i < 65536; i += 1024) { float v = ip[i]; ss = fmaf(v, v, ss); }
  __shared__ float red[16];
  #pragma unroll
  for (int s = 1; s < 64; s <<= 1) ss += __shfl_xor(ss, s, 64);
  if ((t & 63) == 0) red[t >> 6] = ss;
  __syncthreads();
  if (t == 0) {
    float s2 = 0.f;
    for (int i = 0; i < 16; i++) s2 += red[i];
    red[0] = fmaxf(sqrtf(s2), 1e-12f);
  }
  __syncthreads();
  const float nrm = red[0];
  float* op = out + ((long)b*96 + ch) * HW;
  for (int i = t; i < 65536; i += 1024) op[i] = ip[i] / nrm;
}

// -------- a2 stage 1: raw-q Gram + q sum-of-squares partials ----------
#define A2_NCH 16
__global__ __launch_bounds__(256) void a2_part(
    const float* __restrict__ q2n, const float* __restrict__ k2n,
    float* __restrict__ part, float* __restrict__ qqpart)
{
  __shared__ float sh[24*260];
  const int t = threadIdx.x;
  const int ch = blockIdx.x, h = blockIdx.y, b = blockIdx.z;
  const long base = ((long)b*96 + h*12) * HW + ch*4096;
  const int c = t / 12, d = t - (t/12)*12;
  float acc = 0.f;
  float qq = 0.f;
  for (int sub = 0; sub < 16; sub++) {
    __syncthreads();
    #pragma unroll
    for (int j = 0; j < 6; j++) {
      const int v = j*256 + t;
      const int row = v >> 6;
      const int col4 = v & 63;
      const float* src = (row < 12)
        ? q2n + base + (long)row*HW + sub*256 + col4*4
        : k2n + base + (long)(row-12)*HW + sub*256 + col4*4;
      *(float4*)&sh[row*260 + col4*4] = *(const float4*)src;
    }
    __syncthreads();
    if (t < 144) {
      const float* qr = &sh[c*260];
      const float* kr = &sh[(12+d)*260];
      #pragma unroll
      for (int i4 = 0; i4 < 64; i4++) {
        float4 qv = *(const float4*)&qr[i4*4];
        float4 kv = *(const float4*)&kr[i4*4];
        acc = fmaf(qv.x, kv.x, acc);
        acc = fmaf(qv.y, kv.y, acc);
        acc = fmaf(qv.z, kv.z, acc);
        acc = fmaf(qv.w, kv.w, acc);
      }
    } else if (t < 156) {
      const float* qr = &sh[(t-144)*260];
      #pragma unroll
      for (int i4 = 0; i4 < 64; i4++) {
        float4 qv = *(const float4*)&qr[i4*4];
        qq = fmaf(qv.x, qv.x, qq);
        qq = fmaf(qv.y, qv.y, qq);
        qq = fmaf(qv.z, qv.z, qq);
        qq = fmaf(qv.w, qv.w, qq);
      }
    }
  }
  if (t < 144)
    part[(((long)b*8 + h)*A2_NCH + ch)*144 + t] = acc;
  else if (t < 156)
    qqpart[(((long)b*8 + h)*A2_NCH + ch)*12 + (t-144)] = qq;
}

// -------- a2 stage 2: fold q-normalization --------
__global__ __launch_bounds__(256) void a2_fin(
    const float* __restrict__ part, const float* __restrict__ qqpart,
    const float* __restrict__ temp, float* __restrict__ a2s)
{
  __shared__ float m[144];
  __shared__ float qn[12];
  const int t = threadIdx.x;
  const int h = blockIdx.x, b = blockIdx.y;
  if (t < 144) {
    float s = 0.f;
    const float* pp = part + (((long)b*8 + h)*A2_NCH)*144 + t;
    #pragma unroll
    for (int ch = 0; ch < A2_NCH; ch++) s += pp[ch*144];
    m[t] = s;
  } else if (t < 156) {
    float s = 0.f;
    const float* pp = qqpart + (((long)b*8 + h)*A2_NCH)*12 + (t-144);
    #pragma unroll
    for (int ch = 0; ch < A2_NCH; ch++) s += pp[ch*12];
    qn[t-144] = fmaxf(sqrtf(s), 1e-12f);
  }
  __syncthreads();
  if (t < 12) {
    const float tv = temp[h];
    const float scale = tv / qn[t];
    float mx = -INFINITY;
    float a[12];
    #pragma unroll
    for (int d = 0; d < 12; d++) { a[d] = m[t*12+d] * scale; mx = fmaxf(mx, a[d]); }
    float e[12], sum = 0.f;
    #pragma unroll
    for (int d = 0; d < 12; d++) { e[d] = expf(a[d]-mx); sum += e[d]; }
    float inv = 1.0f/sum;
    float* op = a2s + (((long)b*8 + h)*12 + t)*12;
    #pragma unroll
    for (int d = 0; d < 12; d++) op[d] = e[d]*inv;
  }
}

extern "C" void kernel_launch(void* const* d_in, const int* in_sizes, int n_in,
                              void* d_out, int out_size, void* d_ws, size_t ws_size,
                              hipStream_t stream) {
  const float* x        = (const float*)d_in[0];
  const float* qk_w     = (const float*)d_in[1];
  const float* qk_dw    = (const float*)d_in[2];
  const float* v_w      = (const float*)d_in[3];
  const float* v_dw     = (const float*)d_in[4];
  const float* k2_w     = (const float*)d_in[5];
  const float* k2_dw    = (const float*)d_in[6];
  const float* q2_w     = (const float*)d_in[7];
  const float* q2_dw    = (const float*)d_in[8];
  const float* proj_w   = (const float*)d_in[9];
  const float* sab_temp = (const float*)d_in[10];
  const float* fqkv_w   = (const float*)d_in[11];
  const float* fqkv_dw  = (const float*)d_in[12];
  const float* fproj_w  = (const float*)d_in[13];
  const float* fhr_temp = (const float*)d_in[14];
  float* out = (float*)d_out;
  float* ws  = (float*)d_ws;

  float* O2  = out;
  float* KS  = out + 12582912;
  float* VS  = out + 14155776;
  float* K2N = out + 26738688;
  float* V2  = out + 39321600;

  float* A0   = ws;
  float* A1   = ws + 25165824;          // attn-out: ws[25.17M : 37.75M]
  float* QD   = ws + 50331648;
  float* KD   = ws + 51904512;
  float* QN   = ws + 53477376;
  float* A2S  = ws + 55050240;
  float* PART = ws + 55052544;
  unsigned short* QSP = (unsigned short*)(A0 + 16777216);
  unsigned short* KSP = (unsigned short*)(A0 + 16777216 + 786432);
  unsigned short* WHL = (unsigned short*)QN;
  // fhr-phase (post-attention) disjoint buffers:
  float* P1  = ws;                      // pre-q2   ws[0      : 12.58M]
  float* P2  = ws + 12582912;           // pre-k2   ws[12.58M : 25.17M]
  float* P3  = ws + 37748736;           // pre-v2   ws[37.75M : 50.33M]
  float* ALNQ = P2;                     // raw q2-dw (P2 dead after its dw)
  float* QQP = QD;
  unsigned short* W2HL = (unsigned short*)PART;

  dim3 b256(256), b1024(1024);

  wsplit<<<dim3(252), b256, 0, stream>>>(qk_w, v_w, q2_w, k2_w, WHL);
  // fused qk-conv (192ch -> A0) + v-conv (96ch -> A1), Cout=288
  conv1x1_mfma<<<dim3(512,2), b256, 0, stream>>>(
      x, 96L*HW, WHL, WHL+110592, 0, 0,
      A0, 192L*HW, A1, 96L*HW, A1, 96L*HW, 12, 18, 18, 0);
  dw3x3_vs<<<dim3(1024,2), b256, 0, stream>>>(A1, v_dw, VS);
  dw3x3v<<<dim3(64,192,2), b256, 0, stream>>>(A0, 192, qk_dw, A1, 192);
  conv1x1_mfma<<<dim3(512,2), b256, 0, stream>>>(
      A1, 192L*HW, WHL, WHL+110592, 0, 288,
      A0, 192L*HW, A0, 192L*HW, A0, 192L*HW, 12, 12, 12, 0);
  dw4x4s4v<<<dim3(4,192,2), b256, 0, stream>>>(A0, q2_dw, QD);
  conv1x1_mfma<<<dim3(512,2), b256, 0, stream>>>(
      A1 + 96L*HW, 192L*HW, WHL, WHL+110592, 0, 480,
      A0, 192L*HW, A0, 192L*HW, A0, 192L*HW, 12, 12, 12, 0);
  dw4x4s4v<<<dim3(4,192,2), b256, 0, stream>>>(A0, k2_dw, KD);
  l2n192<<<dim3(4096), b256, 0, stream>>>(QD, QN, KD, KS);
  for (int b = 0; b < 2; b++) {
    bf16split<<<dim3(3072), b256, 0, stream>>>(QN + (long)b*786432, QSP);
    bf16split<<<dim3(3072), b256, 0, stream>>>(KS + (long)b*786432, KSP);
    attn_qk_mfma<<<dim3(32,32), b256, 0, stream>>>(QSP, KSP, A0, sab_temp);
    attn_out_k<<<dim3(4096), b256, 0, stream>>>(
        A0, VS + (long)b*6291456, A1 + (long)b*6291456);
  }
  // compose CF = fqkv @ proj -> WHL rows 768..1055
  wcomp1<<<dim3(108), b256, 0, stream>>>(fqkv_w, proj_w, WHL);
  // fused (proj+fhr-qkv) conv, mode 1 on attn-out (A1): q2->P1, k2->P2, v2->P3
  conv1x1_mfma<<<dim3(512,2), b256, 0, stream>>>(
      A1, 6291456L, WHL, WHL+110592, 0, 768,
      P1, 96L*HW, P2, 96L*HW, P3, 96L*HW, 6, 12, 18, 1);
  // depthwise: k2 -> K2N, v2 -> V2, then q2 -> ALNQ (P2 slot, dead)
  dw3x3v<<<dim3(64,96,2), b256, 0, stream>>>(P2, 96, fqkv_dw +  864, K2N, 96);
  dw3x3v<<<dim3(64,96,2), b256, 0, stream>>>(P3, 96, fqkv_dw + 1728, V2,  96);
  dw3x3v<<<dim3(64,96,2), b256, 0, stream>>>(P1, 96, fqkv_dw,        ALNQ, 96);
  l2n_sp<<<dim3(96,2), b1024, 0, stream>>>(K2N, K2N);
  a2_part<<<dim3(A2_NCH,8,2), b256, 0, stream>>>(ALNQ, K2N, PART, QQP);
  a2_fin<<<dim3(8,2), b256, 0, stream>>>(PART, QQP, fhr_temp, A2S);
  // compose W2[b] = fproj @ blockdiag(a2[b]) (PART region; a2_fin consumed it)
  wcomp2<<<dim3(36,2), b256, 0, stream>>>(fproj_w, A2S, W2HL);
  // o2 = W2[b] @ v2 -> d_out (per-batch weights)
  conv1x1_mfma<<<dim3(512,2), b256, 0, stream>>>(
      V2, 96L*HW, W2HL, W2HL+18432, 9216, 0,
      O2, 96L*HW, O2, 96L*HW, O2, 96L*HW, 6, 6, 6, 0);
}

// Round 16
// 805.779 us; speedup vs baseline: 2.3863x; 1.0317x over previous
//
#include <hip/hip_runtime.h>
#include <hip/hip_bf16.h>
#include <math.h>

#define HW 65536L

typedef __attribute__((ext_vector_type(8))) short bf16x8;
typedef __attribute__((ext_vector_type(4))) float f32x4;

__device__ __forceinline__ int iabs_(int v) { return v < 0 ? -v : v; }

__device__ __forceinline__ void rtn_split(float f, unsigned short* h, unsigned short* l) {
  __hip_bfloat16 hb = __float2bfloat16(f);
  float hf = __bfloat162float(hb);
  __hip_bfloat16 lb = __float2bfloat16(f - hf);
  *h = *(unsigned short*)&hb;
  *l = *(unsigned short*)&lb;
}

// ---- split static 1x1 weights into (hi,lo) bf16 planes: whl[2][1152][96] ----
__global__ __launch_bounds__(256) void wsplit(
    const float* __restrict__ qk, const float* __restrict__ v,
    const float* __restrict__ q2, const float* __restrict__ k2,
    unsigned short* __restrict__ whl)
{
  const int e = blockIdx.x*256 + threadIdx.x;
  if (e >= 64512) return;
  const int row = e / 96, col = e - row*96;
  float f;
  if      (row <  192) f = qk[e];
  else if (row <  288) f = v [(row-192)*96+col];
  else if (row <  480) f = q2[(row-288)*96+col];
  else                 f = k2[(row-480)*96+col];
  rtn_split(f, &whl[e], &whl[110592 + e]);
}

// ---- compose CF = fqkv(288x96) @ proj(96x96) -> WHL rows 768..1055 ----
__global__ __launch_bounds__(256) void wcomp1(
    const float* __restrict__ fq, const float* __restrict__ pj,
    unsigned short* __restrict__ whl)
{
  const int e = blockIdx.x*256 + threadIdx.x;
  if (e >= 27648) return;
  const int row = e / 96, col = e - row*96;
  float s = 0.f;
  #pragma unroll 8
  for (int c = 0; c < 96; c++) s = fmaf(fq[row*96 + c], pj[c*96 + col], s);
  rtn_split(s, &whl[(768+row)*96 + col], &whl[110592 + (768+row)*96 + col]);
}

// ---- compose W2[b] = fproj(96x96) @ blockdiag(a2[b]) ----
__global__ __launch_bounds__(256) void wcomp2(
    const float* __restrict__ fp, const float* __restrict__ a2s,
    unsigned short* __restrict__ w2)
{
  const int e = blockIdx.x*256 + threadIdx.x;
  const int b = blockIdx.y;
  if (e >= 9216) return;
  const int co = e / 96, dg = e - co*96;
  const int h = dg / 12, d = dg - h*12;
  const float* ab = a2s + (((long)b*8 + h)*12)*12 + d;
  const float* fpb = fp + co*96 + h*12;
  float s = 0.f;
  #pragma unroll
  for (int c = 0; c < 12; c++) s = fmaf(fpb[c], ab[c*12], s);
  rtn_split(s, &w2[(long)b*9216 + e], &w2[18432 + (long)b*9216 + e]);
}

// ------- conv 1x1 via split-bf16 MFMA (3-way output split) -------
#define BLDS 104
__global__ __launch_bounds__(256) void conv1x1_mfma(
    const float* __restrict__ in, long in_bstride,
    const unsigned short* __restrict__ whl_hi, const unsigned short* __restrict__ whl_lo,
    long wbstride, int wrow0,
    float* __restrict__ out, long out_bstride,
    float* __restrict__ out2, long out2_bstride,
    float* __restrict__ out3, long out3_bstride,
    int ms1, int ms2, int mtiles, int mode)
{
  __shared__ unsigned short bhs[128*BLDS];
  __shared__ unsigned short bls[128*BLDS];
  const int t = threadIdx.x;
  const int p0 = blockIdx.x * 128;
  const int b = blockIdx.y;
  if (mode == 0) {
    #pragma unroll
    for (int it = 0; it < 6; it++) {
      const int idx = it*256 + t;
      const int g8 = idx >> 7;
      const int pix = idx & 127;
      const float* src = in + (long)b*in_bstride + (long)(g8*8)*HW + p0 + pix;
      unsigned hh[8], ll[8];
      #pragma unroll
      for (int j = 0; j < 8; j++) {
        float f = src[(long)j*HW];
        unsigned u = __float_as_uint(f);
        hh[j] = u >> 16;
        float lof = f - __uint_as_float(u & 0xFFFF0000u);
        __hip_bfloat16 lb = __float2bfloat16(lof);
        ll[j] = *(unsigned short*)&lb;
      }
      uint4 hv, lv;
      hv.x = hh[0]|(hh[1]<<16); hv.y = hh[2]|(hh[3]<<16);
      hv.z = hh[4]|(hh[5]<<16); hv.w = hh[6]|(hh[7]<<16);
      lv.x = ll[0]|(ll[1]<<16); lv.y = ll[2]|(ll[3]<<16);
      lv.z = ll[4]|(ll[5]<<16); lv.w = ll[6]|(ll[7]<<16);
      *(uint4*)(bhs + pix*BLDS + g8*8) = hv;
      *(uint4*)(bls + pix*BLDS + g8*8) = lv;
    }
  } else {
    const int pp = t >> 1, half = (t & 1)*48;
    const int p = p0 + pp;
    const int py = p >> 8, px = p & 255;
    const float* src = in + (long)b*in_bstride
        + ((long)((py & 63)*64 + (px & 63))*16 + ((py >> 6)*4 + (px >> 6)))*96 + half;
    #pragma unroll
    for (int j4 = 0; j4 < 12; j4++) {
      float4 v4 = *(const float4*)&src[j4*4];
      float fv[4] = {v4.x, v4.y, v4.z, v4.w};
      unsigned hh[4], ll[4];
      #pragma unroll
      for (int u4 = 0; u4 < 4; u4++) {
        unsigned u = __float_as_uint(fv[u4]);
        hh[u4] = u >> 16;
        float lof = fv[u4] - __uint_as_float(u & 0xFFFF0000u);
        __hip_bfloat16 lb = __float2bfloat16(lof);
        ll[u4] = *(unsigned short*)&lb;
      }
      uint2 hv, lv;
      hv.x = hh[0] | (hh[1] << 16); hv.y = hh[2] | (hh[3] << 16);
      lv.x = ll[0] | (ll[1] << 16); lv.y = ll[2] | (ll[3] << 16);
      *(uint2*)(bhs + pp*BLDS + half + j4*4) = hv;
      *(uint2*)(bls + pp*BLDS + half + j4*4) = lv;
    }
  }
  __syncthreads();
  const int lane = t & 63, w = t >> 6;
  const int fr = lane & 15, fk = lane >> 4;
  bf16x8 Bh[2][3], Bl[2][3];
  #pragma unroll
  for (int nt = 0; nt < 2; nt++)
    #pragma unroll
    for (int kt = 0; kt < 3; kt++) {
      const int pix = w*32 + nt*16 + fr;
      Bh[nt][kt] = *(const bf16x8*)(bhs + pix*BLDS + kt*32 + fk*8);
      Bl[nt][kt] = *(const bf16x8*)(bls + pix*BLDS + kt*32 + fk*8);
    }
  const long wb = (long)b*wbstride;
  for (int m = 0; m < mtiles; m++) {
    const long wbase = wb + (long)(wrow0 + m*16 + fr)*96 + fk*8;
    bf16x8 Ah[3], Al[3];
    #pragma unroll
    for (int kt = 0; kt < 3; kt++) {
      Ah[kt] = *(const bf16x8*)(whl_hi + wbase + kt*32);
      Al[kt] = *(const bf16x8*)(whl_lo + wbase + kt*32);
    }
    f32x4 acc[2] = {};
    #pragma unroll
    for (int nt = 0; nt < 2; nt++)
      #pragma unroll
      for (int kt = 0; kt < 3; kt++) {
        acc[nt] = __builtin_amdgcn_mfma_f32_16x16x32_bf16(Ah[kt], Bh[nt][kt], acc[nt], 0, 0, 0);
        acc[nt] = __builtin_amdgcn_mfma_f32_16x16x32_bf16(Ah[kt], Bl[nt][kt], acc[nt], 0, 0, 0);
        acc[nt] = __builtin_amdgcn_mfma_f32_16x16x32_bf16(Al[kt], Bh[nt][kt], acc[nt], 0, 0, 0);
      }
    int mo; float* dst;
    if (m < ms1)      { mo = m;       dst = out  + (long)b*out_bstride; }
    else if (m < ms2) { mo = m - ms1; dst = out2 + (long)b*out2_bstride; }
    else              { mo = m - ms2; dst = out3 + (long)b*out3_bstride; }
    dst += p0 + w*32;
    #pragma unroll
    for (int nt = 0; nt < 2; nt++)
      #pragma unroll
      for (int r = 0; r < 4; r++)
        dst[(long)(mo*16 + fk*4 + r)*HW + nt*16 + fr] = acc[nt][r];
  }
}

// -------- depthwise 3x3 pad 1, 4-wide vectorized --------
__global__ __launch_bounds__(256) void dw3x3v(
    const float* __restrict__ in, int inCH, const float* __restrict__ w,
    float* __restrict__ out, int outCH)
{
  const int t = threadIdx.x;
  const int p4 = blockIdx.x * 256 + t;
  const int ch = blockIdx.y, b = blockIdx.z;
  const int y = p4 >> 6, x0 = (p4 & 63) << 2;
  const float* ip = in + ((long)b*inCH + ch) * HW;
  const float* wp = w + ch*9;
  float a0 = 0.f, a1 = 0.f, a2 = 0.f, a3 = 0.f;
  #pragma unroll
  for (int dy = -1; dy <= 1; dy++) {
    const int yy = y + dy;
    if (yy < 0 || yy > 255) continue;
    const float* rp = ip + yy*256;
    const float4 c = *(const float4*)&rp[x0];
    const float left  = (x0 > 0)   ? rp[x0-1] : 0.f;
    const float right = (x0 < 252) ? rp[x0+4] : 0.f;
    const float w0 = wp[(dy+1)*3+0], w1 = wp[(dy+1)*3+1], w2 = wp[(dy+1)*3+2];
    a0 = fmaf(left, w0, a0); a0 = fmaf(c.x, w1, a0); a0 = fmaf(c.y, w2, a0);
    a1 = fmaf(c.x,  w0, a1); a1 = fmaf(c.y, w1, a1); a1 = fmaf(c.z, w2, a1);
    a2 = fmaf(c.y,  w0, a2); a2 = fmaf(c.z, w1, a2); a2 = fmaf(c.w, w2, a2);
    a3 = fmaf(c.z,  w0, a3); a3 = fmaf(c.w, w1, a3); a3 = fmaf(right, w2, a3);
  }
  float4 o; o.x = a0; o.y = a1; o.z = a2; o.w = a3;
  *(float4*)&out[((long)b*outCH + ch)*HW + y*256 + x0] = o;
}

// ------- depthwise 3x3 fused with v_s permutation (4-wide compute) ----
__global__ __launch_bounds__(256) void dw3x3_vs(
    const float* __restrict__ in, const float* __restrict__ w,
    float* __restrict__ vs)
{
  __shared__ float tile[96*65];
  const int t = threadIdx.x;
  const int gb = blockIdx.x;
  const int b = blockIdx.y;
  const int y = gb >> 2, xb = gb & 3;
  #pragma unroll
  for (int i = 0; i < 6; i++) {
    const int idx = i*256 + t;
    const int ci = idx >> 4, q = idx & 15;
    const int x0 = xb*64 + q*4;
    const float* ip = in + ((long)b*96 + ci) * HW;
    const float* wp = w + ci*9;
    float a0 = 0.f, a1 = 0.f, a2 = 0.f, a3 = 0.f;
    #pragma unroll
    for (int dy = -1; dy <= 1; dy++) {
      const int yy = y + dy;
      if (yy < 0 || yy > 255) continue;
      const float* rp = ip + yy*256;
      const float4 c = *(const float4*)&rp[x0];
      const float left  = (x0 > 0)   ? rp[x0-1] : 0.f;
      const float right = (x0 < 252) ? rp[x0+4] : 0.f;
      const float w0 = wp[(dy+1)*3+0], w1 = wp[(dy+1)*3+1], w2 = wp[(dy+1)*3+2];
      a0 = fmaf(left, w0, a0); a0 = fmaf(c.x, w1, a0); a0 = fmaf(c.y, w2, a0);
      a1 = fmaf(c.x,  w0, a1); a1 = fmaf(c.y, w1, a1); a1 = fmaf(c.z, w2, a1);
      a2 = fmaf(c.y,  w0, a2); a2 = fmaf(c.z, w1, a2); a2 = fmaf(c.w, w2, a2);
      a3 = fmaf(c.z,  w0, a3); a3 = fmaf(c.w, w1, a3); a3 = fmaf(right, w2, a3);
    }
    const int xl = q*4;
    tile[ci*65 + xl    ] = a0;
    tile[ci*65 + xl + 1] = a1;
    tile[ci*65 + xl + 2] = a2;
    tile[ci*65 + xl + 3] = a3;
  }
  __syncthreads();
  const int blk = (y >> 6)*4 + xb;
  float* obase = vs + ((long)b*4096 + (long)(y & 63)*64) * 1536 + blk*96;
  #pragma unroll
  for (int i = 0; i < 24; i++) {
    const int idx = i*256 + t;
    const int nl = idx / 96, ci = idx % 96;
    obase[(long)nl*1536 + ci] = tile[ci*65 + nl];
  }
}

// ---- depthwise 4x4 stride 4 pad 1 (256->64), 4-wide vectorized ----
__global__ __launch_bounds__(256) void dw4x4s4v(
    const float* __restrict__ in, const float* __restrict__ w,
    float* __restrict__ out)
{
  const int t = threadIdx.x;
  const int p = blockIdx.x*256 + t;
  const int ch = blockIdx.y, b = blockIdx.z;
  const int oy = p >> 4, qx = p & 15;
  const int x0 = qx*16;
  const float* ip = in + (long)(b*192 + ch) * HW;
  const float* wp = w + ch*16;
  float a0 = 0.f, a1 = 0.f, a2 = 0.f, a3 = 0.f;
  #pragma unroll
  for (int ty = 0; ty < 4; ty++) {
    const int iy = 4*oy + ty - 1;
    if (iy < 0 || iy > 255) continue;
    const float* rp = ip + iy*256;
    float r[17];
    r[0] = (x0 > 0) ? rp[x0-1] : 0.f;
    #pragma unroll
    for (int k = 0; k < 4; k++) {
      float4 v4 = *(const float4*)&rp[x0 + k*4];
      r[1+k*4+0]=v4.x; r[1+k*4+1]=v4.y; r[1+k*4+2]=v4.z; r[1+k*4+3]=v4.w;
    }
    const float w0=wp[ty*4+0], w1=wp[ty*4+1], w2=wp[ty*4+2], w3=wp[ty*4+3];
    a0=fmaf(r[ 0],w0,a0); a0=fmaf(r[ 1],w1,a0); a0=fmaf(r[ 2],w2,a0); a0=fmaf(r[ 3],w3,a0);
    a1=fmaf(r[ 4],w0,a1); a1=fmaf(r[ 5],w1,a1); a1=fmaf(r[ 6],w2,a1); a1=fmaf(r[ 7],w3,a1);
    a2=fmaf(r[ 8],w0,a2); a2=fmaf(r[ 9],w1,a2); a2=fmaf(r[10],w2,a2); a2=fmaf(r[11],w3,a2);
    a3=fmaf(r[12],w0,a3); a3=fmaf(r[13],w1,a3); a3=fmaf(r[14],w2,a3); a3=fmaf(r[15],w3,a3);
  }
  float4 o; o.x=a0; o.y=a1; o.z=a2; o.w=a3;
  *(float4*)&out[(long)(b*192 + ch)*4096 + oy*64 + qx*4] = o;
}

// ---------------- l2 norm over 192 channels + transpose (both q & k) ----
__global__ __launch_bounds__(256) void l2n192(
    const float* __restrict__ inA, float* __restrict__ outA,
    const float* __restrict__ inB, float* __restrict__ outB)
{
  const int t = threadIdx.x;
  const int wid = t >> 6, lane = t & 63;
  const int gw2 = blockIdx.x * 4 + wid;
  const int sel = gw2 >> 13;
  const int gw = gw2 & 8191;
  const int b = gw >> 12, n = gw & 4095;
  const float* ip = (sel ? inB : inA) + (long)b * 786432;
  float v0 = ip[(long)(lane      ) * 4096 + n];
  float v1 = ip[(long)(lane +  64) * 4096 + n];
  float v2 = ip[(long)(lane + 128) * 4096 + n];
  float ss = v0*v0 + v1*v1 + v2*v2;
  #pragma unroll
  for (int s = 1; s < 64; s <<= 1) ss += __shfl_xor(ss, s, 64);
  float nrm = fmaxf(sqrtf(ss), 1e-12f);
  float* op = (sel ? outB : outA) + ((long)b*4096 + n) * 192;
  op[lane      ] = v0 / nrm;
  op[lane +  64] = v1 / nrm;
  op[lane + 128] = v2 / nrm;
}

// ------- split fp32 -> (hi,lo) bf16 planes; both batches (R16) -------
__global__ __launch_bounds__(256) void bf16split(
    const float* __restrict__ in, unsigned short* __restrict__ outp)
{
  const int i = blockIdx.x * 256 + threadIdx.x;   // 0..1572863 (2 batches)
  const int n = i / 192, k = i % 192;             // n: 0..8191 global row
  float f = in[i];
  unsigned short h, l;
  rtn_split(f, &h, &l);
  outp[(long)n*384 + k]       = h;
  outp[(long)n*384 + 192 + k] = l;
}

// ------- attention QK^T via split-bf16 MFMA (R16: both batches) -------
#define LDSROW 40
__global__ __launch_bounds__(256) void attn_qk_mfma(
    const unsigned short* __restrict__ Qsp, const unsigned short* __restrict__ Ksp,
    float* __restrict__ attn, const float* __restrict__ tp)
{
  __shared__ unsigned short qs[256*LDSROW];
  __shared__ unsigned short ks[256*LDSROW];
  const int t = threadIdx.x;
  const int lane = t & 63, w = t >> 6;
  const int n0 = blockIdx.x * 128;
  const int m0 = blockIdx.y * 128;
  const int bb = blockIdx.z;
  const unsigned short* Qb = Qsp + (long)bb*1572864;
  const unsigned short* Kb = Ksp + (long)bb*1572864;
  float* attb = attn + (long)bb*16777216;
  const int wr = (w >> 1) * 64, wc = (w & 1) * 64;
  f32x4 acc[4][4] = {};
  const int srow = t & 127;
  const int shl  = t >> 7;
  const unsigned short* qsrc = Qb + (long)(n0 + srow) * 384 + shl * 192;
  const unsigned short* ksrc = Kb + (long)(m0 + srow) * 384 + shl * 192;
  unsigned short* qdst = qs + (shl*128 + srow) * LDSROW;
  unsigned short* kdst = ks + (shl*128 + srow) * LDSROW;
  const int fr = lane & 15;
  const int fk = lane >> 4;
  for (int s = 0; s < 6; s++) {
    __syncthreads();
    #pragma unroll
    for (int j = 0; j < 4; j++) {
      *(bf16x8*)(qdst + j*8) = *(const bf16x8*)(qsrc + s*32 + j*8);
      *(bf16x8*)(kdst + j*8) = *(const bf16x8*)(ksrc + s*32 + j*8);
    }
    __syncthreads();
    bf16x8 ah[4], al[4], bh[4], bl[4];
    #pragma unroll
    for (int i = 0; i < 4; i++) {
      ah[i] = *(const bf16x8*)(qs + (      wr + i*16 + fr) * LDSROW + fk*8);
      al[i] = *(const bf16x8*)(qs + (128 + wr + i*16 + fr) * LDSROW + fk*8);
      bh[i] = *(const bf16x8*)(ks + (      wc + i*16 + fr) * LDSROW + fk*8);
      bl[i] = *(const bf16x8*)(ks + (128 + wc + i*16 + fr) * LDSROW + fk*8);
    }
    #pragma unroll
    for (int i = 0; i < 4; i++)
      #pragma unroll
      for (int j = 0; j < 4; j++) {
        acc[i][j] = __builtin_amdgcn_mfma_f32_16x16x32_bf16(ah[i], bh[j], acc[i][j], 0, 0, 0);
        acc[i][j] = __builtin_amdgcn_mfma_f32_16x16x32_bf16(ah[i], bl[j], acc[i][j], 0, 0, 0);
        acc[i][j] = __builtin_amdgcn_mfma_f32_16x16x32_bf16(al[i], bh[j], acc[i][j], 0, 0, 0);
      }
  }
  const float temp = tp[0];
  #pragma unroll
  for (int i = 0; i < 4; i++)
    #pragma unroll
    for (int j = 0; j < 4; j++)
      #pragma unroll
      for (int r = 0; r < 4; r++) {
        const int nn = n0 + wr + i*16 + (lane >> 4)*4 + r;
        const int mm = m0 + wc + j*16 + (lane & 15);
        attb[(long)nn*4096 + mm] = acc[i][j][r] * temp;
      }
}

// ------- top-5 + local mask + softmax + sparse out -------
// R16: both batches, XCD-chunked row swizzle, register-resident row.
#define CAP 128
__global__ __launch_bounds__(256) void attn_out_k(
    const float* __restrict__ attn, const float* __restrict__ vs,
    float* __restrict__ outr)
{
  __shared__ float top5[256*5];
  __shared__ int   lm[CAP];
  __shared__ float lw[CAP];
  __shared__ float ses[CAP];
  __shared__ float redf[8];
  __shared__ int   wsum[4];
  const int t = threadIdx.x;
  const int bid = blockIdx.x;
  const int n = ((bid & 7) << 9) | (bid >> 3);   // XCD-chunked: each XCD gets 512 contiguous rows
  const int bb = blockIdx.y;
  const float* ar = attn + (long)bb*16777216 + (long)n * 4096;
  const float* vsb = vs + (long)bb*6291456;
  float av[16];
  float t0=-INFINITY,t1=-INFINITY,t2=-INFINITY,t3=-INFINITY,t4=-INFINITY;
  #pragma unroll
  for (int k = 0; k < 16; k++) {
    float v = ar[k*256 + t];
    av[k] = v;
    if (v > t4) {
      if (v > t0)      { t4=t3; t3=t2; t2=t1; t1=t0; t0=v; }
      else if (v > t1) { t4=t3; t3=t2; t2=t1; t1=v; }
      else if (v > t2) { t4=t3; t3=t2; t2=v; }
      else if (v > t3) { t4=t3; t3=v; }
      else             { t4=v; }
    }
  }
  top5[t*5+0]=t0; top5[t*5+1]=t1; top5[t*5+2]=t2; top5[t*5+3]=t3; top5[t*5+4]=t4;
  __syncthreads();
  for (int s = 128; s >= 1; s >>= 1) {
    if (t < s) {
      float* A = &top5[t*5];
      const float* B = &top5[(t+s)*5];
      float m[5]; int i = 0, j = 0;
      #pragma unroll
      for (int k = 0; k < 5; k++) {
        float avv = A[i], bv = B[j];
        if (avv >= bv) { m[k] = avv; i++; } else { m[k] = bv; j++; }
      }
      #pragma unroll
      for (int k = 0; k < 5; k++) A[k] = m[k];
    }
    __syncthreads();
  }
  const float kth = top5[4];
  const int y = n >> 6, x = n & 63;
  int myc = 0;
  float wmax = -INFINITY;
  float fv[16];
  #pragma unroll
  for (int k = 0; k < 16; k++) {
    int m = k*256 + t;
    float a = av[k];
    int c = ((a >= kth) ? 1 : 0) +
            (((iabs_(y - (m >> 6)) + iabs_(x - (m & 63))) <= 4) ? 1 : 0);
    float wv = a * (float)c;
    fv[k] = wv;
    if (wv != 0.0f) { myc++; wmax = fmaxf(wmax, wv); }
  }
  int inc = myc;
  #pragma unroll
  for (int s = 1; s < 64; s <<= 1) {
    int v = __shfl_up(inc, s, 64);
    if ((t & 63) >= s) inc += v;
  }
  if ((t & 63) == 63) wsum[t >> 6] = inc;
  __syncthreads();
  int pre = 0;
  #pragma unroll
  for (int wj = 0; wj < 4; wj++) pre += (wj < (t >> 6)) ? wsum[wj] : 0;
  const int base = pre + inc - myc;
  const int cnt = wsum[0] + wsum[1] + wsum[2] + wsum[3];
  {
    int idx = base;
    #pragma unroll
    for (int k = 0; k < 16; k++) {
      float wv = fv[k];
      if (wv != 0.0f && idx < CAP) { lm[idx] = k*256 + t; lw[idx] = wv; idx++; }
    }
  }
  #pragma unroll
  for (int s = 1; s < 64; s <<= 1) wmax = fmaxf(wmax, __shfl_xor(wmax, s, 64));
  if ((t & 63) == 0) redf[t >> 6] = wmax;
  __syncthreads();
  const float gmax = fmaxf(fmaxf(redf[0], redf[1]), fmaxf(redf[2], redf[3]));
  __syncthreads();
  if (t < cnt && t < CAP) ses[t] = expf(lw[t] - gmax);
  __syncthreads();
  float ps = (t < cnt && t < CAP) ? ses[t] : 0.f;
  #pragma unroll
  for (int s = 1; s < 64; s <<= 1) ps += __shfl_xor(ps, s, 64);
  if ((t & 63) == 0) redf[4 + (t >> 6)] = ps;
  __syncthreads();
  const float S = redf[4] + redf[5] + redf[6] + redf[7];
  const float invS = 1.0f / S;
  float a0=0,a1=0,a2=0,a3=0,a4=0,a5=0;
  const int ecnt = (cnt < CAP) ? cnt : CAP;
  for (int e = 0; e < ecnt; e++) {
    float se = ses[e] * invS;
    const float* vr = vsb + (long)lm[e] * 1536;
    a0 = fmaf(se, vr[        t], a0);
    a1 = fmaf(se, vr[ 256 + t], a1);
    a2 = fmaf(se, vr[ 512 + t], a2);
    a3 = fmaf(se, vr[ 768 + t], a3);
    a4 = fmaf(se, vr[1024 + t], a4);
    a5 = fmaf(se, vr[1280 + t], a5);
  }
  float* orow = outr + (long)bb*6291456 + (long)n * 1536;
  orow[        t] = a0;
  orow[ 256 + t] = a1;
  orow[ 512 + t] = a2;
  orow[ 768 + t] = a3;
  orow[1024 + t] = a4;
  orow[1280 + t] = a5;
}

// ------- per-channel l2 norm over 65536 (fhr k2); in-place safe -------
__global__ __launch_bounds__(1024) void l2n_sp(
    const float* __restrict__ in, float* __restrict__ out)
{
  const int ch = blockIdx.x, b = blockIdx.y, t = threadIdx.x;
  const float* ip = in + ((long)b*96 + ch) * HW;
  float ss = 0.f;
  for (int i = t; i < 65536; i += 1024) { float v = ip[i]; ss = fmaf(v, v, ss); }
  __shared__ float red[16];
  #pragma unroll
  for (int s = 1; s < 64; s <<= 1) ss += __shfl_xor(ss, s, 64);
  if ((t & 63) == 0) red[t >> 6] = ss;
  __syncthreads();
  if (t == 0) {
    float s2 = 0.f;
    for (int i = 0; i < 16; i++) s2 += red[i];
    red[0] = fmaxf(sqrtf(s2), 1e-12f);
  }
  __syncthreads();
  const float nrm = red[0];
  float* op = out + ((long)b*96 + ch) * HW;
  for (int i = t; i < 65536; i += 1024) op[i] = ip[i] / nrm;
}

// -------- a2 stage 1: raw-q Gram + q sum-of-squares partials ----------
#define A2_NCH 16
__global__ __launch_bounds__(256) void a2_part(
    const float* __restrict__ q2n, const float* __restrict__ k2n,
    float* __restrict__ part, float* __restrict__ qqpart)
{
  __shared__ float sh[24*260];
  const int t = threadIdx.x;
  const int ch = blockIdx.x, h = blockIdx.y, b = blockIdx.z;
  const long base = ((long)b*96 + h*12) * HW + ch*4096;
  const int c = t / 12, d = t - (t/12)*12;
  float acc = 0.f;
  float qq = 0.f;
  for (int sub = 0; sub < 16; sub++) {
    __syncthreads();
    #pragma unroll
    for (int j = 0; j < 6; j++) {
      const int v = j*256 + t;
      const int row = v >> 6;
      const int col4 = v & 63;
      const float* src = (row < 12)
        ? q2n + base + (long)row*HW + sub*256 + col4*4
        : k2n + base + (long)(row-12)*HW + sub*256 + col4*4;
      *(float4*)&sh[row*260 + col4*4] = *(const float4*)src;
    }
    __syncthreads();
    if (t < 144) {
      const float* qr = &sh[c*260];
      const float* kr = &sh[(12+d)*260];
      #pragma unroll
      for (int i4 = 0; i4 < 64; i4++) {
        float4 qv = *(const float4*)&qr[i4*4];
        float4 kv = *(const float4*)&kr[i4*4];
        acc = fmaf(qv.x, kv.x, acc);
        acc = fmaf(qv.y, kv.y, acc);
        acc = fmaf(qv.z, kv.z, acc);
        acc = fmaf(qv.w, kv.w, acc);
      }
    } else if (t < 156) {
      const float* qr = &sh[(t-144)*260];
      #pragma unroll
      for (int i4 = 0; i4 < 64; i4++) {
        float4 qv = *(const float4*)&qr[i4*4];
        qq = fmaf(qv.x, qv.x, qq);
        qq = fmaf(qv.y, qv.y, qq);
        qq = fmaf(qv.z, qv.z, qq);
        qq = fmaf(qv.w, qv.w, qq);
      }
    }
  }
  if (t < 144)
    part[(((long)b*8 + h)*A2_NCH + ch)*144 + t] = acc;
  else if (t < 156)
    qqpart[(((long)b*8 + h)*A2_NCH + ch)*12 + (t-144)] = qq;
}

// -------- a2 stage 2: fold q-normalization --------
__global__ __launch_bounds__(256) void a2_fin(
    const float* __restrict__ part, const float* __restrict__ qqpart,
    const float* __restrict__ temp, float* __restrict__ a2s)
{
  __shared__ float m[144];
  __shared__ float qn[12];
  const int t = threadIdx.x;
  const int h = blockIdx.x, b = blockIdx.y;
  if (t < 144) {
    float s = 0.f;
    const float* pp = part + (((long)b*8 + h)*A2_NCH)*144 + t;
    #pragma unroll
    for (int ch = 0; ch < A2_NCH; ch++) s += pp[ch*144];
    m[t] = s;
  } else if (t < 156) {
    float s = 0.f;
    const float* pp = qqpart + (((long)b*8 + h)*A2_NCH)*12 + (t-144);
    #pragma unroll
    for (int ch = 0; ch < A2_NCH; ch++) s += pp[ch*12];
    qn[t-144] = fmaxf(sqrtf(s), 1e-12f);
  }
  __syncthreads();
  if (t < 12) {
    const float tv = temp[h];
    const float scale = tv / qn[t];
    float mx = -INFINITY;
    float a[12];
    #pragma unroll
    for (int d = 0; d < 12; d++) { a[d] = m[t*12+d] * scale; mx = fmaxf(mx, a[d]); }
    float e[12], sum = 0.f;
    #pragma unroll
    for (int d = 0; d < 12; d++) { e[d] = expf(a[d]-mx); sum += e[d]; }
    float inv = 1.0f/sum;
    float* op = a2s + (((long)b*8 + h)*12 + t)*12;
    #pragma unroll
    for (int d = 0; d < 12; d++) op[d] = e[d]*inv;
  }
}

extern "C" void kernel_launch(void* const* d_in, const int* in_sizes, int n_in,
                              void* d_out, int out_size, void* d_ws, size_t ws_size,
                              hipStream_t stream) {
  const float* x        = (const float*)d_in[0];
  const float* qk_w     = (const float*)d_in[1];
  const float* qk_dw    = (const float*)d_in[2];
  const float* v_w      = (const float*)d_in[3];
  const float* v_dw     = (const float*)d_in[4];
  const float* k2_w     = (const float*)d_in[5];
  const float* k2_dw    = (const float*)d_in[6];
  const float* q2_w     = (const float*)d_in[7];
  const float* q2_dw    = (const float*)d_in[8];
  const float* proj_w   = (const float*)d_in[9];
  const float* sab_temp = (const float*)d_in[10];
  const float* fqkv_w   = (const float*)d_in[11];
  const float* fqkv_dw  = (const float*)d_in[12];
  const float* fproj_w  = (const float*)d_in[13];
  const float* fhr_temp = (const float*)d_in[14];
  float* out = (float*)d_out;
  float* ws  = (float*)d_ws;

  float* O2  = out;
  float* KS  = out + 12582912;
  float* VS  = out + 14155776;
  float* K2N = out + 26738688;
  float* V2  = out + 39321600;

  // pre-attention scratch
  float* A0   = ws;                     // conv out      [0      : 25.17M)
  float* A1   = ws + 25165824;          // dw/qk out     [25.17M : 50.33M)
  float* QD   = ws + 50331648;
  float* KD   = ws + 51904512;
  float* QN   = ws + 53477376;
  float* A2S  = ws + 55050240;
  float* PART = ws + 55052544;
  unsigned short* WHL = (unsigned short*)QN;
  // attention phase (R16 layout)
  float* ATT  = ws;                     // attn[2]       [0      : 33.55M)
  unsigned short* QSP = (unsigned short*)(ws + 33554432);  // [33.55M : 35.13M)
  unsigned short* KSP = (unsigned short*)(ws + 35127296);  // [35.13M : 36.70M)
  float* AOUT = ws + 37748736;          // attn-out[2]   [37.75M : 50.33M)
  // fhr phase
  float* P1  = ws;                      // pre-q2        [0      : 12.58M)
  float* P2  = ws + 12582912;           // pre-k2        [12.58M : 25.17M)
  float* P3  = ws + 25165824;           // pre-v2        [25.17M : 37.75M)
  float* ALNQ = P2;
  float* QQP = QD;
  unsigned short* W2HL = (unsigned short*)PART;

  dim3 b256(256), b1024(1024);

  wsplit<<<dim3(252), b256, 0, stream>>>(qk_w, v_w, q2_w, k2_w, WHL);
  // fused qk-conv (192ch -> A0) + v-conv (96ch -> A1)
  conv1x1_mfma<<<dim3(512,2), b256, 0, stream>>>(
      x, 96L*HW, WHL, WHL+110592, 0, 0,
      A0, 192L*HW, A1, 96L*HW, A1, 96L*HW, 12, 18, 18, 0);
  dw3x3_vs<<<dim3(1024,2), b256, 0, stream>>>(A1, v_dw, VS);
  dw3x3v<<<dim3(64,192,2), b256, 0, stream>>>(A0, 192, qk_dw, A1, 192);
  conv1x1_mfma<<<dim3(512,2), b256, 0, stream>>>(
      A1, 192L*HW, WHL, WHL+110592, 0, 288,
      A0, 192L*HW, A0, 192L*HW, A0, 192L*HW, 12, 12, 12, 0);
  dw4x4s4v<<<dim3(4,192,2), b256, 0, stream>>>(A0, q2_dw, QD);
  conv1x1_mfma<<<dim3(512,2), b256, 0, stream>>>(
      A1 + 96L*HW, 192L*HW, WHL, WHL+110592, 0, 480,
      A0, 192L*HW, A0, 192L*HW, A0, 192L*HW, 12, 12, 12, 0);
  dw4x4s4v<<<dim3(4,192,2), b256, 0, stream>>>(A0, k2_dw, KD);
  l2n192<<<dim3(4096), b256, 0, stream>>>(QD, QN, KD, KS);
  // split both batches of Q and K
  bf16split<<<dim3(6144), b256, 0, stream>>>(QN, QSP);
  bf16split<<<dim3(6144), b256, 0, stream>>>(KS, KSP);
  // attention: both batches in single dispatches
  attn_qk_mfma<<<dim3(32,32,2), b256, 0, stream>>>(QSP, KSP, ATT, sab_temp);
  attn_out_k<<<dim3(4096,2), b256, 0, stream>>>(ATT, VS, AOUT);
  // compose CF = fqkv @ proj -> WHL rows 768..1055
  wcomp1<<<dim3(108), b256, 0, stream>>>(fqkv_w, proj_w, WHL);
  // fused (proj+fhr-qkv) conv, mode 1 on AOUT: q2->P1, k2->P2, v2->P3
  conv1x1_mfma<<<dim3(512,2), b256, 0, stream>>>(
      AOUT, 6291456L, WHL, WHL+110592, 0, 768,
      P1, 96L*HW, P2, 96L*HW, P3, 96L*HW, 6, 12, 18, 1);
  dw3x3v<<<dim3(64,96,2), b256, 0, stream>>>(P2, 96, fqkv_dw +  864, K2N, 96);
  dw3x3v<<<dim3(64,96,2), b256, 0, stream>>>(P3, 96, fqkv_dw + 1728, V2,  96);
  dw3x3v<<<dim3(64,96,2), b256, 0, stream>>>(P1, 96, fqkv_dw,        ALNQ, 96);
  l2n_sp<<<dim3(96,2), b1024, 0, stream>>>(K2N, K2N);
  a2_part<<<dim3(A2_NCH,8,2), b256, 0, stream>>>(ALNQ, K2N, PART, QQP);
  a2_fin<<<dim3(8,2), b256, 0, stream>>>(PART, QQP, fhr_temp, A2S);
  wcomp2<<<dim3(36,2), b256, 0, stream>>>(fproj_w, A2S, W2HL);
  conv1x1_mfma<<<dim3(512,2), b256, 0, stream>>>(
      V2, 96L*HW, W2HL, W2HL+18432, 9216, 0,
      O2, 96L*HW, O2, 96L*HW, O2, 96L*HW, 6, 6, 6, 0);
}

// Round 17
// 798.242 us; speedup vs baseline: 2.4088x; 1.0094x over previous
//
#include <hip/hip_runtime.h>
#include <hip/hip_bf16.h>
#include <math.h>

#define HW 65536L

typedef __attribute__((ext_vector_type(8))) short bf16x8;
typedef __attribute__((ext_vector_type(4))) float f32x4;

__device__ __forceinline__ int iabs_(int v) { return v < 0 ? -v : v; }

__device__ __forceinline__ void rtn_split(float f, unsigned short* h, unsigned short* l) {
  __hip_bfloat16 hb = __float2bfloat16(f);
  float hf = __bfloat162float(hb);
  __hip_bfloat16 lb = __float2bfloat16(f - hf);
  *h = *(unsigned short*)&hb;
  *l = *(unsigned short*)&lb;
}

// ---- split static 1x1 weights into (hi,lo) bf16 planes: whl[2][1152][96] ----
__global__ __launch_bounds__(256) void wsplit(
    const float* __restrict__ qk, const float* __restrict__ v,
    const float* __restrict__ q2, const float* __restrict__ k2,
    unsigned short* __restrict__ whl)
{
  const int e = blockIdx.x*256 + threadIdx.x;
  if (e >= 64512) return;
  const int row = e / 96, col = e - row*96;
  float f;
  if      (row <  192) f = qk[e];
  else if (row <  288) f = v [(row-192)*96+col];
  else if (row <  480) f = q2[(row-288)*96+col];
  else                 f = k2[(row-480)*96+col];
  rtn_split(f, &whl[e], &whl[110592 + e]);
}

// ---- compose CF = fqkv(288x96) @ proj(96x96) -> WHL rows 768..1055 ----
__global__ __launch_bounds__(256) void wcomp1(
    const float* __restrict__ fq, const float* __restrict__ pj,
    unsigned short* __restrict__ whl)
{
  const int e = blockIdx.x*256 + threadIdx.x;
  if (e >= 27648) return;
  const int row = e / 96, col = e - row*96;
  float s = 0.f;
  #pragma unroll 8
  for (int c = 0; c < 96; c++) s = fmaf(fq[row*96 + c], pj[c*96 + col], s);
  rtn_split(s, &whl[(768+row)*96 + col], &whl[110592 + (768+row)*96 + col]);
}

// ---- compose W2[b] = fproj(96x96) @ blockdiag(a2[b]) ----
__global__ __launch_bounds__(256) void wcomp2(
    const float* __restrict__ fp, const float* __restrict__ a2s,
    unsigned short* __restrict__ w2)
{
  const int e = blockIdx.x*256 + threadIdx.x;
  const int b = blockIdx.y;
  if (e >= 9216) return;
  const int co = e / 96, dg = e - co*96;
  const int h = dg / 12, d = dg - h*12;
  const float* ab = a2s + (((long)b*8 + h)*12)*12 + d;
  const float* fpb = fp + co*96 + h*12;
  float s = 0.f;
  #pragma unroll
  for (int c = 0; c < 12; c++) s = fmaf(fpb[c], ab[c*12], s);
  rtn_split(s, &w2[(long)b*9216 + e], &w2[18432 + (long)b*9216 + e]);
}

// ------- conv 1x1 via split-bf16 MFMA (3-way output split) -------
#define BLDS 104
__global__ __launch_bounds__(256) void conv1x1_mfma(
    const float* __restrict__ in, long in_bstride,
    const unsigned short* __restrict__ whl_hi, const unsigned short* __restrict__ whl_lo,
    long wbstride, int wrow0,
    float* __restrict__ out, long out_bstride,
    float* __restrict__ out2, long out2_bstride,
    float* __restrict__ out3, long out3_bstride,
    int ms1, int ms2, int mtiles, int mode)
{
  __shared__ unsigned short bhs[128*BLDS];
  __shared__ unsigned short bls[128*BLDS];
  const int t = threadIdx.x;
  const int p0 = blockIdx.x * 128;
  const int b = blockIdx.y;
  if (mode == 0) {
    #pragma unroll
    for (int it = 0; it < 6; it++) {
      const int idx = it*256 + t;
      const int g8 = idx >> 7;
      const int pix = idx & 127;
      const float* src = in + (long)b*in_bstride + (long)(g8*8)*HW + p0 + pix;
      unsigned hh[8], ll[8];
      #pragma unroll
      for (int j = 0; j < 8; j++) {
        float f = src[(long)j*HW];
        unsigned u = __float_as_uint(f);
        hh[j] = u >> 16;
        float lof = f - __uint_as_float(u & 0xFFFF0000u);
        __hip_bfloat16 lb = __float2bfloat16(lof);
        ll[j] = *(unsigned short*)&lb;
      }
      uint4 hv, lv;
      hv.x = hh[0]|(hh[1]<<16); hv.y = hh[2]|(hh[3]<<16);
      hv.z = hh[4]|(hh[5]<<16); hv.w = hh[6]|(hh[7]<<16);
      lv.x = ll[0]|(ll[1]<<16); lv.y = ll[2]|(ll[3]<<16);
      lv.z = ll[4]|(ll[5]<<16); lv.w = ll[6]|(ll[7]<<16);
      *(uint4*)(bhs + pix*BLDS + g8*8) = hv;
      *(uint4*)(bls + pix*BLDS + g8*8) = lv;
    }
  } else {
    const int pp = t >> 1, half = (t & 1)*48;
    const int p = p0 + pp;
    const int py = p >> 8, px = p & 255;
    const float* src = in + (long)b*in_bstride
        + ((long)((py & 63)*64 + (px & 63))*16 + ((py >> 6)*4 + (px >> 6)))*96 + half;
    #pragma unroll
    for (int j4 = 0; j4 < 12; j4++) {
      float4 v4 = *(const float4*)&src[j4*4];
      float fv[4] = {v4.x, v4.y, v4.z, v4.w};
      unsigned hh[4], ll[4];
      #pragma unroll
      for (int u4 = 0; u4 < 4; u4++) {
        unsigned u = __float_as_uint(fv[u4]);
        hh[u4] = u >> 16;
        float lof = fv[u4] - __uint_as_float(u & 0xFFFF0000u);
        __hip_bfloat16 lb = __float2bfloat16(lof);
        ll[u4] = *(unsigned short*)&lb;
      }
      uint2 hv, lv;
      hv.x = hh[0] | (hh[1] << 16); hv.y = hh[2] | (hh[3] << 16);
      lv.x = ll[0] | (ll[1] << 16); lv.y = ll[2] | (ll[3] << 16);
      *(uint2*)(bhs + pp*BLDS + half + j4*4) = hv;
      *(uint2*)(bls + pp*BLDS + half + j4*4) = lv;
    }
  }
  __syncthreads();
  const int lane = t & 63, w = t >> 6;
  const int fr = lane & 15, fk = lane >> 4;
  bf16x8 Bh[2][3], Bl[2][3];
  #pragma unroll
  for (int nt = 0; nt < 2; nt++)
    #pragma unroll
    for (int kt = 0; kt < 3; kt++) {
      const int pix = w*32 + nt*16 + fr;
      Bh[nt][kt] = *(const bf16x8*)(bhs + pix*BLDS + kt*32 + fk*8);
      Bl[nt][kt] = *(const bf16x8*)(bls + pix*BLDS + kt*32 + fk*8);
    }
  const long wb = (long)b*wbstride;
  for (int m = 0; m < mtiles; m++) {
    const long wbase = wb + (long)(wrow0 + m*16 + fr)*96 + fk*8;
    bf16x8 Ah[3], Al[3];
    #pragma unroll
    for (int kt = 0; kt < 3; kt++) {
      Ah[kt] = *(const bf16x8*)(whl_hi + wbase + kt*32);
      Al[kt] = *(const bf16x8*)(whl_lo + wbase + kt*32);
    }
    f32x4 acc[2] = {};
    #pragma unroll
    for (int nt = 0; nt < 2; nt++)
      #pragma unroll
      for (int kt = 0; kt < 3; kt++) {
        acc[nt] = __builtin_amdgcn_mfma_f32_16x16x32_bf16(Ah[kt], Bh[nt][kt], acc[nt], 0, 0, 0);
        acc[nt] = __builtin_amdgcn_mfma_f32_16x16x32_bf16(Ah[kt], Bl[nt][kt], acc[nt], 0, 0, 0);
        acc[nt] = __builtin_amdgcn_mfma_f32_16x16x32_bf16(Al[kt], Bh[nt][kt], acc[nt], 0, 0, 0);
      }
    int mo; float* dst;
    if (m < ms1)      { mo = m;       dst = out  + (long)b*out_bstride; }
    else if (m < ms2) { mo = m - ms1; dst = out2 + (long)b*out2_bstride; }
    else              { mo = m - ms2; dst = out3 + (long)b*out3_bstride; }
    dst += p0 + w*32;
    #pragma unroll
    for (int nt = 0; nt < 2; nt++)
      #pragma unroll
      for (int r = 0; r < 4; r++)
        dst[(long)(mo*16 + fk*4 + r)*HW + nt*16 + fr] = acc[nt][r];
  }
}

// -------- depthwise 3x3 pad 1, 4-wide vectorized --------
__global__ __launch_bounds__(256) void dw3x3v(
    const float* __restrict__ in, int inCH, const float* __restrict__ w,
    float* __restrict__ out, int outCH)
{
  const int t = threadIdx.x;
  const int p4 = blockIdx.x * 256 + t;
  const int ch = blockIdx.y, b = blockIdx.z;
  const int y = p4 >> 6, x0 = (p4 & 63) << 2;
  const float* ip = in + ((long)b*inCH + ch) * HW;
  const float* wp = w + ch*9;
  float a0 = 0.f, a1 = 0.f, a2 = 0.f, a3 = 0.f;
  #pragma unroll
  for (int dy = -1; dy <= 1; dy++) {
    const int yy = y + dy;
    if (yy < 0 || yy > 255) continue;
    const float* rp = ip + yy*256;
    const float4 c = *(const float4*)&rp[x0];
    const float left  = (x0 > 0)   ? rp[x0-1] : 0.f;
    const float right = (x0 < 252) ? rp[x0+4] : 0.f;
    const float w0 = wp[(dy+1)*3+0], w1 = wp[(dy+1)*3+1], w2 = wp[(dy+1)*3+2];
    a0 = fmaf(left, w0, a0); a0 = fmaf(c.x, w1, a0); a0 = fmaf(c.y, w2, a0);
    a1 = fmaf(c.x,  w0, a1); a1 = fmaf(c.y, w1, a1); a1 = fmaf(c.z, w2, a1);
    a2 = fmaf(c.y,  w0, a2); a2 = fmaf(c.z, w1, a2); a2 = fmaf(c.w, w2, a2);
    a3 = fmaf(c.z,  w0, a3); a3 = fmaf(c.w, w1, a3); a3 = fmaf(right, w2, a3);
  }
  float4 o; o.x = a0; o.y = a1; o.z = a2; o.w = a3;
  *(float4*)&out[((long)b*outCH + ch)*HW + y*256 + x0] = o;
}

// ------- depthwise 3x3 fused with v_s permutation (4-wide compute) ----
__global__ __launch_bounds__(256) void dw3x3_vs(
    const float* __restrict__ in, const float* __restrict__ w,
    float* __restrict__ vs)
{
  __shared__ float tile[96*65];
  const int t = threadIdx.x;
  const int gb = blockIdx.x;
  const int b = blockIdx.y;
  const int y = gb >> 2, xb = gb & 3;
  #pragma unroll
  for (int i = 0; i < 6; i++) {
    const int idx = i*256 + t;
    const int ci = idx >> 4, q = idx & 15;
    const int x0 = xb*64 + q*4;
    const float* ip = in + ((long)b*96 + ci) * HW;
    const float* wp = w + ci*9;
    float a0 = 0.f, a1 = 0.f, a2 = 0.f, a3 = 0.f;
    #pragma unroll
    for (int dy = -1; dy <= 1; dy++) {
      const int yy = y + dy;
      if (yy < 0 || yy > 255) continue;
      const float* rp = ip + yy*256;
      const float4 c = *(const float4*)&rp[x0];
      const float left  = (x0 > 0)   ? rp[x0-1] : 0.f;
      const float right = (x0 < 252) ? rp[x0+4] : 0.f;
      const float w0 = wp[(dy+1)*3+0], w1 = wp[(dy+1)*3+1], w2 = wp[(dy+1)*3+2];
      a0 = fmaf(left, w0, a0); a0 = fmaf(c.x, w1, a0); a0 = fmaf(c.y, w2, a0);
      a1 = fmaf(c.x,  w0, a1); a1 = fmaf(c.y, w1, a1); a1 = fmaf(c.z, w2, a1);
      a2 = fmaf(c.y,  w0, a2); a2 = fmaf(c.z, w1, a2); a2 = fmaf(c.w, w2, a2);
      a3 = fmaf(c.z,  w0, a3); a3 = fmaf(c.w, w1, a3); a3 = fmaf(right, w2, a3);
    }
    const int xl = q*4;
    tile[ci*65 + xl    ] = a0;
    tile[ci*65 + xl + 1] = a1;
    tile[ci*65 + xl + 2] = a2;
    tile[ci*65 + xl + 3] = a3;
  }
  __syncthreads();
  const int blk = (y >> 6)*4 + xb;
  float* obase = vs + ((long)b*4096 + (long)(y & 63)*64) * 1536 + blk*96;
  #pragma unroll
  for (int i = 0; i < 24; i++) {
    const int idx = i*256 + t;
    const int nl = idx / 96, ci = idx % 96;
    obase[(long)nl*1536 + ci] = tile[ci*65 + nl];
  }
}

// ---- depthwise 4x4 stride 4 pad 1 (256->64), 4-wide vectorized ----
__global__ __launch_bounds__(256) void dw4x4s4v(
    const float* __restrict__ in, const float* __restrict__ w,
    float* __restrict__ out)
{
  const int t = threadIdx.x;
  const int p = blockIdx.x*256 + t;
  const int ch = blockIdx.y, b = blockIdx.z;
  const int oy = p >> 4, qx = p & 15;
  const int x0 = qx*16;
  const float* ip = in + (long)(b*192 + ch) * HW;
  const float* wp = w + ch*16;
  float a0 = 0.f, a1 = 0.f, a2 = 0.f, a3 = 0.f;
  #pragma unroll
  for (int ty = 0; ty < 4; ty++) {
    const int iy = 4*oy + ty - 1;
    if (iy < 0 || iy > 255) continue;
    const float* rp = ip + iy*256;
    float r[17];
    r[0] = (x0 > 0) ? rp[x0-1] : 0.f;
    #pragma unroll
    for (int k = 0; k < 4; k++) {
      float4 v4 = *(const float4*)&rp[x0 + k*4];
      r[1+k*4+0]=v4.x; r[1+k*4+1]=v4.y; r[1+k*4+2]=v4.z; r[1+k*4+3]=v4.w;
    }
    const float w0=wp[ty*4+0], w1=wp[ty*4+1], w2=wp[ty*4+2], w3=wp[ty*4+3];
    a0=fmaf(r[ 0],w0,a0); a0=fmaf(r[ 1],w1,a0); a0=fmaf(r[ 2],w2,a0); a0=fmaf(r[ 3],w3,a0);
    a1=fmaf(r[ 4],w0,a1); a1=fmaf(r[ 5],w1,a1); a1=fmaf(r[ 6],w2,a1); a1=fmaf(r[ 7],w3,a1);
    a2=fmaf(r[ 8],w0,a2); a2=fmaf(r[ 9],w1,a2); a2=fmaf(r[10],w2,a2); a2=fmaf(r[11],w3,a2);
    a3=fmaf(r[12],w0,a3); a3=fmaf(r[13],w1,a3); a3=fmaf(r[14],w2,a3); a3=fmaf(r[15],w3,a3);
  }
  float4 o; o.x=a0; o.y=a1; o.z=a2; o.w=a3;
  *(float4*)&out[(long)(b*192 + ch)*4096 + oy*64 + qx*4] = o;
}

// ---------------- l2 norm over 192 channels + transpose (both q & k) ----
__global__ __launch_bounds__(256) void l2n192(
    const float* __restrict__ inA, float* __restrict__ outA,
    const float* __restrict__ inB, float* __restrict__ outB)
{
  const int t = threadIdx.x;
  const int wid = t >> 6, lane = t & 63;
  const int gw2 = blockIdx.x * 4 + wid;
  const int sel = gw2 >> 13;
  const int gw = gw2 & 8191;
  const int b = gw >> 12, n = gw & 4095;
  const float* ip = (sel ? inB : inA) + (long)b * 786432;
  float v0 = ip[(long)(lane      ) * 4096 + n];
  float v1 = ip[(long)(lane +  64) * 4096 + n];
  float v2 = ip[(long)(lane + 128) * 4096 + n];
  float ss = v0*v0 + v1*v1 + v2*v2;
  #pragma unroll
  for (int s = 1; s < 64; s <<= 1) ss += __shfl_xor(ss, s, 64);
  float nrm = fmaxf(sqrtf(ss), 1e-12f);
  float* op = (sel ? outB : outA) + ((long)b*4096 + n) * 192;
  op[lane      ] = v0 / nrm;
  op[lane +  64] = v1 / nrm;
  op[lane + 128] = v2 / nrm;
}

// ------- split fp32 -> (hi,lo) bf16 planes; both batches -------
__global__ __launch_bounds__(256) void bf16split(
    const float* __restrict__ in, unsigned short* __restrict__ outp)
{
  const int i = blockIdx.x * 256 + threadIdx.x;
  const int n = i / 192, k = i % 192;
  float f = in[i];
  unsigned short h, l;
  rtn_split(f, &h, &l);
  outp[(long)n*384 + k]       = h;
  outp[(long)n*384 + 192 + k] = l;
}

// ------- attention QK^T via split-bf16 MFMA (both batches) -------
#define LDSROW 40
__global__ __launch_bounds__(256) void attn_qk_mfma(
    const unsigned short* __restrict__ Qsp, const unsigned short* __restrict__ Ksp,
    float* __restrict__ attn, const float* __restrict__ tp)
{
  __shared__ unsigned short qs[256*LDSROW];
  __shared__ unsigned short ks[256*LDSROW];
  const int t = threadIdx.x;
  const int lane = t & 63, w = t >> 6;
  const int n0 = blockIdx.x * 128;
  const int m0 = blockIdx.y * 128;
  const int bb = blockIdx.z;
  const unsigned short* Qb = Qsp + (long)bb*1572864;
  const unsigned short* Kb = Ksp + (long)bb*1572864;
  float* attb = attn + (long)bb*16777216;
  const int wr = (w >> 1) * 64, wc = (w & 1) * 64;
  f32x4 acc[4][4] = {};
  const int srow = t & 127;
  const int shl  = t >> 7;
  const unsigned short* qsrc = Qb + (long)(n0 + srow) * 384 + shl * 192;
  const unsigned short* ksrc = Kb + (long)(m0 + srow) * 384 + shl * 192;
  unsigned short* qdst = qs + (shl*128 + srow) * LDSROW;
  unsigned short* kdst = ks + (shl*128 + srow) * LDSROW;
  const int fr = lane & 15;
  const int fk = lane >> 4;
  for (int s = 0; s < 6; s++) {
    __syncthreads();
    #pragma unroll
    for (int j = 0; j < 4; j++) {
      *(bf16x8*)(qdst + j*8) = *(const bf16x8*)(qsrc + s*32 + j*8);
      *(bf16x8*)(kdst + j*8) = *(const bf16x8*)(ksrc + s*32 + j*8);
    }
    __syncthreads();
    bf16x8 ah[4], al[4], bh[4], bl[4];
    #pragma unroll
    for (int i = 0; i < 4; i++) {
      ah[i] = *(const bf16x8*)(qs + (      wr + i*16 + fr) * LDSROW + fk*8);
      al[i] = *(const bf16x8*)(qs + (128 + wr + i*16 + fr) * LDSROW + fk*8);
      bh[i] = *(const bf16x8*)(ks + (      wc + i*16 + fr) * LDSROW + fk*8);
      bl[i] = *(const bf16x8*)(ks + (128 + wc + i*16 + fr) * LDSROW + fk*8);
    }
    #pragma unroll
    for (int i = 0; i < 4; i++)
      #pragma unroll
      for (int j = 0; j < 4; j++) {
        acc[i][j] = __builtin_amdgcn_mfma_f32_16x16x32_bf16(ah[i], bh[j], acc[i][j], 0, 0, 0);
        acc[i][j] = __builtin_amdgcn_mfma_f32_16x16x32_bf16(ah[i], bl[j], acc[i][j], 0, 0, 0);
        acc[i][j] = __builtin_amdgcn_mfma_f32_16x16x32_bf16(al[i], bh[j], acc[i][j], 0, 0, 0);
      }
  }
  const float temp = tp[0];
  #pragma unroll
  for (int i = 0; i < 4; i++)
    #pragma unroll
    for (int j = 0; j < 4; j++)
      #pragma unroll
      for (int r = 0; r < 4; r++) {
        const int nn = n0 + wr + i*16 + (lane >> 4)*4 + r;
        const int mm = m0 + wc + j*16 + (lane & 15);
        attb[(long)nn*4096 + mm] = acc[i][j][r] * temp;
      }
}

// ------- top-5 + local mask + softmax + sparse out -------
// R17: float4 row read (thread owns m = t*16+k), float4 PV and output.
#define CAP 128
__global__ __launch_bounds__(256) void attn_out_k(
    const float* __restrict__ attn, const float* __restrict__ vs,
    float* __restrict__ outr)
{
  __shared__ float top5[256*5];
  __shared__ int   lm[CAP];
  __shared__ float lw[CAP];
  __shared__ float ses[CAP];
  __shared__ float redf[8];
  __shared__ int   wsum[4];
  const int t = threadIdx.x;
  const int bid = blockIdx.x;
  const int n = ((bid & 7) << 9) | (bid >> 3);   // XCD-chunked rows
  const int bb = blockIdx.y;
  const float* ar = attn + (long)bb*16777216 + (long)n * 4096;
  const float* vsb = vs + (long)bb*6291456;
  float av[16];
  float t0=-INFINITY,t1=-INFINITY,t2=-INFINITY,t3=-INFINITY,t4=-INFINITY;
  #pragma unroll
  for (int q = 0; q < 4; q++) {
    float4 v4 = *(const float4*)&ar[t*16 + q*4];
    float vv[4] = {v4.x, v4.y, v4.z, v4.w};
    #pragma unroll
    for (int u = 0; u < 4; u++) {
      float v = vv[u];
      av[q*4+u] = v;
      if (v > t4) {
        if (v > t0)      { t4=t3; t3=t2; t2=t1; t1=t0; t0=v; }
        else if (v > t1) { t4=t3; t3=t2; t2=t1; t1=v; }
        else if (v > t2) { t4=t3; t3=t2; t2=v; }
        else if (v > t3) { t4=t3; t3=v; }
        else             { t4=v; }
      }
    }
  }
  top5[t*5+0]=t0; top5[t*5+1]=t1; top5[t*5+2]=t2; top5[t*5+3]=t3; top5[t*5+4]=t4;
  __syncthreads();
  for (int s = 128; s >= 1; s >>= 1) {
    if (t < s) {
      float* A = &top5[t*5];
      const float* B = &top5[(t+s)*5];
      float m[5]; int i = 0, j = 0;
      #pragma unroll
      for (int k = 0; k < 5; k++) {
        float avv = A[i], bv = B[j];
        if (avv >= bv) { m[k] = avv; i++; } else { m[k] = bv; j++; }
      }
      #pragma unroll
      for (int k = 0; k < 5; k++) A[k] = m[k];
    }
    __syncthreads();
  }
  const float kth = top5[4];
  const int y = n >> 6, x = n & 63;
  int myc = 0;
  float wmax = -INFINITY;
  float fvv[16];
  #pragma unroll
  for (int k = 0; k < 16; k++) {
    const int m = t*16 + k;
    float a = av[k];
    int c = ((a >= kth) ? 1 : 0) +
            (((iabs_(y - (m >> 6)) + iabs_(x - (m & 63))) <= 4) ? 1 : 0);
    float wv = a * (float)c;
    fvv[k] = wv;
    if (wv != 0.0f) { myc++; wmax = fmaxf(wmax, wv); }
  }
  int inc = myc;
  #pragma unroll
  for (int s = 1; s < 64; s <<= 1) {
    int v = __shfl_up(inc, s, 64);
    if ((t & 63) >= s) inc += v;
  }
  if ((t & 63) == 63) wsum[t >> 6] = inc;
  __syncthreads();
  int pre = 0;
  #pragma unroll
  for (int wj = 0; wj < 4; wj++) pre += (wj < (t >> 6)) ? wsum[wj] : 0;
  const int base = pre + inc - myc;
  const int cnt = wsum[0] + wsum[1] + wsum[2] + wsum[3];
  {
    int idx = base;
    #pragma unroll
    for (int k = 0; k < 16; k++) {
      float wv = fvv[k];
      if (wv != 0.0f && idx < CAP) { lm[idx] = t*16 + k; lw[idx] = wv; idx++; }
    }
  }
  #pragma unroll
  for (int s = 1; s < 64; s <<= 1) wmax = fmaxf(wmax, __shfl_xor(wmax, s, 64));
  if ((t & 63) == 0) redf[t >> 6] = wmax;
  __syncthreads();
  const float gmax = fmaxf(fmaxf(redf[0], redf[1]), fmaxf(redf[2], redf[3]));
  __syncthreads();
  if (t < cnt && t < CAP) ses[t] = expf(lw[t] - gmax);
  __syncthreads();
  float ps = (t < cnt && t < CAP) ? ses[t] : 0.f;
  #pragma unroll
  for (int s = 1; s < 64; s <<= 1) ps += __shfl_xor(ps, s, 64);
  if ((t & 63) == 0) redf[4 + (t >> 6)] = ps;
  __syncthreads();
  const float S = redf[4] + redf[5] + redf[6] + redf[7];
  const float invS = 1.0f / S;
  // PV: thread owns out[t*4..t*4+3]; waves 0-1 additionally own [1024+t*4 ..)
  float a0 = 0.f, a1 = 0.f, a2 = 0.f, a3 = 0.f;
  float b0 = 0.f, b1 = 0.f, b2 = 0.f, b3 = 0.f;
  const int ecnt = (cnt < CAP) ? cnt : CAP;
  const bool lohalf = (t < 128);
  for (int e = 0; e < ecnt; e++) {
    float se = ses[e] * invS;
    const float* vr = vsb + (long)lm[e] * 1536;
    float4 v4 = *(const float4*)&vr[t*4];
    a0 = fmaf(se, v4.x, a0);
    a1 = fmaf(se, v4.y, a1);
    a2 = fmaf(se, v4.z, a2);
    a3 = fmaf(se, v4.w, a3);
    if (lohalf) {
      float4 w4 = *(const float4*)&vr[1024 + t*4];
      b0 = fmaf(se, w4.x, b0);
      b1 = fmaf(se, w4.y, b1);
      b2 = fmaf(se, w4.z, b2);
      b3 = fmaf(se, w4.w, b3);
    }
  }
  float* orow = outr + (long)bb*6291456 + (long)n * 1536;
  float4 o; o.x = a0; o.y = a1; o.z = a2; o.w = a3;
  *(float4*)&orow[t*4] = o;
  if (lohalf) {
    float4 o2; o2.x = b0; o2.y = b1; o2.z = b2; o2.w = b3;
    *(float4*)&orow[1024 + t*4] = o2;
  }
}

// ------- per-channel l2 norm over 65536 (fhr k2); in-place safe -------
__global__ __launch_bounds__(1024) void l2n_sp(
    const float* __restrict__ in, float* __restrict__ out)
{
  const int ch = blockIdx.x, b = blockIdx.y, t = threadIdx.x;
  const float* ip = in + ((long)b*96 + ch) * HW;
  float ss = 0.f;
  for (int i = t; i < 65536; i += 1024) { float v = ip[i]; ss = fmaf(v, v, ss); }
  __shared__ float red[16];
  #pragma unroll
  for (int s = 1; s < 64; s <<= 1) ss += __shfl_xor(ss, s, 64);
  if ((t & 63) == 0) red[t >> 6] = ss;
  __syncthreads();
  if (t == 0) {
    float s2 = 0.f;
    for (int i = 0; i < 16; i++) s2 += red[i];
    red[0] = fmaxf(sqrtf(s2), 1e-12f);
  }
  __syncthreads();
  const float nrm = red[0];
  float* op = out + ((long)b*96 + ch) * HW;
  for (int i = t; i < 65536; i += 1024) op[i] = ip[i] / nrm;
}

// -------- a2 stage 1: raw-q Gram + q sum-of-squares partials ----------
#define A2_NCH 16
__global__ __launch_bounds__(256) void a2_part(
    const float* __restrict__ q2n, const float* __restrict__ k2n,
    float* __restrict__ part, float* __restrict__ qqpart)
{
  __shared__ float sh[24*260];
  const int t = threadIdx.x;
  const int ch = blockIdx.x, h = blockIdx.y, b = blockIdx.z;
  const long base = ((long)b*96 + h*12) * HW + ch*4096;
  const int c = t / 12, d = t - (t/12)*12;
  float acc = 0.f;
  float qq = 0.f;
  for (int sub = 0; sub < 16; sub++) {
    __syncthreads();
    #pragma unroll
    for (int j = 0; j < 6; j++) {
      const int v = j*256 + t;
      const int row = v >> 6;
      const int col4 = v & 63;
      const float* src = (row < 12)
        ? q2n + base + (long)row*HW + sub*256 + col4*4
        : k2n + base + (long)(row-12)*HW + sub*256 + col4*4;
      *(float4*)&sh[row*260 + col4*4] = *(const float4*)src;
    }
    __syncthreads();
    if (t < 144) {
      const float* qr = &sh[c*260];
      const float* kr = &sh[(12+d)*260];
      #pragma unroll
      for (int i4 = 0; i4 < 64; i4++) {
        float4 qv = *(const float4*)&qr[i4*4];
        float4 kv = *(const float4*)&kr[i4*4];
        acc = fmaf(qv.x, kv.x, acc);
        acc = fmaf(qv.y, kv.y, acc);
        acc = fmaf(qv.z, kv.z, acc);
        acc = fmaf(qv.w, kv.w, acc);
      }
    } else if (t < 156) {
      const float* qr = &sh[(t-144)*260];
      #pragma unroll
      for (int i4 = 0; i4 < 64; i4++) {
        float4 qv = *(const float4*)&qr[i4*4];
        qq = fmaf(qv.x, qv.x, qq);
        qq = fmaf(qv.y, qv.y, qq);
        qq = fmaf(qv.z, qv.z, qq);
        qq = fmaf(qv.w, qv.w, qq);
      }
    }
  }
  if (t < 144)
    part[(((long)b*8 + h)*A2_NCH + ch)*144 + t] = acc;
  else if (t < 156)
    qqpart[(((long)b*8 + h)*A2_NCH + ch)*12 + (t-144)] = qq;
}

// -------- a2 stage 2: fold q-normalization --------
__global__ __launch_bounds__(256) void a2_fin(
    const float* __restrict__ part, const float* __restrict__ qqpart,
    const float* __restrict__ temp, float* __restrict__ a2s)
{
  __shared__ float m[144];
  __shared__ float qn[12];
  const int t = threadIdx.x;
  const int h = blockIdx.x, b = blockIdx.y;
  if (t < 144) {
    float s = 0.f;
    const float* pp = part + (((long)b*8 + h)*A2_NCH)*144 + t;
    #pragma unroll
    for (int ch = 0; ch < A2_NCH; ch++) s += pp[ch*144];
    m[t] = s;
  } else if (t < 156) {
    float s = 0.f;
    const float* pp = qqpart + (((long)b*8 + h)*A2_NCH)*12 + (t-144);
    #pragma unroll
    for (int ch = 0; ch < A2_NCH; ch++) s += pp[ch*12];
    qn[t-144] = fmaxf(sqrtf(s), 1e-12f);
  }
  __syncthreads();
  if (t < 12) {
    const float tv = temp[h];
    const float scale = tv / qn[t];
    float mx = -INFINITY;
    float a[12];
    #pragma unroll
    for (int d = 0; d < 12; d++) { a[d] = m[t*12+d] * scale; mx = fmaxf(mx, a[d]); }
    float e[12], sum = 0.f;
    #pragma unroll
    for (int d = 0; d < 12; d++) { e[d] = expf(a[d]-mx); sum += e[d]; }
    float inv = 1.0f/sum;
    float* op = a2s + (((long)b*8 + h)*12 + t)*12;
    #pragma unroll
    for (int d = 0; d < 12; d++) op[d] = e[d]*inv;
  }
}

extern "C" void kernel_launch(void* const* d_in, const int* in_sizes, int n_in,
                              void* d_out, int out_size, void* d_ws, size_t ws_size,
                              hipStream_t stream) {
  const float* x        = (const float*)d_in[0];
  const float* qk_w     = (const float*)d_in[1];
  const float* qk_dw    = (const float*)d_in[2];
  const float* v_w      = (const float*)d_in[3];
  const float* v_dw     = (const float*)d_in[4];
  const float* k2_w     = (const float*)d_in[5];
  const float* k2_dw    = (const float*)d_in[6];
  const float* q2_w     = (const float*)d_in[7];
  const float* q2_dw    = (const float*)d_in[8];
  const float* proj_w   = (const float*)d_in[9];
  const float* sab_temp = (const float*)d_in[10];
  const float* fqkv_w   = (const float*)d_in[11];
  const float* fqkv_dw  = (const float*)d_in[12];
  const float* fproj_w  = (const float*)d_in[13];
  const float* fhr_temp = (const float*)d_in[14];
  float* out = (float*)d_out;
  float* ws  = (float*)d_ws;

  float* O2  = out;
  float* KS  = out + 12582912;
  float* VS  = out + 14155776;
  float* K2N = out + 26738688;
  float* V2  = out + 39321600;

  float* A0   = ws;
  float* A1   = ws + 25165824;
  float* QD   = ws + 50331648;
  float* KD   = ws + 51904512;
  float* QN   = ws + 53477376;
  float* A2S  = ws + 55050240;
  float* PART = ws + 55052544;
  unsigned short* WHL = (unsigned short*)QN;
  float* ATT  = ws;
  unsigned short* QSP = (unsigned short*)(ws + 33554432);
  unsigned short* KSP = (unsigned short*)(ws + 35127296);
  float* AOUT = ws + 37748736;
  float* P1  = ws;
  float* P2  = ws + 12582912;
  float* P3  = ws + 25165824;
  float* ALNQ = P2;
  float* QQP = QD;
  unsigned short* W2HL = (unsigned short*)PART;

  dim3 b256(256), b1024(1024);

  wsplit<<<dim3(252), b256, 0, stream>>>(qk_w, v_w, q2_w, k2_w, WHL);
  conv1x1_mfma<<<dim3(512,2), b256, 0, stream>>>(
      x, 96L*HW, WHL, WHL+110592, 0, 0,
      A0, 192L*HW, A1, 96L*HW, A1, 96L*HW, 12, 18, 18, 0);
  dw3x3_vs<<<dim3(1024,2), b256, 0, stream>>>(A1, v_dw, VS);
  dw3x3v<<<dim3(64,192,2), b256, 0, stream>>>(A0, 192, qk_dw, A1, 192);
  conv1x1_mfma<<<dim3(512,2), b256, 0, stream>>>(
      A1, 192L*HW, WHL, WHL+110592, 0, 288,
      A0, 192L*HW, A0, 192L*HW, A0, 192L*HW, 12, 12, 12, 0);
  dw4x4s4v<<<dim3(4,192,2), b256, 0, stream>>>(A0, q2_dw, QD);
  conv1x1_mfma<<<dim3(512,2), b256, 0, stream>>>(
      A1 + 96L*HW, 192L*HW, WHL, WHL+110592, 0, 480,
      A0, 192L*HW, A0, 192L*HW, A0, 192L*HW, 12, 12, 12, 0);
  dw4x4s4v<<<dim3(4,192,2), b256, 0, stream>>>(A0, k2_dw, KD);
  l2n192<<<dim3(4096), b256, 0, stream>>>(QD, QN, KD, KS);
  bf16split<<<dim3(6144), b256, 0, stream>>>(QN, QSP);
  bf16split<<<dim3(6144), b256, 0, stream>>>(KS, KSP);
  attn_qk_mfma<<<dim3(32,32,2), b256, 0, stream>>>(QSP, KSP, ATT, sab_temp);
  attn_out_k<<<dim3(4096,2), b256, 0, stream>>>(ATT, VS, AOUT);
  wcomp1<<<dim3(108), b256, 0, stream>>>(fqkv_w, proj_w, WHL);
  conv1x1_mfma<<<dim3(512,2), b256, 0, stream>>>(
      AOUT, 6291456L, WHL, WHL+110592, 0, 768,
      P1, 96L*HW, P2, 96L*HW, P3, 96L*HW, 6, 12, 18, 1);
  dw3x3v<<<dim3(64,96,2), b256, 0, stream>>>(P2, 96, fqkv_dw +  864, K2N, 96);
  dw3x3v<<<dim3(64,96,2), b256, 0, stream>>>(P3, 96, fqkv_dw + 1728, V2,  96);
  dw3x3v<<<dim3(64,96,2), b256, 0, stream>>>(P1, 96, fqkv_dw,        ALNQ, 96);
  l2n_sp<<<dim3(96,2), b1024, 0, stream>>>(K2N, K2N);
  a2_part<<<dim3(A2_NCH,8,2), b256, 0, stream>>>(ALNQ, K2N, PART, QQP);
  a2_fin<<<dim3(8,2), b256, 0, stream>>>(PART, QQP, fhr_temp, A2S);
  wcomp2<<<dim3(36,2), b256, 0, stream>>>(fproj_w, A2S, W2HL);
  conv1x1_mfma<<<dim3(512,2), b256, 0, stream>>>(
      V2, 96L*HW, W2HL, W2HL+18432, 9216, 0,
      O2, 96L*HW, O2, 96L*HW, O2, 96L*HW, 6, 6, 6, 0);
}